// Round 5
// baseline (921.592 us; speedup 1.0000x reference)
//
#include <hip/hip_runtime.h>
#include <hip/hip_bf16.h>

typedef unsigned short u16;
typedef unsigned int u32;
typedef __attribute__((ext_vector_type(8))) short short8;
typedef __attribute__((ext_vector_type(4))) float f32x4;

#define Bq 8
#define Cc 128
#define C4 512
#define Hh 256
#define Wf 256
#define H2 128
#define W2 128
#define HW2 16384
#define NPIX 131072.0f

__device__ __forceinline__ float gelu_f(float x) {
    return 0.5f * x * (1.0f + erff(x * 0.70710678118654752f));
}
__device__ __forceinline__ float bf2f(u16 u) {
    union { float f; u32 i; } v; v.i = ((u32)u) << 16; return v.f;
}
__device__ __forceinline__ u16 f2bf(float f) {
    union { float f; u32 i; } v; v.f = f;
    u32 r = v.i + 0x7FFFu + ((v.i >> 16) & 1u);
    return (u16)(r >> 16);
}

// ---------------- weights f32 -> bf16 (pw1 pre-scaled by gn_g) ----------------
__global__ __launch_bounds__(256) void k_wconv(const float* __restrict__ w_c1,
                                               const float* __restrict__ pw1,
                                               const float* __restrict__ pw2,
                                               const float* __restrict__ w_c2,
                                               const float* __restrict__ gn_g,
                                               u16* __restrict__ wb) {
    int i = blockIdx.x * 256 + threadIdx.x;   // 0..163839
    float v;
    if (i < 65536) v = w_c1[i];
    else if (i < 81920) v = pw1[i - 65536] * gn_g[(i - 65536) & 127];
    else if (i < 98304) v = pw2[i - 81920];
    else v = w_c2[i - 98304];
    wb[i] = f2bf(v);
}

// ---------------- LN-fold vectors: wgs[o]=sum_c w*g, wbv[o]=sum_c w*b --------
__global__ __launch_bounds__(128) void k_wvec(const float* __restrict__ pw1,
                                              const float* __restrict__ gg,
                                              const float* __restrict__ gb,
                                              float* __restrict__ wbv,
                                              float* __restrict__ wgs) {
    int o = threadIdx.x;
    float a = 0.f, bv = 0.f;
    for (int c = 0; c < 128; ++c) {
        float w = pw1[o * 128 + c];
        a += w * gg[c];
        bv += w * gb[c];
    }
    wgs[o] = a;
    wbv[o] = bv;
}

// ---------------- DWT: x NCHW f32 -> h1 pixel-major bf16 [b][pix][512] --------
__global__ __launch_bounds__(256) void k_dwt(const float* __restrict__ x,
                                             u16* __restrict__ h1) {
    __shared__ float lin[2 * 4224];
    __shared__ __align__(16) u16 obuf[16 * 512];
    const int t = threadIdx.x;
    const int b = blockIdx.z, oi = blockIdx.y, jt = blockIdx.x;
    {
        int c = t & 127, h = t >> 7;
        const float* xp = x + (((long)(b * Cc + c)) * Hh + (2 * oi + h)) * Wf + jt * 32;
        float* lp = lin + h * 4224 + c * 33;
#pragma unroll
        for (int q = 0; q < 8; ++q) {
            float4 v = *(const float4*)(xp + q * 4);
            lp[q * 4 + 0] = v.x; lp[q * 4 + 1] = v.y;
            lp[q * 4 + 2] = v.z; lp[q * 4 + 3] = v.w;
        }
    }
    __syncthreads();
    {
        int c = t & 127, pg = t >> 7;
        const float* l0 = lin + c * 33;
        const float* l1 = lin + 4224 + c * 33;
#pragma unroll
        for (int u = 0; u < 8; ++u) {
            int p = pg * 8 + u;
            float x00 = l0[2 * p], x01 = l0[2 * p + 1];
            float x10 = l1[2 * p], x11 = l1[2 * p + 1];
            obuf[p * 512 + 0 * 128 + c] = f2bf((x00 + x01 + x10 + x11) * 0.5f);
            obuf[p * 512 + 1 * 128 + c] = f2bf((x00 + x01 - x10 - x11) * 0.5f);
            obuf[p * 512 + 2 * 128 + c] = f2bf((x00 - x01 + x10 - x11) * 0.5f);
            obuf[p * 512 + 3 * 128 + c] = f2bf((x00 - x01 - x10 + x11) * 0.5f);
        }
    }
    __syncthreads();
    {
        int p = t >> 4, seg = t & 15;
        long opix = (long)b * HW2 + (long)oi * W2 + jt * 16 + p;
        const uint4* src = (const uint4*)(obuf + p * 512 + seg * 32);
        uint4* dst = (uint4*)(h1 + opix * 512 + seg * 32);
        dst[0] = src[0]; dst[1] = src[1]; dst[2] = src[2]; dst[3] = src[3];
    }
}

// ---------------- bf16 MFMA NT-GEMM with fused stats + coalesced epilogue -----
// C[M][N] = A[M][K] * B[N][K]^T.
// EPI: 0 raw bf16 store; 1 LN-folded affine + gelu (pw1); 2 +bias +residual (pw2)
// STATS: 0 none; 1 per-col sum/sq (conv1), padded atomics (value i at [i*16]).
template <int EPI, int STATS>
__global__ __launch_bounds__(256) void k_mfma(const u16* __restrict__ A,
                                              const u16* __restrict__ Bw,
                                              u16* __restrict__ C,
                                              const float* __restrict__ bias,
                                              const u16* __restrict__ res,
                                              const float* __restrict__ wbv,
                                              const float* __restrict__ wgs,
                                              const float* __restrict__ lnS,
                                              const float* __restrict__ lnQ,
                                              float* __restrict__ statS,
                                              float* __restrict__ statQ,
                                              int N, int K,
                                              long aBs, long bBs, long cBs) {
    __shared__ __align__(16) u16 lds[16384];   // staging (2x8K), then C bounce
    __shared__ float sblk[128], qblk[128];
    __shared__ float lnred[2];
    const int t = threadIdx.x;
    const int lane = t & 63, w = t >> 6, wr = w >> 1, wc = w & 1;
    const int b = blockIdx.z;
    const int m0 = blockIdx.y * 128, n0 = blockIdx.x * 128;
    const u16* Ab = A + (long)b * aBs + (long)m0 * K;
    const u16* Bb = Bw + (long)b * bBs + (long)n0 * K;

    if (EPI == 1) {
        if (t < 64) {
            float s = lnS[((long)b * 64 + t) * 16];
            float q = lnQ[((long)b * 64 + t) * 16];
#pragma unroll
            for (int off = 32; off; off >>= 1) {
                s += __shfl_down(s, off);
                q += __shfl_down(q, off);
            }
            if (t == 0) { lnred[0] = s; lnred[1] = q; }
        }
        __syncthreads();
    }
    if (t < 128) {
        if (STATS) { sblk[t] = 0.f; qblk[t] = 0.f; }
        if (EPI == 1) {
            const float invN = 1.0f / 2097152.0f;
            float mu = lnred[0] * invN;
            float var = lnred[1] * invN - mu * mu;
            float rs2 = rsqrtf(var + 1e-5f);
            sblk[t] = bias[t] + wbv[t] - mu * rs2 * wgs[t];
        }
        if (EPI == 2) sblk[t] = bias[t];
    }

    uint4 ra[4], rb[4];
#define GLOAD(dst, base, k0)                                                     \
    {                                                                            \
        _Pragma("unroll")                                                        \
        for (int i = 0; i < 4; ++i) {                                            \
            int s = i * 256 + t;                                                 \
            dst[i] = *(const uint4*)(base + (long)(s >> 3) * K + (k0) + (s & 7) * 8); \
        }                                                                        \
    }
#define LWRITE(ofs, src)                                                         \
    {                                                                            \
        _Pragma("unroll")                                                        \
        for (int i = 0; i < 4; ++i) {                                            \
            int s = i * 256 + t;                                                 \
            int row_ = s >> 3, ch_ = s & 7;                                      \
            *(uint4*)((char*)lds + (ofs) + row_ * 128 + 16 * (ch_ ^ (row_ & 7))) = src[i]; \
        }                                                                        \
    }

    f32x4 acc[4][4];
#pragma unroll
    for (int i = 0; i < 4; ++i)
#pragma unroll
        for (int j = 0; j < 4; ++j) acc[i][j] = (f32x4){0.f, 0.f, 0.f, 0.f};

    GLOAD(ra, Ab, 0)
    GLOAD(rb, Bb, 0)
    const int r15 = lane & 15, kq = lane >> 4;
    for (int k0 = 0; k0 < K; k0 += 64) {
        __syncthreads();
        LWRITE(0, ra)
        LWRITE(16384, rb)
        __syncthreads();
        if (k0 + 64 < K) { GLOAD(ra, Ab, k0 + 64) GLOAD(rb, Bb, k0 + 64) }
#pragma unroll
        for (int ks = 0; ks < 2; ++ks) {
            short8 af[4], bfv[4];
            const int ch = ks * 4 + kq;
#pragma unroll
            for (int mi = 0; mi < 4; ++mi) {
                int row = wr * 64 + mi * 16 + r15;
                af[mi] = *(const short8*)((const char*)lds + row * 128 + 16 * (ch ^ (row & 7)));
            }
#pragma unroll
            for (int ni = 0; ni < 4; ++ni) {
                int row = wc * 64 + ni * 16 + r15;
                bfv[ni] = *(const short8*)((const char*)lds + 16384 + row * 128 + 16 * (ch ^ (row & 7)));
            }
#pragma unroll
            for (int mi = 0; mi < 4; ++mi)
#pragma unroll
                for (int ni = 0; ni < 4; ++ni)
                    acc[mi][ni] = __builtin_amdgcn_mfma_f32_16x16x32_bf16(
                        af[mi], bfv[ni], acc[mi][ni], 0, 0, 0);
        }
    }
    __syncthreads();

    // --- bounce raw acc (bf16) into lds: [row][col ^ ((row&7)<<3)] ---
#pragma unroll
    for (int mi = 0; mi < 4; ++mi)
#pragma unroll
        for (int ni = 0; ni < 4; ++ni)
#pragma unroll
            for (int r = 0; r < 4; ++r) {
                int row = wr * 64 + mi * 16 + kq * 4 + r;
                int col = wc * 64 + ni * 16 + r15;
                lds[row * 128 + (col ^ ((row & 7) << 3))] = f2bf(acc[mi][ni][r]);
            }

    if (STATS == 1) {
#pragma unroll
        for (int ni = 0; ni < 4; ++ni) {
            float s = 0.f, q2 = 0.f;
#pragma unroll
            for (int mi = 0; mi < 4; ++mi)
#pragma unroll
                for (int r = 0; r < 4; ++r) {
                    float v = acc[mi][ni][r];
                    s += v; q2 += v * v;
                }
            s += __shfl_down(s, 32); s += __shfl_down(s, 16);
            q2 += __shfl_down(q2, 32); q2 += __shfl_down(q2, 16);
            if (lane < 16) {
                int col = wc * 64 + ni * 16 + r15;
                atomicAdd(&sblk[col], s);
                atomicAdd(&qblk[col], q2);
            }
        }
    }
    __syncthreads();

    // --- coalesced read-back + epilogue transform + uint4 stores ---
    u16* Cb = C + (long)b * cBs;
    {
        int row = t >> 1, half = (t & 1) * 64;
        int sx = (row & 7) << 3;
        long gbase = (long)(m0 + row) * N + n0;
        float rs = 1.f;
        if (EPI == 1) {
            const float invN = 1.0f / 2097152.0f;
            float mu = lnred[0] * invN;
            float var = lnred[1] * invN - mu * mu;
            rs = rsqrtf(var + 1e-5f);
        }
#pragma unroll
        for (int q = 0; q < 8; ++q) {
            int c = half + q * 8;
            uint4 raw = *(const uint4*)(lds + row * 128 + (c ^ sx));
            if (EPI == 0) {
                *(uint4*)(Cb + gbase + c) = raw;
            } else {
                u16* pv = (u16*)&raw;
                uint4 rr;
                if (EPI == 2) rr = *(const uint4*)(res + (long)b * cBs + gbase + c);
                const u16* rv = (const u16*)&rr;
#pragma unroll
                for (int u = 0; u < 8; ++u) {
                    float v = bf2f(pv[u]);
                    if (EPI == 1) v = gelu_f(rs * v + sblk[c + u]);
                    if (EPI == 2) v = v + sblk[c + u] + bf2f(rv[u]);
                    pv[u] = f2bf(v);
                }
                *(uint4*)(Cb + gbase + c) = raw;
            }
        }
    }
    if (STATS && t < 128) {
        int base = (STATS == 1) ? n0 : m0;
        atomicAdd(statS + (long)(base + t) * 16, sblk[t]);
        atomicAdd(statQ + (long)(base + t) * 16, qblk[t]);
    }
#undef GLOAD
#undef LWRITE
}

// ---------------- BN1 apply + gelu: bufA -> bufH (padded stats) ----------------
__global__ __launch_bounds__(256) void k_bn1_gelu(const u16* __restrict__ in,
                                                  u16* __restrict__ out,
                                                  const float* __restrict__ sum,
                                                  const float* __restrict__ sq,
                                                  const float* __restrict__ g,
                                                  const float* __restrict__ bb) {
    long e = ((long)blockIdx.x * 256 + threadIdx.x) * 8;
    int c0 = (int)(e & 127);
    uint4 raw = *(const uint4*)(in + e);
    u16* pv = (u16*)&raw;
    const float invN = 1.0f / 131072.0f;
#pragma unroll
    for (int u = 0; u < 8; ++u) {
        int c = c0 + u;
        float mu = sum[(long)c * 16] * invN;
        float var = sq[(long)c * 16] * invN - mu * mu;
        float rscale = rsqrtf(var + 1e-5f);
        float sc = rscale * g[c], sh = bb[c] - mu * sc;
        pv[u] = f2bf(gelu_f(bf2f(pv[u]) * sc + sh));
    }
    *(uint4*)(out + e) = raw;
}

// ---------------- depthwise 3x3 NHWC bf16 + fused LN stats (64 slots/batch) ---
__global__ __launch_bounds__(256) void k_dwconv(const u16* __restrict__ x,
                                                u16* __restrict__ y,
                                                const float* __restrict__ w,
                                                const float* __restrict__ bias,
                                                float* __restrict__ lnS,
                                                float* __restrict__ lnQ) {
    __shared__ float wl2[1152];
    const int t = threadIdx.x;
    for (int idx = t; idx < 1152; idx += 256) {
        int c = idx / 9, tap = idx - c * 9;
        wl2[tap * 128 + (c & 7) * 16 + (c >> 3)] = w[idx];
    }
    __syncthreads();
    const int cg = t & 15, jj = t >> 4;
    const int j = blockIdx.x * 16 + jj, i = blockIdx.y, b = blockIdx.z;
    const u16* xb = x + (long)b * HW2 * 128 + cg * 8;
    uint4 raw[3][3];
    const uint4 z4 = make_uint4(0u, 0u, 0u, 0u);
#pragma unroll
    for (int r = 0; r < 3; ++r) {
        int row = i - 1 + r;
#pragma unroll
        for (int q = 0; q < 3; ++q) {
            int col = j - 1 + q;
            bool ok = (row >= 0) & (row < H2) & (col >= 0) & (col < W2);
            raw[r][q] = ok ? *(const uint4*)(xb + ((long)row * W2 + col) * 128) : z4;
        }
    }
    float acc[8];
#pragma unroll
    for (int u = 0; u < 8; ++u) acc[u] = bias[cg * 8 + u];
#pragma unroll
    for (int r = 0; r < 3; ++r)
#pragma unroll
        for (int q = 0; q < 3; ++q) {
            const u16* pv = (const u16*)&raw[r][q];
            const int tap = r * 3 + q;
#pragma unroll
            for (int u = 0; u < 8; ++u)
                acc[u] = fmaf(bf2f(pv[u]), wl2[tap * 128 + u * 16 + cg], acc[u]);
        }
    uint4 outv; u16* ov = (u16*)&outv;
    float s = 0.f, q2 = 0.f;
#pragma unroll
    for (int u = 0; u < 8; ++u) {
        ov[u] = f2bf(acc[u]);
        s += acc[u]; q2 += acc[u] * acc[u];
    }
    *(uint4*)(y + ((long)b * HW2 + (long)i * W2 + j) * 128 + cg * 8) = outv;
#pragma unroll
    for (int off = 32; off; off >>= 1) {
        s += __shfl_down(s, off);
        q2 += __shfl_down(q2, off);
    }
    __shared__ float r1[4], r2[4];
    if ((t & 63) == 0) { r1[t >> 6] = s; r2[t >> 6] = q2; }
    __syncthreads();
    if (t == 0) {
        int slot = (blockIdx.y * 8 + blockIdx.x) & 63;
        atomicAdd(lnS + ((long)b * 64 + slot) * 16, r1[0] + r1[1] + r1[2] + r1[3]);
        atomicAdd(lnQ + ((long)b * 64 + slot) * 16, r2[0] + r2[1] + r2[2] + r2[3]);
    }
}

// ---------------- second-moment M2 = Y^T Y (128x128) + col-sums ----------------
// 32 blocks, each reduces a 4096-pixel chunk via MFMA with transpose-in-LDS.
__global__ __launch_bounds__(256) void k_moment(const u16* __restrict__ Y,
                                                float* __restrict__ M2,
                                                float* __restrict__ csum) {
    __shared__ __align__(16) u16 T[8192];   // [128 c][64 px] swizzled, 16 KB
    const int t = threadIdx.x;
    const int lane = t & 63, w = t >> 6, wr = w >> 1, wc = w & 1;
    const int r15 = lane & 15, kq = lane >> 4;
    const long px0 = (long)blockIdx.x * 4096;
    const int myc = t >> 1, ph = t & 1;   // col-sum assignment
    float csacc = 0.f;

    f32x4 acc[4][4];
#pragma unroll
    for (int i = 0; i < 4; ++i)
#pragma unroll
        for (int j = 0; j < 4; ++j) acc[i][j] = (f32x4){0.f, 0.f, 0.f, 0.f};

    for (int it = 0; it < 64; ++it) {
        uint4 rv[4];
#pragma unroll
        for (int i = 0; i < 4; ++i) {
            int s = i * 256 + t;
            int px = s >> 4, ch8 = (s & 15) * 8;
            rv[i] = *(const uint4*)(Y + (px0 + it * 64 + px) * 128 + ch8);
        }
        __syncthreads();
#pragma unroll
        for (int i = 0; i < 4; ++i) {
            int s = i * 256 + t;
            int px = s >> 4, ch8 = (s & 15) * 8;
            const u16* pv = (const u16*)&rv[i];
#pragma unroll
            for (int u = 0; u < 8; ++u) {
                int row = ch8 + u;
                T[row * 64 + 8 * ((px >> 3) ^ (row & 7)) + (px & 7)] = pv[u];
            }
        }
        __syncthreads();
        // col-sum from LDS tile
#pragma unroll
        for (int p2 = 0; p2 < 32; ++p2) {
            int px = ph * 32 + p2;
            csacc += bf2f(T[myc * 64 + 8 * ((px >> 3) ^ (myc & 7)) + (px & 7)]);
        }
        // MFMA: A rows = c (wr half), B rows = c' (wc half), k = px
#pragma unroll
        for (int ks = 0; ks < 2; ++ks) {
            const int ch = ks * 4 + kq;
            short8 af[4], bfv[4];
#pragma unroll
            for (int mi = 0; mi < 4; ++mi) {
                int row = wr * 64 + mi * 16 + r15;
                af[mi] = *(const short8*)(T + row * 64 + 8 * (ch ^ (row & 7)));
            }
#pragma unroll
            for (int ni = 0; ni < 4; ++ni) {
                int row = wc * 64 + ni * 16 + r15;
                bfv[ni] = *(const short8*)(T + row * 64 + 8 * (ch ^ (row & 7)));
            }
#pragma unroll
            for (int mi = 0; mi < 4; ++mi)
#pragma unroll
                for (int ni = 0; ni < 4; ++ni)
                    acc[mi][ni] = __builtin_amdgcn_mfma_f32_16x16x32_bf16(
                        af[mi], bfv[ni], acc[mi][ni], 0, 0, 0);
        }
    }
#pragma unroll
    for (int mi = 0; mi < 4; ++mi)
#pragma unroll
        for (int ni = 0; ni < 4; ++ni)
#pragma unroll
            for (int r = 0; r < 4; ++r) {
                int row = wr * 64 + mi * 16 + kq * 4 + r;
                int col = wc * 64 + ni * 16 + r15;
                atomicAdd(M2 + row * 128 + col, acc[mi][ni][r]);
            }
    atomicAdd(csum + (long)myc * 16, csacc);
}

// ---------------- combine: per-out-channel BN2 scale/shift ----------------
__global__ __launch_bounds__(128) void k_statcomb(const float* __restrict__ w_c2,
                                                  const float* __restrict__ M2,
                                                  const float* __restrict__ csum,
                                                  const float* __restrict__ g,
                                                  const float* __restrict__ bb,
                                                  float* __restrict__ scsh) {
    __shared__ float wl[128];
    __shared__ float red[2][2];
    const int o = blockIdx.x, c = threadIdx.x;
    wl[c] = w_c2[o * 128 + c];
    __syncthreads();
    const float* m2r = M2 + c * 128;
    float tmp = 0.f;
#pragma unroll
    for (int c2 = 0; c2 < 128; c2 += 4) {
        float4 m = *(const float4*)(m2r + c2);
        tmp += m.x * wl[c2] + m.y * wl[c2 + 1] + m.z * wl[c2 + 2] + m.w * wl[c2 + 3];
    }
    float s2p = wl[c] * tmp;
    float mup = wl[c] * csum[(long)c * 16];
#pragma unroll
    for (int off = 32; off; off >>= 1) {
        s2p += __shfl_down(s2p, off);
        mup += __shfl_down(mup, off);
    }
    if ((c & 63) == 0) { red[0][c >> 6] = s2p; red[1][c >> 6] = mup; }
    __syncthreads();
    if (c == 0) {
        float s2 = (red[0][0] + red[0][1]) / NPIX;
        float mu = (red[1][0] + red[1][1]) / NPIX;
        float var = s2 - mu * mu;
        float rs = rsqrtf(var + 1e-5f);
        float sc = g[o] * rs;
        scsh[o] = sc;
        scsh[512 + o] = bb[o] - mu * sc;
    }
}

// ---------------- conv2 + BN2 + GELU + IDWT -> out f32 NCHW ----------------
// Grid: (256 pixel-tiles of 64, 1, 8 batches). Block: 256 thr, 4 waves (2x2).
// Per block: B-tile = 64 px x K128 (staged once), 4 sequential m-tiles (subbands).
__global__ __launch_bounds__(256) void k_conv2_idwt(const u16* __restrict__ Y,
                                                    const u16* __restrict__ W,
                                                    const float* __restrict__ scsh,
                                                    float* __restrict__ out) {
    __shared__ __align__(16) u16 lA[16384];  // [2 chunk][128 row][64 k]  32 KB
    __shared__ __align__(16) u16 lB[8192];   // [2 chunk][64 row][64 k]   16 KB
    __shared__ float sparam[1024];           // scale[512] | shift[512]
    const int t = threadIdx.x;
    const int lane = t & 63, w = t >> 6, wr = w >> 1, wc = w & 1;
    const int r15 = lane & 15, kq = lane >> 4;
    const int b = blockIdx.y, n0 = blockIdx.x;
#pragma unroll
    for (int u = 0; u < 4; ++u) sparam[t + u * 256] = scsh[t + u * 256];

    const u16* Yb = Y + ((long)b * HW2 + (long)n0 * 64) * 128;
    uint4 rb4[4], ra8[8];
#pragma unroll
    for (int i = 0; i < 4; ++i) {            // B: 64 rows x 16 segs
        int s = i * 256 + t, row = s >> 4, seg = s & 15;
        rb4[i] = *(const uint4*)(Yb + (long)row * 128 + seg * 8);
    }
#define GLOADA(q)                                                                \
    {                                                                            \
        _Pragma("unroll")                                                        \
        for (int i = 0; i < 8; ++i) {                                            \
            int s = i * 256 + t, row = s >> 4, seg = s & 15;                     \
            ra8[i] = *(const uint4*)(W + (long)((q) * 128 + row) * 128 + seg * 8); \
        }                                                                        \
    }
#define LWRITEA()                                                                \
    {                                                                            \
        _Pragma("unroll")                                                        \
        for (int i = 0; i < 8; ++i) {                                            \
            int s = i * 256 + t, row = s >> 4, seg = s & 15;                     \
            *(uint4*)((char*)lA + (seg >> 3) * 16384 + row * 128 +               \
                      16 * ((seg & 7) ^ (row & 7))) = ra8[i];                    \
        }                                                                        \
    }
    GLOADA(0)
#pragma unroll
    for (int i = 0; i < 4; ++i) {
        int s = i * 256 + t, row = s >> 4, seg = s & 15;
        *(uint4*)((char*)lB + (seg >> 3) * 8192 + row * 128 +
                  16 * ((seg & 7) ^ (row & 7))) = rb4[i];
    }
    LWRITEA()
    __syncthreads();

    u32 sbp[4][4][2][2];   // [q][mi][ni][rpair] packed bf16 subband values
    for (int q = 0; q < 4; ++q) {
        f32x4 acc[4][2];
#pragma unroll
        for (int mi = 0; mi < 4; ++mi)
#pragma unroll
            for (int ni = 0; ni < 2; ++ni) acc[mi][ni] = (f32x4){0.f, 0.f, 0.f, 0.f};
#pragma unroll
        for (int chunk = 0; chunk < 2; ++chunk)
#pragma unroll
            for (int ks = 0; ks < 2; ++ks) {
                const int ch = ks * 4 + kq;
                short8 af[4], bfv[2];
#pragma unroll
                for (int mi = 0; mi < 4; ++mi) {
                    int row = wr * 64 + mi * 16 + r15;
                    af[mi] = *(const short8*)((const char*)lA + chunk * 16384 +
                                              row * 128 + 16 * (ch ^ (row & 7)));
                }
#pragma unroll
                for (int ni = 0; ni < 2; ++ni) {
                    int row = wc * 32 + ni * 16 + r15;
                    bfv[ni] = *(const short8*)((const char*)lB + chunk * 8192 +
                                               row * 128 + 16 * (ch ^ (row & 7)));
                }
#pragma unroll
                for (int mi = 0; mi < 4; ++mi)
#pragma unroll
                    for (int ni = 0; ni < 2; ++ni)
                        acc[mi][ni] = __builtin_amdgcn_mfma_f32_16x16x32_bf16(
                            af[mi], bfv[ni], acc[mi][ni], 0, 0, 0);
            }
        if (q < 3) GLOADA(q + 1)
        // epilogue: BN2 affine + gelu, pack to bf16 pairs
#pragma unroll
        for (int mi = 0; mi < 4; ++mi)
#pragma unroll
            for (int ni = 0; ni < 2; ++ni)
#pragma unroll
                for (int rp = 0; rp < 2; ++rp) {
                    int c0 = q * 128 + wr * 64 + mi * 16 + kq * 4 + rp * 2;
                    float v0 = gelu_f(acc[mi][ni][rp * 2] * sparam[c0] + sparam[512 + c0]);
                    float v1 = gelu_f(acc[mi][ni][rp * 2 + 1] * sparam[c0 + 1] + sparam[512 + c0 + 1]);
                    sbp[q][mi][ni][rp] = (u32)f2bf(v0) | ((u32)f2bf(v1) << 16);
                }
        if (q < 3) {
            __syncthreads();
            LWRITEA()
            __syncthreads();
        }
    }
    // IDWT combine + f32 stores
    const int i = n0 >> 1, jbase = (n0 & 1) * 64;
#pragma unroll
    for (int mi = 0; mi < 4; ++mi)
#pragma unroll
        for (int ni = 0; ni < 2; ++ni) {
            int j = jbase + wc * 32 + ni * 16 + r15;
#pragma unroll
            for (int rp = 0; rp < 2; ++rp) {
                u32 p0 = sbp[0][mi][ni][rp], p1 = sbp[1][mi][ni][rp];
                u32 p2 = sbp[2][mi][ni][rp], p3 = sbp[3][mi][ni][rp];
#pragma unroll
                for (int e = 0; e < 2; ++e) {
                    int c = wr * 64 + mi * 16 + kq * 4 + rp * 2 + e;
                    float ll = bf2f(e ? (u16)(p0 >> 16) : (u16)(p0 & 0xFFFF));
                    float lh = bf2f(e ? (u16)(p1 >> 16) : (u16)(p1 & 0xFFFF));
                    float hl = bf2f(e ? (u16)(p2 >> 16) : (u16)(p2 & 0xFFFF));
                    float hh = bf2f(e ? (u16)(p3 >> 16) : (u16)(p3 & 0xFFFF));
                    long ob = (((long)(b * Cc + c) * Hh + 2 * i) * Wf + 2 * j);
                    *(float2*)(out + ob) =
                        make_float2((ll + lh + hl + hh) * 0.5f, (ll + lh - hl - hh) * 0.5f);
                    *(float2*)(out + ob + Wf) =
                        make_float2((ll - lh + hl - hh) * 0.5f, (ll - lh - hl + hh) * 0.5f);
                }
            }
        }
#undef GLOADA
#undef LWRITEA
}

extern "C" void kernel_launch(void* const* d_in, const int* in_sizes, int n_in,
                              void* d_out, int out_size, void* d_ws, size_t ws_size,
                              hipStream_t stream) {
    const float* x     = (const float*)d_in[0];
    const float* w_c1  = (const float*)d_in[1];
    const float* bn1_g = (const float*)d_in[3];
    const float* bn1_b = (const float*)d_in[4];
    const float* dw_w  = (const float*)d_in[5];
    const float* dw_b  = (const float*)d_in[6];
    const float* gn_g  = (const float*)d_in[7];
    const float* gn_b  = (const float*)d_in[8];
    const float* pw1_w = (const float*)d_in[9];
    const float* pw1_b = (const float*)d_in[10];
    const float* pw2_w = (const float*)d_in[11];
    const float* pw2_b = (const float*)d_in[12];
    const float* w_c2  = (const float*)d_in[13];
    const float* bn2_g = (const float*)d_in[15];
    const float* bn2_b = (const float*)d_in[16];
    float* out = (float*)d_out;

    const size_t n512 = (size_t)Bq * C4 * HW2;
    const size_t n128 = (size_t)Bq * Cc * HW2;
    u16* h1   = (u16*)d_ws;        // DWT out
    u16* bufA = h1 + n512;         // conv1 raw out
    u16* bufH = bufA + n128;       // post BN1+gelu (= residual)
    u16* bufD = bufH + n128;       // dwconv raw out
    u16* bufP = bufD + n128;       // pw1 out
    u16* bufY = bufP + n128;       // pw2 out (= conv2 input)
    u16* wb   = bufY + n128;       // bf16 weights
    float* stats = (float*)(wb + 163840);
    size_t need = (n512 + 5 * n128 + 163840) * 2 + 41000 * 4;
    if (ws_size < need) return;

    // stats layout (floats):
    float* bn1_sum = stats;            // [0,2048)      128 x16 padded
    float* bn1_sq  = stats + 2048;     // [2048,4096)
    float* ln_sum  = stats + 4096;     // [4096,12288)  8x64 x16 padded
    float* ln_sq   = stats + 12288;    // [12288,20480)
    float* csum    = stats + 20480;    // [20480,22528) 128 x16 padded
    float* M2      = stats + 22528;    // [22528,38912) 128x128 dense
    float* scsh    = stats + 38912;    // [38912,39936) 512 scale | 512 shift
    float* wbv     = stats + 39936;    // 128 dense
    float* wgs     = stats + 40064;    // 128 dense

    hipMemsetAsync(stats, 0, 38912 * sizeof(float), stream);

    // 0. weights -> bf16 (+ LN-fold vectors)
    k_wconv<<<640, 256, 0, stream>>>(w_c1, pw1_w, pw2_w, w_c2, gn_g, wb);
    k_wvec<<<1, 128, 0, stream>>>(pw1_w, gn_g, gn_b, wbv, wgs);

    // 1. DWT -> h1 (pixel-major bf16)
    k_dwt<<<dim3(8, 128, 8), 256, 0, stream>>>(x, h1);

    // 2. conv1 + fused BN1 stats (padded atomics)
    k_mfma<0, 1><<<dim3(1, 128, 8), 256, 0, stream>>>(
        h1, wb, bufA, nullptr, nullptr, nullptr, nullptr, nullptr, nullptr,
        bn1_sum, bn1_sq, 128, 512, (long)HW2 * 512, 0, (long)HW2 * 128);

    // 3. BN1 apply + gelu -> bufH
    k_bn1_gelu<<<8192, 256, 0, stream>>>(bufA, bufH, bn1_sum, bn1_sq, bn1_g, bn1_b);

    // 4. depthwise 3x3 + fused LN stats (64 padded slots/batch)
    k_dwconv<<<dim3(8, 128, 8), 256, 0, stream>>>(bufH, bufD, dw_w, dw_b, ln_sum, ln_sq);

    // 5. pw1 on RAW bufD, LN folded into weights/affine, + gelu
    k_mfma<1, 0><<<dim3(1, 128, 8), 256, 0, stream>>>(
        bufD, wb + 65536, bufP, pw1_b, nullptr, wbv, wgs, ln_sum, ln_sq,
        nullptr, nullptr, 128, 128, (long)HW2 * 128, 0, (long)HW2 * 128);

    // 6. pw2 + bias + residual -> bufY
    k_mfma<2, 0><<<dim3(1, 128, 8), 256, 0, stream>>>(
        bufP, wb + 81920, bufY, pw2_b, bufH, nullptr, nullptr, nullptr, nullptr,
        nullptr, nullptr, 128, 128, (long)HW2 * 128, 0, (long)HW2 * 128);

    // 7. BN2 stats via second moment: M2 = Y^T Y, col-sums; then scale/shift
    k_moment<<<32, 256, 0, stream>>>(bufY, M2, csum);
    k_statcomb<<<512, 128, 0, stream>>>(w_c2, M2, csum, bn2_g, bn2_b, scsh);

    // 8. conv2 + BN2 + gelu + IDWT -> out (z2 never materialized)
    k_conv2_idwt<<<dim3(256, 8), 256, 0, stream>>>(bufY, wb + 98304, scsh, out);
}

// Round 6
// 598.354 us; speedup vs baseline: 1.5402x; 1.5402x over previous
//
#include <hip/hip_runtime.h>
#include <hip/hip_bf16.h>

typedef unsigned short u16;
typedef unsigned int u32;
typedef __attribute__((ext_vector_type(8))) short short8;
typedef __attribute__((ext_vector_type(4))) float f32x4;

#define Bq 8
#define Cc 128
#define C4 512
#define Hh 256
#define Wf 256
#define H2 128
#define W2 128
#define HW2 16384
#define NPIX 131072.0f

// tanh-approx GELU: max abs err ~1e-3, well under the 0.134 budget; ~10 VALU ops
__device__ __forceinline__ float gelu_f(float x) {
    float u = 1.5957691216057308f * (x + 0.044715f * x * x * x);  // 2*sqrt(2/pi)*(...)
    float t = 1.0f - 2.0f / (__expf(u) + 1.0f);                   // tanh(u/2*2)=tanh(inner)
    return 0.5f * x * (1.0f + t);
}
__device__ __forceinline__ float bf2f(u16 u) {
    union { float f; u32 i; } v; v.i = ((u32)u) << 16; return v.f;
}
__device__ __forceinline__ u16 f2bf(float f) {
    union { float f; u32 i; } v; v.f = f;
    u32 r = v.i + 0x7FFFu + ((v.i >> 16) & 1u);
    return (u16)(r >> 16);
}

// ---- weights f32 -> bf16. w_c1 gets the DWT folded in (stride-2 2x2 conv):
// W'[o][c*4+dy*2+dx] = 0.5*(w_ll + sdy*w_lh + sdx*w_hl + sdy*sdx*w_hh)
__global__ __launch_bounds__(256) void k_wconv(const float* __restrict__ w_c1,
                                               const float* __restrict__ pw1,
                                               const float* __restrict__ pw2,
                                               const float* __restrict__ w_c2,
                                               const float* __restrict__ gn_g,
                                               u16* __restrict__ wb) {
    int i = blockIdx.x * 256 + threadIdx.x;   // 0..163839
    float v;
    if (i < 65536) {
        int o = i >> 9, kn = i & 511;
        int c = kn >> 2, dy = (kn >> 1) & 1, dx = kn & 1;
        float sdy = dy ? -1.f : 1.f, sdx = dx ? -1.f : 1.f;
        const float* wr = w_c1 + o * 512 + c;
        v = 0.5f * (wr[0] + sdy * wr[128] + sdx * wr[256] + sdy * sdx * wr[384]);
    } else if (i < 81920) v = pw1[i - 65536] * gn_g[(i - 65536) & 127];
    else if (i < 98304) v = pw2[i - 81920];
    else v = w_c2[i - 98304];
    wb[i] = f2bf(v);
}

// ---- LN-fold vectors: wgs[o]=sum_c w*g, wbv[o]=sum_c w*b ----
__global__ __launch_bounds__(128) void k_wvec(const float* __restrict__ pw1,
                                              const float* __restrict__ gg,
                                              const float* __restrict__ gb,
                                              float* __restrict__ wbv,
                                              float* __restrict__ wgs) {
    int o = threadIdx.x;
    float a = 0.f, bv = 0.f;
    for (int c = 0; c < 128; ++c) {
        float w = pw1[o * 128 + c];
        a += w * gg[c];
        bv += w * gb[c];
    }
    wgs[o] = a;
    wbv[o] = bv;
}

// ---- fused DWT+conv1+BN1-stats: reads x f32 NCHW directly ----
// C[px=i*128+j][o] = sum_k bf16(x[b][c][2i+dy][2j+dx]) * W'[o][k], k=c*4+dy*2+dx
__global__ __launch_bounds__(256) void k_conv1(const float* __restrict__ x,
                                               const u16* __restrict__ Wt,
                                               u16* __restrict__ Cout,
                                               float* __restrict__ statS,
                                               float* __restrict__ statQ) {
    __shared__ __align__(16) u16 lds[16384];   // A 16KB | B 16KB, then C bounce
    __shared__ float sblk[128], qblk[128];
    const int t = threadIdx.x;
    const int lane = t & 63, w = t >> 6, wr = w >> 1, wc = w & 1;
    const int b = blockIdx.z, i = blockIdx.y;   // lowres row
    if (t < 128) { sblk[t] = 0.f; qblk[t] = 0.f; }

    uint4 rb[4];
#pragma unroll
    for (int ii = 0; ii < 4; ++ii) {
        int s = ii * 256 + t;
        rb[ii] = *(const uint4*)(Wt + (long)(s >> 3) * 512 + (s & 7) * 8);
    }
    const int r15 = lane & 15, kq = lane >> 4;
    // staging coords: colblk = t&7 (col chunk), cc = (t>>3)&15 (channel), dy = t>>7
    const int colblk = t & 7, cc = (t >> 3) & 15, dy = t >> 7;
    const int kbase = cc * 4 + dy * 2;
    const int gG = kbase >> 3, e2 = (kbase & 7) * 2;

    f32x4 acc[4][4];
#pragma unroll
    for (int a2 = 0; a2 < 4; ++a2)
#pragma unroll
        for (int j2 = 0; j2 < 4; ++j2) acc[a2][j2] = (f32x4){0.f, 0.f, 0.f, 0.f};

    for (int k0 = 0; k0 < 512; k0 += 64) {
        const int c0 = k0 >> 2;
        const float* xp = x + (((long)(b * Cc + c0 + cc)) * Hh + (2 * i + dy)) * Wf;
        __syncthreads();
#pragma unroll
        for (int fi = 0; fi < 8; ++fi) {
            int col = fi * 32 + colblk * 4;
            float4 v = *(const float4*)(xp + col);
            int j0 = col >> 1;
            u32 p0 = (u32)f2bf(v.x) | ((u32)f2bf(v.y) << 16);
            u32 p1 = (u32)f2bf(v.z) | ((u32)f2bf(v.w) << 16);
            *(u32*)((char*)lds + j0 * 128 + 16 * (gG ^ (j0 & 7)) + e2) = p0;
            *(u32*)((char*)lds + (j0 + 1) * 128 + 16 * (gG ^ ((j0 + 1) & 7)) + e2) = p1;
        }
#pragma unroll
        for (int ii = 0; ii < 4; ++ii) {
            int s = ii * 256 + t;
            int row_ = s >> 3, ch_ = s & 7;
            *(uint4*)((char*)lds + 16384 + row_ * 128 + 16 * (ch_ ^ (row_ & 7))) = rb[ii];
        }
        __syncthreads();
        if (k0 + 64 < 512) {
#pragma unroll
            for (int ii = 0; ii < 4; ++ii) {
                int s = ii * 256 + t;
                rb[ii] = *(const uint4*)(Wt + (long)(s >> 3) * 512 + (k0 + 64) + (s & 7) * 8);
            }
        }
#pragma unroll
        for (int ks = 0; ks < 2; ++ks) {
            short8 af[4], bfv[4];
            const int ch = ks * 4 + kq;
#pragma unroll
            for (int mi = 0; mi < 4; ++mi) {
                int row = wr * 64 + mi * 16 + r15;
                af[mi] = *(const short8*)((const char*)lds + row * 128 + 16 * (ch ^ (row & 7)));
            }
#pragma unroll
            for (int ni = 0; ni < 4; ++ni) {
                int row = wc * 64 + ni * 16 + r15;
                bfv[ni] = *(const short8*)((const char*)lds + 16384 + row * 128 + 16 * (ch ^ (row & 7)));
            }
#pragma unroll
            for (int mi = 0; mi < 4; ++mi)
#pragma unroll
                for (int ni = 0; ni < 4; ++ni)
                    acc[mi][ni] = __builtin_amdgcn_mfma_f32_16x16x32_bf16(
                        af[mi], bfv[ni], acc[mi][ni], 0, 0, 0);
        }
    }
    __syncthreads();

    // bounce C (bf16) into lds: [row=px][col=o ^ swz]
#pragma unroll
    for (int mi = 0; mi < 4; ++mi)
#pragma unroll
        for (int ni = 0; ni < 4; ++ni)
#pragma unroll
            for (int r = 0; r < 4; ++r) {
                int row = wr * 64 + mi * 16 + kq * 4 + r;
                int col = wc * 64 + ni * 16 + r15;
                lds[row * 128 + (col ^ ((row & 7) << 3))] = f2bf(acc[mi][ni][r]);
            }
    // per-col (out-channel) stats
#pragma unroll
    for (int ni = 0; ni < 4; ++ni) {
        float s = 0.f, q2 = 0.f;
#pragma unroll
        for (int mi = 0; mi < 4; ++mi)
#pragma unroll
            for (int r = 0; r < 4; ++r) {
                float v = acc[mi][ni][r];
                s += v; q2 += v * v;
            }
        s += __shfl_down(s, 32); s += __shfl_down(s, 16);
        q2 += __shfl_down(q2, 32); q2 += __shfl_down(q2, 16);
        if (lane < 16) {
            int col = wc * 64 + ni * 16 + r15;
            atomicAdd(&sblk[col], s);
            atomicAdd(&qblk[col], q2);
        }
    }
    __syncthreads();
    // coalesced store
    {
        u16* Cb = Cout + (long)b * HW2 * 128;
        int row = t >> 1, half = (t & 1) * 64;
        int sx = (row & 7) << 3;
        long gbase = (long)(i * 128 + row) * 128;
#pragma unroll
        for (int q = 0; q < 8; ++q) {
            int c = half + q * 8;
            *(uint4*)(Cb + gbase + c) = *(const uint4*)(lds + row * 128 + (c ^ sx));
        }
    }
    if (t < 128) {
        atomicAdd(statS + (long)t * 16, sblk[t]);
        atomicAdd(statQ + (long)t * 16, qblk[t]);
    }
}

// ---- bf16 MFMA NT-GEMM (pw1/pw2). EPI: 1 LN-folded affine+gelu; 2 +bias+res --
template <int EPI>
__global__ __launch_bounds__(256) void k_mfma(const u16* __restrict__ A,
                                              const u16* __restrict__ Bw,
                                              u16* __restrict__ C,
                                              const float* __restrict__ bias,
                                              const u16* __restrict__ res,
                                              const float* __restrict__ wbv,
                                              const float* __restrict__ wgs,
                                              const float* __restrict__ lnS,
                                              const float* __restrict__ lnQ,
                                              int N, int K,
                                              long aBs, long bBs, long cBs) {
    __shared__ __align__(16) u16 lds[16384];
    __shared__ float sblk[128];
    __shared__ float lnred[2];
    const int t = threadIdx.x;
    const int lane = t & 63, w = t >> 6, wr = w >> 1, wc = w & 1;
    const int b = blockIdx.z;
    const int m0 = blockIdx.y * 128, n0 = blockIdx.x * 128;
    const u16* Ab = A + (long)b * aBs + (long)m0 * K;
    const u16* Bb = Bw + (long)b * bBs + (long)n0 * K;

    if (EPI == 1) {
        if (t < 64) {
            float s = lnS[((long)b * 64 + t) * 16];
            float q = lnQ[((long)b * 64 + t) * 16];
#pragma unroll
            for (int off = 32; off; off >>= 1) {
                s += __shfl_down(s, off);
                q += __shfl_down(q, off);
            }
            if (t == 0) { lnred[0] = s; lnred[1] = q; }
        }
        __syncthreads();
    }
    if (t < 128) {
        if (EPI == 1) {
            const float invN = 1.0f / 2097152.0f;
            float mu = lnred[0] * invN;
            float var = lnred[1] * invN - mu * mu;
            float rs2 = rsqrtf(var + 1e-5f);
            sblk[t] = bias[t] + wbv[t] - mu * rs2 * wgs[t];
        }
        if (EPI == 2) sblk[t] = bias[t];
    }

    uint4 ra[4], rb[4];
#define GLOAD(dst, base, k0)                                                     \
    {                                                                            \
        _Pragma("unroll")                                                        \
        for (int i = 0; i < 4; ++i) {                                            \
            int s = i * 256 + t;                                                 \
            dst[i] = *(const uint4*)(base + (long)(s >> 3) * K + (k0) + (s & 7) * 8); \
        }                                                                        \
    }
#define LWRITE(ofs, src)                                                         \
    {                                                                            \
        _Pragma("unroll")                                                        \
        for (int i = 0; i < 4; ++i) {                                            \
            int s = i * 256 + t;                                                 \
            int row_ = s >> 3, ch_ = s & 7;                                      \
            *(uint4*)((char*)lds + (ofs) + row_ * 128 + 16 * (ch_ ^ (row_ & 7))) = src[i]; \
        }                                                                        \
    }

    f32x4 acc[4][4];
#pragma unroll
    for (int i = 0; i < 4; ++i)
#pragma unroll
        for (int j = 0; j < 4; ++j) acc[i][j] = (f32x4){0.f, 0.f, 0.f, 0.f};

    GLOAD(ra, Ab, 0)
    GLOAD(rb, Bb, 0)
    const int r15 = lane & 15, kq = lane >> 4;
    for (int k0 = 0; k0 < K; k0 += 64) {
        __syncthreads();
        LWRITE(0, ra)
        LWRITE(16384, rb)
        __syncthreads();
        if (k0 + 64 < K) { GLOAD(ra, Ab, k0 + 64) GLOAD(rb, Bb, k0 + 64) }
#pragma unroll
        for (int ks = 0; ks < 2; ++ks) {
            short8 af[4], bfv[4];
            const int ch = ks * 4 + kq;
#pragma unroll
            for (int mi = 0; mi < 4; ++mi) {
                int row = wr * 64 + mi * 16 + r15;
                af[mi] = *(const short8*)((const char*)lds + row * 128 + 16 * (ch ^ (row & 7)));
            }
#pragma unroll
            for (int ni = 0; ni < 4; ++ni) {
                int row = wc * 64 + ni * 16 + r15;
                bfv[ni] = *(const short8*)((const char*)lds + 16384 + row * 128 + 16 * (ch ^ (row & 7)));
            }
#pragma unroll
            for (int mi = 0; mi < 4; ++mi)
#pragma unroll
                for (int ni = 0; ni < 4; ++ni)
                    acc[mi][ni] = __builtin_amdgcn_mfma_f32_16x16x32_bf16(
                        af[mi], bfv[ni], acc[mi][ni], 0, 0, 0);
        }
    }
    __syncthreads();
#pragma unroll
    for (int mi = 0; mi < 4; ++mi)
#pragma unroll
        for (int ni = 0; ni < 4; ++ni)
#pragma unroll
            for (int r = 0; r < 4; ++r) {
                int row = wr * 64 + mi * 16 + kq * 4 + r;
                int col = wc * 64 + ni * 16 + r15;
                lds[row * 128 + (col ^ ((row & 7) << 3))] = f2bf(acc[mi][ni][r]);
            }
    __syncthreads();
    u16* Cb = C + (long)b * cBs;
    {
        int row = t >> 1, half = (t & 1) * 64;
        int sx = (row & 7) << 3;
        long gbase = (long)(m0 + row) * N + n0;
        float rs = 1.f;
        if (EPI == 1) {
            const float invN = 1.0f / 2097152.0f;
            float mu = lnred[0] * invN;
            float var = lnred[1] * invN - mu * mu;
            rs = rsqrtf(var + 1e-5f);
        }
#pragma unroll
        for (int q = 0; q < 8; ++q) {
            int c = half + q * 8;
            uint4 raw = *(const uint4*)(lds + row * 128 + (c ^ sx));
            u16* pv = (u16*)&raw;
            uint4 rr;
            if (EPI == 2) rr = *(const uint4*)(res + (long)b * cBs + gbase + c);
            const u16* rv = (const u16*)&rr;
#pragma unroll
            for (int u = 0; u < 8; ++u) {
                float v = bf2f(pv[u]);
                if (EPI == 1) v = gelu_f(rs * v + sblk[c + u]);
                if (EPI == 2) v = v + sblk[c + u] + bf2f(rv[u]);
                pv[u] = f2bf(v);
            }
            *(uint4*)(Cb + gbase + c) = raw;
        }
    }
#undef GLOAD
#undef LWRITE
}

// ---- BN1 apply + gelu: bufA -> bufH (padded stats) ----
__global__ __launch_bounds__(256) void k_bn1_gelu(const u16* __restrict__ in,
                                                  u16* __restrict__ out,
                                                  const float* __restrict__ sum,
                                                  const float* __restrict__ sq,
                                                  const float* __restrict__ g,
                                                  const float* __restrict__ bb) {
    long e = ((long)blockIdx.x * 256 + threadIdx.x) * 8;
    int c0 = (int)(e & 127);
    uint4 raw = *(const uint4*)(in + e);
    u16* pv = (u16*)&raw;
    const float invN = 1.0f / 131072.0f;
#pragma unroll
    for (int u = 0; u < 8; ++u) {
        int c = c0 + u;
        float mu = sum[(long)c * 16] * invN;
        float var = sq[(long)c * 16] * invN - mu * mu;
        float rscale = rsqrtf(var + 1e-5f);
        float sc = rscale * g[c], sh = bb[c] - mu * sc;
        pv[u] = f2bf(gelu_f(bf2f(pv[u]) * sc + sh));
    }
    *(uint4*)(out + e) = raw;
}

// ---- depthwise 3x3 NHWC bf16 + fused LN stats (64 padded slots/batch) ----
__global__ __launch_bounds__(256) void k_dwconv(const u16* __restrict__ x,
                                                u16* __restrict__ y,
                                                const float* __restrict__ w,
                                                const float* __restrict__ bias,
                                                float* __restrict__ lnS,
                                                float* __restrict__ lnQ) {
    __shared__ float wl2[1152];
    const int t = threadIdx.x;
    for (int idx = t; idx < 1152; idx += 256) {
        int c = idx / 9, tap = idx - c * 9;
        wl2[tap * 128 + (c & 7) * 16 + (c >> 3)] = w[idx];
    }
    __syncthreads();
    const int cg = t & 15, jj = t >> 4;
    const int j = blockIdx.x * 16 + jj, i = blockIdx.y, b = blockIdx.z;
    const u16* xb = x + (long)b * HW2 * 128 + cg * 8;
    uint4 raw[3][3];
    const uint4 z4 = make_uint4(0u, 0u, 0u, 0u);
#pragma unroll
    for (int r = 0; r < 3; ++r) {
        int row = i - 1 + r;
#pragma unroll
        for (int q = 0; q < 3; ++q) {
            int col = j - 1 + q;
            bool ok = (row >= 0) & (row < H2) & (col >= 0) & (col < W2);
            raw[r][q] = ok ? *(const uint4*)(xb + ((long)row * W2 + col) * 128) : z4;
        }
    }
    float acc[8];
#pragma unroll
    for (int u = 0; u < 8; ++u) acc[u] = bias[cg * 8 + u];
#pragma unroll
    for (int r = 0; r < 3; ++r)
#pragma unroll
        for (int q = 0; q < 3; ++q) {
            const u16* pv = (const u16*)&raw[r][q];
            const int tap = r * 3 + q;
#pragma unroll
            for (int u = 0; u < 8; ++u)
                acc[u] = fmaf(bf2f(pv[u]), wl2[tap * 128 + u * 16 + cg], acc[u]);
        }
    uint4 outv; u16* ov = (u16*)&outv;
    float s = 0.f, q2 = 0.f;
#pragma unroll
    for (int u = 0; u < 8; ++u) {
        ov[u] = f2bf(acc[u]);
        s += acc[u]; q2 += acc[u] * acc[u];
    }
    *(uint4*)(y + ((long)b * HW2 + (long)i * W2 + j) * 128 + cg * 8) = outv;
#pragma unroll
    for (int off = 32; off; off >>= 1) {
        s += __shfl_down(s, off);
        q2 += __shfl_down(q2, off);
    }
    __shared__ float r1[4], r2[4];
    if ((t & 63) == 0) { r1[t >> 6] = s; r2[t >> 6] = q2; }
    __syncthreads();
    if (t == 0) {
        int slot = (blockIdx.y * 8 + blockIdx.x) & 63;
        atomicAdd(lnS + ((long)b * 64 + slot) * 16, r1[0] + r1[1] + r1[2] + r1[3]);
        atomicAdd(lnQ + ((long)b * 64 + slot) * 16, r2[0] + r2[1] + r2[2] + r2[3]);
    }
}

// ---- second moment M2 = Y^T Y (128x128) + col-sums; 128 blocks x 1024 px ----
__global__ __launch_bounds__(256) void k_moment(const u16* __restrict__ Y,
                                                float* __restrict__ M2,
                                                float* __restrict__ csum) {
    __shared__ __align__(16) u16 T[8192];       // [128 c][64 px] swizzled
    __shared__ float cred[16][16][8];           // 8 KB
    const int t = threadIdx.x;
    const int lane = t & 63, w = t >> 6, wr = w >> 1, wc = w & 1;
    const int r15 = lane & 15, kq = lane >> 4;
    const long px0 = (long)blockIdx.x * 1024;
    float cs[8] = {};

    f32x4 acc[4][4];
#pragma unroll
    for (int i = 0; i < 4; ++i)
#pragma unroll
        for (int j = 0; j < 4; ++j) acc[i][j] = (f32x4){0.f, 0.f, 0.f, 0.f};

    for (int it = 0; it < 16; ++it) {
        uint4 rv[4];
#pragma unroll
        for (int i = 0; i < 4; ++i) {
            int s = i * 256 + t;
            int px = s >> 4, ch8 = (s & 15) * 8;
            rv[i] = *(const uint4*)(Y + (px0 + it * 64 + px) * 128 + ch8);
        }
        // col-sum partials from registers (thread's 8 channels fixed = (t&15)*8)
#pragma unroll
        for (int i = 0; i < 4; ++i) {
            const u16* pv = (const u16*)&rv[i];
#pragma unroll
            for (int u = 0; u < 8; ++u) cs[u] += bf2f(pv[u]);
        }
        __syncthreads();
#pragma unroll
        for (int i = 0; i < 4; ++i) {
            int s = i * 256 + t;
            int px = s >> 4, ch8 = (s & 15) * 8;
            const u16* pv = (const u16*)&rv[i];
#pragma unroll
            for (int u = 0; u < 8; ++u) {
                int row = ch8 + u;
                T[row * 64 + 8 * ((px >> 3) ^ (row & 7)) + (px & 7)] = pv[u];
            }
        }
        __syncthreads();
#pragma unroll
        for (int ks = 0; ks < 2; ++ks) {
            const int ch = ks * 4 + kq;
            short8 af[4], bfv[4];
#pragma unroll
            for (int mi = 0; mi < 4; ++mi) {
                int row = wr * 64 + mi * 16 + r15;
                af[mi] = *(const short8*)(T + row * 64 + 8 * (ch ^ (row & 7)));
            }
#pragma unroll
            for (int ni = 0; ni < 4; ++ni) {
                int row = wc * 64 + ni * 16 + r15;
                bfv[ni] = *(const short8*)(T + row * 64 + 8 * (ch ^ (row & 7)));
            }
#pragma unroll
            for (int mi = 0; mi < 4; ++mi)
#pragma unroll
                for (int ni = 0; ni < 4; ++ni)
                    acc[mi][ni] = __builtin_amdgcn_mfma_f32_16x16x32_bf16(
                        af[mi], bfv[ni], acc[mi][ni], 0, 0, 0);
        }
    }
    // reduce col-sums: 16 member-threads per channel group
    {
        int g = t & 15, m = t >> 4;
#pragma unroll
        for (int u = 0; u < 8; ++u) cred[m][g][u] = cs[u];
    }
    __syncthreads();
    if (t < 128) {
        float s = 0.f;
#pragma unroll
        for (int m = 0; m < 16; ++m) s += cred[m][t >> 3][t & 7];
        atomicAdd(csum + (long)t * 16, s);
    }
#pragma unroll
    for (int mi = 0; mi < 4; ++mi)
#pragma unroll
        for (int ni = 0; ni < 4; ++ni)
#pragma unroll
            for (int r = 0; r < 4; ++r) {
                int row = wr * 64 + mi * 16 + kq * 4 + r;
                int col = wc * 64 + ni * 16 + r15;
                atomicAdd(M2 + row * 128 + col, acc[mi][ni][r]);
            }
}

// ---- combine: per-out-channel BN2 scale/shift ----
__global__ __launch_bounds__(128) void k_statcomb(const float* __restrict__ w_c2,
                                                  const float* __restrict__ M2,
                                                  const float* __restrict__ csum,
                                                  const float* __restrict__ g,
                                                  const float* __restrict__ bb,
                                                  float* __restrict__ scsh) {
    __shared__ float wl[128];
    __shared__ float red[2][2];
    const int o = blockIdx.x, c = threadIdx.x;
    wl[c] = w_c2[o * 128 + c];
    __syncthreads();
    const float* m2r = M2 + c * 128;
    float tmp = 0.f;
#pragma unroll
    for (int c2 = 0; c2 < 128; c2 += 4) {
        float4 m = *(const float4*)(m2r + c2);
        tmp += m.x * wl[c2] + m.y * wl[c2 + 1] + m.z * wl[c2 + 2] + m.w * wl[c2 + 3];
    }
    float s2p = wl[c] * tmp;
    float mup = wl[c] * csum[(long)c * 16];
#pragma unroll
    for (int off = 32; off; off >>= 1) {
        s2p += __shfl_down(s2p, off);
        mup += __shfl_down(mup, off);
    }
    if ((c & 63) == 0) { red[0][c >> 6] = s2p; red[1][c >> 6] = mup; }
    __syncthreads();
    if (c == 0) {
        float s2 = (red[0][0] + red[0][1]) / NPIX;
        float mu = (red[1][0] + red[1][1]) / NPIX;
        float var = s2 - mu * mu;
        float rs = rsqrtf(var + 1e-5f);
        float sc = g[o] * rs;
        scsh[o] = sc;
        scsh[512 + o] = bb[o] - mu * sc;
    }
}

// ---- conv2 + BN2 + GELU + IDWT -> out f32 NCHW ----
__global__ __launch_bounds__(256) void k_conv2_idwt(const u16* __restrict__ Y,
                                                    const u16* __restrict__ W,
                                                    const float* __restrict__ scsh,
                                                    float* __restrict__ out) {
    __shared__ __align__(16) u16 lA[16384];  // [2 chunk][128 row][64 k]
    __shared__ __align__(16) u16 lB[8192];   // [2 chunk][64 row][64 k]
    __shared__ float sparam[1024];
    const int t = threadIdx.x;
    const int lane = t & 63, w = t >> 6, wr = w >> 1, wc = w & 1;
    const int r15 = lane & 15, kq = lane >> 4;
    const int b = blockIdx.y, n0 = blockIdx.x;
#pragma unroll
    for (int u = 0; u < 4; ++u) sparam[t + u * 256] = scsh[t + u * 256];

    const u16* Yb = Y + ((long)b * HW2 + (long)n0 * 64) * 128;
    uint4 rb4[4], ra8[8];
#pragma unroll
    for (int i = 0; i < 4; ++i) {
        int s = i * 256 + t, row = s >> 4, seg = s & 15;
        rb4[i] = *(const uint4*)(Yb + (long)row * 128 + seg * 8);
    }
#define GLOADA(q)                                                                \
    {                                                                            \
        _Pragma("unroll")                                                        \
        for (int i = 0; i < 8; ++i) {                                            \
            int s = i * 256 + t, row = s >> 4, seg = s & 15;                     \
            ra8[i] = *(const uint4*)(W + (long)((q) * 128 + row) * 128 + seg * 8); \
        }                                                                        \
    }
#define LWRITEA()                                                                \
    {                                                                            \
        _Pragma("unroll")                                                        \
        for (int i = 0; i < 8; ++i) {                                            \
            int s = i * 256 + t, row = s >> 4, seg = s & 15;                     \
            *(uint4*)((char*)lA + (seg >> 3) * 16384 + row * 128 +               \
                      16 * ((seg & 7) ^ (row & 7))) = ra8[i];                    \
        }                                                                        \
    }
    GLOADA(0)
#pragma unroll
    for (int i = 0; i < 4; ++i) {
        int s = i * 256 + t, row = s >> 4, seg = s & 15;
        *(uint4*)((char*)lB + (seg >> 3) * 8192 + row * 128 +
                  16 * ((seg & 7) ^ (row & 7))) = rb4[i];
    }
    LWRITEA()
    __syncthreads();

    u32 sbp[4][4][2][2];
    for (int q = 0; q < 4; ++q) {
        f32x4 acc[4][2];
#pragma unroll
        for (int mi = 0; mi < 4; ++mi)
#pragma unroll
            for (int ni = 0; ni < 2; ++ni) acc[mi][ni] = (f32x4){0.f, 0.f, 0.f, 0.f};
#pragma unroll
        for (int chunk = 0; chunk < 2; ++chunk)
#pragma unroll
            for (int ks = 0; ks < 2; ++ks) {
                const int ch = ks * 4 + kq;
                short8 af[4], bfv[2];
#pragma unroll
                for (int mi = 0; mi < 4; ++mi) {
                    int row = wr * 64 + mi * 16 + r15;
                    af[mi] = *(const short8*)((const char*)lA + chunk * 16384 +
                                              row * 128 + 16 * (ch ^ (row & 7)));
                }
#pragma unroll
                for (int ni = 0; ni < 2; ++ni) {
                    int row = wc * 32 + ni * 16 + r15;
                    bfv[ni] = *(const short8*)((const char*)lB + chunk * 8192 +
                                               row * 128 + 16 * (ch ^ (row & 7)));
                }
#pragma unroll
                for (int mi = 0; mi < 4; ++mi)
#pragma unroll
                    for (int ni = 0; ni < 2; ++ni)
                        acc[mi][ni] = __builtin_amdgcn_mfma_f32_16x16x32_bf16(
                            af[mi], bfv[ni], acc[mi][ni], 0, 0, 0);
            }
        if (q < 3) GLOADA(q + 1)
#pragma unroll
        for (int mi = 0; mi < 4; ++mi)
#pragma unroll
            for (int ni = 0; ni < 2; ++ni)
#pragma unroll
                for (int rp = 0; rp < 2; ++rp) {
                    int c0 = q * 128 + wr * 64 + mi * 16 + kq * 4 + rp * 2;
                    float v0 = gelu_f(acc[mi][ni][rp * 2] * sparam[c0] + sparam[512 + c0]);
                    float v1 = gelu_f(acc[mi][ni][rp * 2 + 1] * sparam[c0 + 1] + sparam[512 + c0 + 1]);
                    sbp[q][mi][ni][rp] = (u32)f2bf(v0) | ((u32)f2bf(v1) << 16);
                }
        if (q < 3) {
            __syncthreads();
            LWRITEA()
            __syncthreads();
        }
    }
    const int i = n0 >> 1, jbase = (n0 & 1) * 64;
#pragma unroll
    for (int mi = 0; mi < 4; ++mi)
#pragma unroll
        for (int ni = 0; ni < 2; ++ni) {
            int j = jbase + wc * 32 + ni * 16 + r15;
#pragma unroll
            for (int rp = 0; rp < 2; ++rp) {
                u32 p0 = sbp[0][mi][ni][rp], p1 = sbp[1][mi][ni][rp];
                u32 p2 = sbp[2][mi][ni][rp], p3 = sbp[3][mi][ni][rp];
#pragma unroll
                for (int e = 0; e < 2; ++e) {
                    int c = wr * 64 + mi * 16 + kq * 4 + rp * 2 + e;
                    float ll = bf2f(e ? (u16)(p0 >> 16) : (u16)(p0 & 0xFFFF));
                    float lh = bf2f(e ? (u16)(p1 >> 16) : (u16)(p1 & 0xFFFF));
                    float hl = bf2f(e ? (u16)(p2 >> 16) : (u16)(p2 & 0xFFFF));
                    float hh = bf2f(e ? (u16)(p3 >> 16) : (u16)(p3 & 0xFFFF));
                    long ob = (((long)(b * Cc + c) * Hh + 2 * i) * Wf + 2 * j);
                    *(float2*)(out + ob) =
                        make_float2((ll + lh + hl + hh) * 0.5f, (ll + lh - hl - hh) * 0.5f);
                    *(float2*)(out + ob + Wf) =
                        make_float2((ll - lh + hl - hh) * 0.5f, (ll - lh - hl + hh) * 0.5f);
                }
            }
        }
#undef GLOADA
#undef LWRITEA
}

extern "C" void kernel_launch(void* const* d_in, const int* in_sizes, int n_in,
                              void* d_out, int out_size, void* d_ws, size_t ws_size,
                              hipStream_t stream) {
    const float* x     = (const float*)d_in[0];
    const float* w_c1  = (const float*)d_in[1];
    const float* bn1_g = (const float*)d_in[3];
    const float* bn1_b = (const float*)d_in[4];
    const float* dw_w  = (const float*)d_in[5];
    const float* dw_b  = (const float*)d_in[6];
    const float* gn_g  = (const float*)d_in[7];
    const float* gn_b  = (const float*)d_in[8];
    const float* pw1_w = (const float*)d_in[9];
    const float* pw1_b = (const float*)d_in[10];
    const float* pw2_w = (const float*)d_in[11];
    const float* pw2_b = (const float*)d_in[12];
    const float* w_c2  = (const float*)d_in[13];
    const float* bn2_g = (const float*)d_in[15];
    const float* bn2_b = (const float*)d_in[16];
    float* out = (float*)d_out;

    const size_t n128 = (size_t)Bq * Cc * HW2;
    u16* bufA = (u16*)d_ws;        // conv1 raw out [b][px][128]
    u16* bufH = bufA + n128;       // post BN1+gelu (= residual)
    u16* bufD = bufH + n128;       // dwconv raw out
    u16* bufP = bufD + n128;       // pw1 out
    u16* bufY = bufP + n128;       // pw2 out (= conv2 input)
    u16* wb   = bufY + n128;       // bf16 weights: W'c1|pw1g|pw2|w_c2
    float* stats = (float*)(wb + 163840);
    size_t need = (5 * n128 + 163840) * 2 + 41000 * 4;
    if (ws_size < need) return;

    float* bn1_sum = stats;            // 128 x16 padded
    float* bn1_sq  = stats + 2048;
    float* ln_sum  = stats + 4096;     // 8x64 x16 padded
    float* ln_sq   = stats + 12288;
    float* csum    = stats + 20480;    // 128 x16 padded
    float* M2      = stats + 22528;    // 128x128 dense
    float* scsh    = stats + 38912;    // 512 scale | 512 shift
    float* wbv     = stats + 39936;
    float* wgs     = stats + 40064;

    hipMemsetAsync(stats, 0, 38912 * sizeof(float), stream);

    // 0. weights -> bf16 (w_c1 with DWT folded; pw1 pre-scaled by gn_g)
    k_wconv<<<640, 256, 0, stream>>>(w_c1, pw1_w, pw2_w, w_c2, gn_g, wb);
    k_wvec<<<1, 128, 0, stream>>>(pw1_w, gn_g, gn_b, wbv, wgs);

    // 1. fused DWT + conv1 + BN1 stats (reads x directly)
    k_conv1<<<dim3(1, 128, 8), 256, 0, stream>>>(x, wb, bufA, bn1_sum, bn1_sq);

    // 2. BN1 apply + gelu -> bufH
    k_bn1_gelu<<<8192, 256, 0, stream>>>(bufA, bufH, bn1_sum, bn1_sq, bn1_g, bn1_b);

    // 3. depthwise 3x3 + fused LN stats
    k_dwconv<<<dim3(8, 128, 8), 256, 0, stream>>>(bufH, bufD, dw_w, dw_b, ln_sum, ln_sq);

    // 4. pw1 on RAW bufD, LN folded into weights/affine, + gelu
    k_mfma<1><<<dim3(1, 128, 8), 256, 0, stream>>>(
        bufD, wb + 65536, bufP, pw1_b, nullptr, wbv, wgs, ln_sum, ln_sq,
        128, 128, (long)HW2 * 128, 0, (long)HW2 * 128);

    // 5. pw2 + bias + residual -> bufY
    k_mfma<2><<<dim3(1, 128, 8), 256, 0, stream>>>(
        bufP, wb + 81920, bufY, pw2_b, bufH, nullptr, nullptr, nullptr, nullptr,
        128, 128, (long)HW2 * 128, 0, (long)HW2 * 128);

    // 6. BN2 stats via second moment
    k_moment<<<128, 256, 0, stream>>>(bufY, M2, csum);
    k_statcomb<<<512, 128, 0, stream>>>(w_c2, M2, csum, bn2_g, bn2_b, scsh);

    // 7. conv2 + BN2 + gelu + IDWT -> out
    k_conv2_idwt<<<dim3(256, 8), 256, 0, stream>>>(bufY, wb + 98304, scsh, out);
}

// Round 7
// 557.236 us; speedup vs baseline: 1.6539x; 1.0738x over previous
//
#include <hip/hip_runtime.h>
#include <hip/hip_bf16.h>

typedef unsigned short u16;
typedef unsigned int u32;
typedef __attribute__((ext_vector_type(8))) short short8;
typedef __attribute__((ext_vector_type(4))) float f32x4;

#define Bq 8
#define Cc 128
#define C4 512
#define Hh 256
#define Wf 256
#define H2 128
#define W2 128
#define HW2 16384
#define NPIX 131072.0f

// tanh-approx GELU: max abs err ~1e-3, well under the 0.134 budget
__device__ __forceinline__ float gelu_f(float x) {
    float u = 1.5957691216057308f * (x + 0.044715f * x * x * x);
    float t = 1.0f - 2.0f / (__expf(u) + 1.0f);
    return 0.5f * x * (1.0f + t);
}
__device__ __forceinline__ float bf2f(u16 u) {
    union { float f; u32 i; } v; v.i = ((u32)u) << 16; return v.f;
}
__device__ __forceinline__ u16 f2bf(float f) {
    union { float f; u32 i; } v; v.f = f;
    u32 r = v.i + 0x7FFFu + ((v.i >> 16) & 1u);
    return (u16)(r >> 16);
}

// ---- weights f32 -> bf16. w_c1 gets the DWT folded in (stride-2 2x2 conv):
__global__ __launch_bounds__(256) void k_wconv(const float* __restrict__ w_c1,
                                               const float* __restrict__ pw1,
                                               const float* __restrict__ pw2,
                                               const float* __restrict__ w_c2,
                                               const float* __restrict__ gn_g,
                                               u16* __restrict__ wb) {
    int i = blockIdx.x * 256 + threadIdx.x;   // 0..163839
    float v;
    if (i < 65536) {
        int o = i >> 9, kn = i & 511;
        int c = kn >> 2, dy = (kn >> 1) & 1, dx = kn & 1;
        float sdy = dy ? -1.f : 1.f, sdx = dx ? -1.f : 1.f;
        const float* wr = w_c1 + o * 512 + c;
        v = 0.5f * (wr[0] + sdy * wr[128] + sdx * wr[256] + sdy * sdx * wr[384]);
    } else if (i < 81920) v = pw1[i - 65536] * gn_g[(i - 65536) & 127];
    else if (i < 98304) v = pw2[i - 81920];
    else v = w_c2[i - 98304];
    wb[i] = f2bf(v);
}

// ---- LN-fold vectors: wgs[o]=sum_c w*g, wbv[o]=sum_c w*b ----
__global__ __launch_bounds__(128) void k_wvec(const float* __restrict__ pw1,
                                              const float* __restrict__ gg,
                                              const float* __restrict__ gb,
                                              float* __restrict__ wbv,
                                              float* __restrict__ wgs) {
    int o = threadIdx.x;
    float a = 0.f, bv = 0.f;
    for (int c = 0; c < 128; ++c) {
        float w = pw1[o * 128 + c];
        a += w * gg[c];
        bv += w * gb[c];
    }
    wgs[o] = a;
    wbv[o] = bv;
}

// ---- fused DWT+conv1+BN1-stats: reads x f32 NCHW directly ----
__global__ __launch_bounds__(256) void k_conv1(const float* __restrict__ x,
                                               const u16* __restrict__ Wt,
                                               u16* __restrict__ Cout,
                                               float* __restrict__ statS,
                                               float* __restrict__ statQ) {
    __shared__ __align__(16) u16 lds[16384];   // A 16KB | B 16KB, then C bounce
    __shared__ float sblk[128], qblk[128];
    const int t = threadIdx.x;
    const int lane = t & 63, w = t >> 6, wr = w >> 1, wc = w & 1;
    const int b = blockIdx.z, i = blockIdx.y;   // lowres row
    if (t < 128) { sblk[t] = 0.f; qblk[t] = 0.f; }

    uint4 rb[4];
#pragma unroll
    for (int ii = 0; ii < 4; ++ii) {
        int s = ii * 256 + t;
        rb[ii] = *(const uint4*)(Wt + (long)(s >> 3) * 512 + (s & 7) * 8);
    }
    const int r15 = lane & 15, kq = lane >> 4;
    const int colblk = t & 7, cc = (t >> 3) & 15, dy = t >> 7;
    const int kbase = cc * 4 + dy * 2;
    const int gG = kbase >> 3, e2 = (kbase & 7) * 2;

    f32x4 acc[4][4];
#pragma unroll
    for (int a2 = 0; a2 < 4; ++a2)
#pragma unroll
        for (int j2 = 0; j2 < 4; ++j2) acc[a2][j2] = (f32x4){0.f, 0.f, 0.f, 0.f};

    for (int k0 = 0; k0 < 512; k0 += 64) {
        const int c0 = k0 >> 2;
        const float* xp = x + (((long)(b * Cc + c0 + cc)) * Hh + (2 * i + dy)) * Wf;
        __syncthreads();
#pragma unroll
        for (int fi = 0; fi < 8; ++fi) {
            int col = fi * 32 + colblk * 4;
            float4 v = *(const float4*)(xp + col);
            int j0 = col >> 1;
            u32 p0 = (u32)f2bf(v.x) | ((u32)f2bf(v.y) << 16);
            u32 p1 = (u32)f2bf(v.z) | ((u32)f2bf(v.w) << 16);
            *(u32*)((char*)lds + j0 * 128 + 16 * (gG ^ (j0 & 7)) + e2) = p0;
            *(u32*)((char*)lds + (j0 + 1) * 128 + 16 * (gG ^ ((j0 + 1) & 7)) + e2) = p1;
        }
#pragma unroll
        for (int ii = 0; ii < 4; ++ii) {
            int s = ii * 256 + t;
            int row_ = s >> 3, ch_ = s & 7;
            *(uint4*)((char*)lds + 16384 + row_ * 128 + 16 * (ch_ ^ (row_ & 7))) = rb[ii];
        }
        __syncthreads();
        if (k0 + 64 < 512) {
#pragma unroll
            for (int ii = 0; ii < 4; ++ii) {
                int s = ii * 256 + t;
                rb[ii] = *(const uint4*)(Wt + (long)(s >> 3) * 512 + (k0 + 64) + (s & 7) * 8);
            }
        }
#pragma unroll
        for (int ks = 0; ks < 2; ++ks) {
            short8 af[4], bfv[4];
            const int ch = ks * 4 + kq;
#pragma unroll
            for (int mi = 0; mi < 4; ++mi) {
                int row = wr * 64 + mi * 16 + r15;
                af[mi] = *(const short8*)((const char*)lds + row * 128 + 16 * (ch ^ (row & 7)));
            }
#pragma unroll
            for (int ni = 0; ni < 4; ++ni) {
                int row = wc * 64 + ni * 16 + r15;
                bfv[ni] = *(const short8*)((const char*)lds + 16384 + row * 128 + 16 * (ch ^ (row & 7)));
            }
#pragma unroll
            for (int mi = 0; mi < 4; ++mi)
#pragma unroll
                for (int ni = 0; ni < 4; ++ni)
                    acc[mi][ni] = __builtin_amdgcn_mfma_f32_16x16x32_bf16(
                        af[mi], bfv[ni], acc[mi][ni], 0, 0, 0);
        }
    }
    __syncthreads();

#pragma unroll
    for (int mi = 0; mi < 4; ++mi)
#pragma unroll
        for (int ni = 0; ni < 4; ++ni)
#pragma unroll
            for (int r = 0; r < 4; ++r) {
                int row = wr * 64 + mi * 16 + kq * 4 + r;
                int col = wc * 64 + ni * 16 + r15;
                lds[row * 128 + (col ^ ((row & 7) << 3))] = f2bf(acc[mi][ni][r]);
            }
#pragma unroll
    for (int ni = 0; ni < 4; ++ni) {
        float s = 0.f, q2 = 0.f;
#pragma unroll
        for (int mi = 0; mi < 4; ++mi)
#pragma unroll
            for (int r = 0; r < 4; ++r) {
                float v = acc[mi][ni][r];
                s += v; q2 += v * v;
            }
        s += __shfl_down(s, 32); s += __shfl_down(s, 16);
        q2 += __shfl_down(q2, 32); q2 += __shfl_down(q2, 16);
        if (lane < 16) {
            int col = wc * 64 + ni * 16 + r15;
            atomicAdd(&sblk[col], s);
            atomicAdd(&qblk[col], q2);
        }
    }
    __syncthreads();
    {
        u16* Cb = Cout + (long)b * HW2 * 128;
        int row = t >> 1, half = (t & 1) * 64;
        int sx = (row & 7) << 3;
        long gbase = (long)(i * 128 + row) * 128;
#pragma unroll
        for (int q = 0; q < 8; ++q) {
            int c = half + q * 8;
            *(uint4*)(Cb + gbase + c) = *(const uint4*)(lds + row * 128 + (c ^ sx));
        }
    }
    if (t < 128) {
        atomicAdd(statS + (long)t * 16, sblk[t]);
        atomicAdd(statQ + (long)t * 16, qblk[t]);
    }
}

// ---- bf16 MFMA NT-GEMM (pw1/pw2). EPI: 1 LN-folded affine+gelu; 2 +bias+res --
template <int EPI>
__global__ __launch_bounds__(256) void k_mfma(const u16* __restrict__ A,
                                              const u16* __restrict__ Bw,
                                              u16* __restrict__ C,
                                              const float* __restrict__ bias,
                                              const u16* __restrict__ res,
                                              const float* __restrict__ wbv,
                                              const float* __restrict__ wgs,
                                              const float* __restrict__ lnS,
                                              const float* __restrict__ lnQ,
                                              int N, int K,
                                              long aBs, long bBs, long cBs) {
    __shared__ __align__(16) u16 lds[16384];
    __shared__ float sblk[128];
    __shared__ float lnred[2];
    const int t = threadIdx.x;
    const int lane = t & 63, w = t >> 6, wr = w >> 1, wc = w & 1;
    const int b = blockIdx.z;
    const int m0 = blockIdx.y * 128, n0 = blockIdx.x * 128;
    const u16* Ab = A + (long)b * aBs + (long)m0 * K;
    const u16* Bb = Bw + (long)b * bBs + (long)n0 * K;

    if (EPI == 1) {
        if (t < 64) {
            float s = lnS[((long)b * 64 + t) * 16];
            float q = lnQ[((long)b * 64 + t) * 16];
#pragma unroll
            for (int off = 32; off; off >>= 1) {
                s += __shfl_down(s, off);
                q += __shfl_down(q, off);
            }
            if (t == 0) { lnred[0] = s; lnred[1] = q; }
        }
        __syncthreads();
    }
    if (t < 128) {
        if (EPI == 1) {
            const float invN = 1.0f / 2097152.0f;
            float mu = lnred[0] * invN;
            float var = lnred[1] * invN - mu * mu;
            float rs2 = rsqrtf(var + 1e-5f);
            sblk[t] = bias[t] + wbv[t] - mu * rs2 * wgs[t];
        }
        if (EPI == 2) sblk[t] = bias[t];
    }

    uint4 ra[4], rb[4];
#define GLOAD(dst, base, k0)                                                     \
    {                                                                            \
        _Pragma("unroll")                                                        \
        for (int i = 0; i < 4; ++i) {                                            \
            int s = i * 256 + t;                                                 \
            dst[i] = *(const uint4*)(base + (long)(s >> 3) * K + (k0) + (s & 7) * 8); \
        }                                                                        \
    }
#define LWRITE(ofs, src)                                                         \
    {                                                                            \
        _Pragma("unroll")                                                        \
        for (int i = 0; i < 4; ++i) {                                            \
            int s = i * 256 + t;                                                 \
            int row_ = s >> 3, ch_ = s & 7;                                      \
            *(uint4*)((char*)lds + (ofs) + row_ * 128 + 16 * (ch_ ^ (row_ & 7))) = src[i]; \
        }                                                                        \
    }

    f32x4 acc[4][4];
#pragma unroll
    for (int i = 0; i < 4; ++i)
#pragma unroll
        for (int j = 0; j < 4; ++j) acc[i][j] = (f32x4){0.f, 0.f, 0.f, 0.f};

    GLOAD(ra, Ab, 0)
    GLOAD(rb, Bb, 0)
    const int r15 = lane & 15, kq = lane >> 4;
    for (int k0 = 0; k0 < K; k0 += 64) {
        __syncthreads();
        LWRITE(0, ra)
        LWRITE(16384, rb)
        __syncthreads();
        if (k0 + 64 < K) { GLOAD(ra, Ab, k0 + 64) GLOAD(rb, Bb, k0 + 64) }
#pragma unroll
        for (int ks = 0; ks < 2; ++ks) {
            short8 af[4], bfv[4];
            const int ch = ks * 4 + kq;
#pragma unroll
            for (int mi = 0; mi < 4; ++mi) {
                int row = wr * 64 + mi * 16 + r15;
                af[mi] = *(const short8*)((const char*)lds + row * 128 + 16 * (ch ^ (row & 7)));
            }
#pragma unroll
            for (int ni = 0; ni < 4; ++ni) {
                int row = wc * 64 + ni * 16 + r15;
                bfv[ni] = *(const short8*)((const char*)lds + 16384 + row * 128 + 16 * (ch ^ (row & 7)));
            }
#pragma unroll
            for (int mi = 0; mi < 4; ++mi)
#pragma unroll
                for (int ni = 0; ni < 4; ++ni)
                    acc[mi][ni] = __builtin_amdgcn_mfma_f32_16x16x32_bf16(
                        af[mi], bfv[ni], acc[mi][ni], 0, 0, 0);
        }
    }
    __syncthreads();
#pragma unroll
    for (int mi = 0; mi < 4; ++mi)
#pragma unroll
        for (int ni = 0; ni < 4; ++ni)
#pragma unroll
            for (int r = 0; r < 4; ++r) {
                int row = wr * 64 + mi * 16 + kq * 4 + r;
                int col = wc * 64 + ni * 16 + r15;
                lds[row * 128 + (col ^ ((row & 7) << 3))] = f2bf(acc[mi][ni][r]);
            }
    __syncthreads();
    u16* Cb = C + (long)b * cBs;
    {
        int row = t >> 1, half = (t & 1) * 64;
        int sx = (row & 7) << 3;
        long gbase = (long)(m0 + row) * N + n0;
        float rs = 1.f;
        if (EPI == 1) {
            const float invN = 1.0f / 2097152.0f;
            float mu = lnred[0] * invN;
            float var = lnred[1] * invN - mu * mu;
            rs = rsqrtf(var + 1e-5f);
        }
#pragma unroll
        for (int q = 0; q < 8; ++q) {
            int c = half + q * 8;
            uint4 raw = *(const uint4*)(lds + row * 128 + (c ^ sx));
            u16* pv = (u16*)&raw;
            uint4 rr;
            if (EPI == 2) rr = *(const uint4*)(res + (long)b * cBs + gbase + c);
            const u16* rv = (const u16*)&rr;
#pragma unroll
            for (int u = 0; u < 8; ++u) {
                float v = bf2f(pv[u]);
                if (EPI == 1) v = gelu_f(rs * v + sblk[c + u]);
                if (EPI == 2) v = v + sblk[c + u] + bf2f(rv[u]);
                pv[u] = f2bf(v);
            }
            *(uint4*)(Cb + gbase + c) = raw;
        }
    }
#undef GLOAD
#undef LWRITE
}

// ---- BN1 apply + gelu: bufA -> bufH (padded stats) ----
__global__ __launch_bounds__(256) void k_bn1_gelu(const u16* __restrict__ in,
                                                  u16* __restrict__ out,
                                                  const float* __restrict__ sum,
                                                  const float* __restrict__ sq,
                                                  const float* __restrict__ g,
                                                  const float* __restrict__ bb) {
    long e = ((long)blockIdx.x * 256 + threadIdx.x) * 8;
    int c0 = (int)(e & 127);
    uint4 raw = *(const uint4*)(in + e);
    u16* pv = (u16*)&raw;
    const float invN = 1.0f / 131072.0f;
#pragma unroll
    for (int u = 0; u < 8; ++u) {
        int c = c0 + u;
        float mu = sum[(long)c * 16] * invN;
        float var = sq[(long)c * 16] * invN - mu * mu;
        float rscale = rsqrtf(var + 1e-5f);
        float sc = rscale * g[c], sh = bb[c] - mu * sc;
        pv[u] = f2bf(gelu_f(bf2f(pv[u]) * sc + sh));
    }
    *(uint4*)(out + e) = raw;
}

// ---- depthwise 3x3 NHWC bf16 + fused LN stats (64 padded slots/batch) ----
__global__ __launch_bounds__(256) void k_dwconv(const u16* __restrict__ x,
                                                u16* __restrict__ y,
                                                const float* __restrict__ w,
                                                const float* __restrict__ bias,
                                                float* __restrict__ lnS,
                                                float* __restrict__ lnQ) {
    __shared__ float wl2[1152];
    const int t = threadIdx.x;
    for (int idx = t; idx < 1152; idx += 256) {
        int c = idx / 9, tap = idx - c * 9;
        wl2[tap * 128 + (c & 7) * 16 + (c >> 3)] = w[idx];
    }
    __syncthreads();
    const int cg = t & 15, jj = t >> 4;
    const int j = blockIdx.x * 16 + jj, i = blockIdx.y, b = blockIdx.z;
    const u16* xb = x + (long)b * HW2 * 128 + cg * 8;
    uint4 raw[3][3];
    const uint4 z4 = make_uint4(0u, 0u, 0u, 0u);
#pragma unroll
    for (int r = 0; r < 3; ++r) {
        int row = i - 1 + r;
#pragma unroll
        for (int q = 0; q < 3; ++q) {
            int col = j - 1 + q;
            bool ok = (row >= 0) & (row < H2) & (col >= 0) & (col < W2);
            raw[r][q] = ok ? *(const uint4*)(xb + ((long)row * W2 + col) * 128) : z4;
        }
    }
    float acc[8];
#pragma unroll
    for (int u = 0; u < 8; ++u) acc[u] = bias[cg * 8 + u];
#pragma unroll
    for (int r = 0; r < 3; ++r)
#pragma unroll
        for (int q = 0; q < 3; ++q) {
            const u16* pv = (const u16*)&raw[r][q];
            const int tap = r * 3 + q;
#pragma unroll
            for (int u = 0; u < 8; ++u)
                acc[u] = fmaf(bf2f(pv[u]), wl2[tap * 128 + u * 16 + cg], acc[u]);
        }
    uint4 outv; u16* ov = (u16*)&outv;
    float s = 0.f, q2 = 0.f;
#pragma unroll
    for (int u = 0; u < 8; ++u) {
        ov[u] = f2bf(acc[u]);
        s += acc[u]; q2 += acc[u] * acc[u];
    }
    *(uint4*)(y + ((long)b * HW2 + (long)i * W2 + j) * 128 + cg * 8) = outv;
#pragma unroll
    for (int off = 32; off; off >>= 1) {
        s += __shfl_down(s, off);
        q2 += __shfl_down(q2, off);
    }
    __shared__ float r1[4], r2[4];
    if ((t & 63) == 0) { r1[t >> 6] = s; r2[t >> 6] = q2; }
    __syncthreads();
    if (t == 0) {
        int slot = (blockIdx.y * 8 + blockIdx.x) & 63;
        atomicAdd(lnS + ((long)b * 64 + slot) * 16, r1[0] + r1[1] + r1[2] + r1[3]);
        atomicAdd(lnQ + ((long)b * 64 + slot) * 16, r2[0] + r2[1] + r2[2] + r2[3]);
    }
}

// ---- second moment M2 = Y^T Y (128x128) + col-sums; 128 blocks x 1024 px ----
__global__ __launch_bounds__(256) void k_moment(const u16* __restrict__ Y,
                                                float* __restrict__ M2,
                                                float* __restrict__ csum) {
    __shared__ __align__(16) u16 T[8192];
    __shared__ float cred[16][16][8];
    const int t = threadIdx.x;
    const int lane = t & 63, w = t >> 6, wr = w >> 1, wc = w & 1;
    const int r15 = lane & 15, kq = lane >> 4;
    const long px0 = (long)blockIdx.x * 1024;
    float cs[8] = {};

    f32x4 acc[4][4];
#pragma unroll
    for (int i = 0; i < 4; ++i)
#pragma unroll
        for (int j = 0; j < 4; ++j) acc[i][j] = (f32x4){0.f, 0.f, 0.f, 0.f};

    for (int it = 0; it < 16; ++it) {
        uint4 rv[4];
#pragma unroll
        for (int i = 0; i < 4; ++i) {
            int s = i * 256 + t;
            int px = s >> 4, ch8 = (s & 15) * 8;
            rv[i] = *(const uint4*)(Y + (px0 + it * 64 + px) * 128 + ch8);
        }
#pragma unroll
        for (int i = 0; i < 4; ++i) {
            const u16* pv = (const u16*)&rv[i];
#pragma unroll
            for (int u = 0; u < 8; ++u) cs[u] += bf2f(pv[u]);
        }
        __syncthreads();
#pragma unroll
        for (int i = 0; i < 4; ++i) {
            int s = i * 256 + t;
            int px = s >> 4, ch8 = (s & 15) * 8;
            const u16* pv = (const u16*)&rv[i];
#pragma unroll
            for (int u = 0; u < 8; ++u) {
                int row = ch8 + u;
                T[row * 64 + 8 * ((px >> 3) ^ (row & 7)) + (px & 7)] = pv[u];
            }
        }
        __syncthreads();
#pragma unroll
        for (int ks = 0; ks < 2; ++ks) {
            const int ch = ks * 4 + kq;
            short8 af[4], bfv[4];
#pragma unroll
            for (int mi = 0; mi < 4; ++mi) {
                int row = wr * 64 + mi * 16 + r15;
                af[mi] = *(const short8*)(T + row * 64 + 8 * (ch ^ (row & 7)));
            }
#pragma unroll
            for (int ni = 0; ni < 4; ++ni) {
                int row = wc * 64 + ni * 16 + r15;
                bfv[ni] = *(const short8*)(T + row * 64 + 8 * (ch ^ (row & 7)));
            }
#pragma unroll
            for (int mi = 0; mi < 4; ++mi)
#pragma unroll
                for (int ni = 0; ni < 4; ++ni)
                    acc[mi][ni] = __builtin_amdgcn_mfma_f32_16x16x32_bf16(
                        af[mi], bfv[ni], acc[mi][ni], 0, 0, 0);
        }
    }
    {
        int g = t & 15, m = t >> 4;
#pragma unroll
        for (int u = 0; u < 8; ++u) cred[m][g][u] = cs[u];
    }
    __syncthreads();
    if (t < 128) {
        float s = 0.f;
#pragma unroll
        for (int m = 0; m < 16; ++m) s += cred[m][t >> 3][t & 7];
        atomicAdd(csum + (long)t * 16, s);
    }
#pragma unroll
    for (int mi = 0; mi < 4; ++mi)
#pragma unroll
        for (int ni = 0; ni < 4; ++ni)
#pragma unroll
            for (int r = 0; r < 4; ++r) {
                int row = wr * 64 + mi * 16 + kq * 4 + r;
                int col = wc * 64 + ni * 16 + r15;
                atomicAdd(M2 + row * 128 + col, acc[mi][ni][r]);
            }
}

// ---- combine: per-out-channel BN2 scale/shift ----
__global__ __launch_bounds__(128) void k_statcomb(const float* __restrict__ w_c2,
                                                  const float* __restrict__ M2,
                                                  const float* __restrict__ csum,
                                                  const float* __restrict__ g,
                                                  const float* __restrict__ bb,
                                                  float* __restrict__ scsh) {
    __shared__ float wl[128];
    __shared__ float red[2][2];
    const int o = blockIdx.x, c = threadIdx.x;
    wl[c] = w_c2[o * 128 + c];
    __syncthreads();
    const float* m2r = M2 + c * 128;
    float tmp = 0.f;
#pragma unroll
    for (int c2 = 0; c2 < 128; c2 += 4) {
        float4 m = *(const float4*)(m2r + c2);
        tmp += m.x * wl[c2] + m.y * wl[c2 + 1] + m.z * wl[c2 + 2] + m.w * wl[c2 + 3];
    }
    float s2p = wl[c] * tmp;
    float mup = wl[c] * csum[(long)c * 16];
#pragma unroll
    for (int off = 32; off; off >>= 1) {
        s2p += __shfl_down(s2p, off);
        mup += __shfl_down(mup, off);
    }
    if ((c & 63) == 0) { red[0][c >> 6] = s2p; red[1][c >> 6] = mup; }
    __syncthreads();
    if (c == 0) {
        float s2 = (red[0][0] + red[0][1]) / NPIX;
        float mu = (red[1][0] + red[1][1]) / NPIX;
        float var = s2 - mu * mu;
        float rs = rsqrtf(var + 1e-5f);
        float sc = g[o] * rs;
        scsh[o] = sc;
        scsh[512 + o] = bb[o] - mu * sc;
    }
}

// ---- conv2 + BN2 + GELU + IDWT -> out f32 NCHW ----
// q-loop FULLY UNROLLED so sbp[][] is statically indexed (registers, not scratch)
__global__ __launch_bounds__(256, 2) void k_conv2_idwt(const u16* __restrict__ Y,
                                                       const u16* __restrict__ W,
                                                       const float* __restrict__ scsh,
                                                       float* __restrict__ out) {
    __shared__ __align__(16) u16 lA[16384];  // [2 chunk][128 row][64 k]
    __shared__ __align__(16) u16 lB[8192];   // [2 chunk][64 row][64 k]
    __shared__ float sparam[1024];
    const int t = threadIdx.x;
    const int lane = t & 63, w = t >> 6, wr = w >> 1, wc = w & 1;
    const int r15 = lane & 15, kq = lane >> 4;
    const int b = blockIdx.y, n0 = blockIdx.x;
#pragma unroll
    for (int u = 0; u < 4; ++u) sparam[t + u * 256] = scsh[t + u * 256];

    const u16* Yb = Y + ((long)b * HW2 + (long)n0 * 64) * 128;
    uint4 rb4[4], ra8[8];
#pragma unroll
    for (int i = 0; i < 4; ++i) {
        int s = i * 256 + t, row = s >> 4, seg = s & 15;
        rb4[i] = *(const uint4*)(Yb + (long)row * 128 + seg * 8);
    }
#define GLOADA(q)                                                                \
    {                                                                            \
        _Pragma("unroll")                                                        \
        for (int i = 0; i < 8; ++i) {                                            \
            int s = i * 256 + t, row = s >> 4, seg = s & 15;                     \
            ra8[i] = *(const uint4*)(W + (long)((q) * 128 + row) * 128 + seg * 8); \
        }                                                                        \
    }
#define LWRITEA()                                                                \
    {                                                                            \
        _Pragma("unroll")                                                        \
        for (int i = 0; i < 8; ++i) {                                            \
            int s = i * 256 + t, row = s >> 4, seg = s & 15;                     \
            *(uint4*)((char*)lA + (seg >> 3) * 16384 + row * 128 +               \
                      16 * ((seg & 7) ^ (row & 7))) = ra8[i];                    \
        }                                                                        \
    }
    GLOADA(0)
#pragma unroll
    for (int i = 0; i < 4; ++i) {
        int s = i * 256 + t, row = s >> 4, seg = s & 15;
        *(uint4*)((char*)lB + (seg >> 3) * 8192 + row * 128 +
                  16 * ((seg & 7) ^ (row & 7))) = rb4[i];
    }
    LWRITEA()
    __syncthreads();

    u32 sbp[4][4][2][2];
#pragma unroll
    for (int q = 0; q < 4; ++q) {
        f32x4 acc[4][2];
#pragma unroll
        for (int mi = 0; mi < 4; ++mi)
#pragma unroll
            for (int ni = 0; ni < 2; ++ni) acc[mi][ni] = (f32x4){0.f, 0.f, 0.f, 0.f};
#pragma unroll
        for (int chunk = 0; chunk < 2; ++chunk)
#pragma unroll
            for (int ks = 0; ks < 2; ++ks) {
                const int ch = ks * 4 + kq;
                short8 af[4], bfv[2];
#pragma unroll
                for (int mi = 0; mi < 4; ++mi) {
                    int row = wr * 64 + mi * 16 + r15;
                    af[mi] = *(const short8*)((const char*)lA + chunk * 16384 +
                                              row * 128 + 16 * (ch ^ (row & 7)));
                }
#pragma unroll
                for (int ni = 0; ni < 2; ++ni) {
                    int row = wc * 32 + ni * 16 + r15;
                    bfv[ni] = *(const short8*)((const char*)lB + chunk * 8192 +
                                               row * 128 + 16 * (ch ^ (row & 7)));
                }
#pragma unroll
                for (int mi = 0; mi < 4; ++mi)
#pragma unroll
                    for (int ni = 0; ni < 2; ++ni)
                        acc[mi][ni] = __builtin_amdgcn_mfma_f32_16x16x32_bf16(
                            af[mi], bfv[ni], acc[mi][ni], 0, 0, 0);
            }
        if (q < 3) GLOADA(q + 1)
#pragma unroll
        for (int mi = 0; mi < 4; ++mi)
#pragma unroll
            for (int ni = 0; ni < 2; ++ni)
#pragma unroll
                for (int rp = 0; rp < 2; ++rp) {
                    int c0 = q * 128 + wr * 64 + mi * 16 + kq * 4 + rp * 2;
                    float v0 = gelu_f(acc[mi][ni][rp * 2] * sparam[c0] + sparam[512 + c0]);
                    float v1 = gelu_f(acc[mi][ni][rp * 2 + 1] * sparam[c0 + 1] + sparam[512 + c0 + 1]);
                    sbp[q][mi][ni][rp] = (u32)f2bf(v0) | ((u32)f2bf(v1) << 16);
                }
        if (q < 3) {
            __syncthreads();
            LWRITEA()
            __syncthreads();
        }
    }
    const int i = n0 >> 1, jbase = (n0 & 1) * 64;
#pragma unroll
    for (int mi = 0; mi < 4; ++mi)
#pragma unroll
        for (int ni = 0; ni < 2; ++ni) {
            int j = jbase + wc * 32 + ni * 16 + r15;
#pragma unroll
            for (int rp = 0; rp < 2; ++rp) {
                u32 p0 = sbp[0][mi][ni][rp], p1 = sbp[1][mi][ni][rp];
                u32 p2 = sbp[2][mi][ni][rp], p3 = sbp[3][mi][ni][rp];
#pragma unroll
                for (int e = 0; e < 2; ++e) {
                    int c = wr * 64 + mi * 16 + kq * 4 + rp * 2 + e;
                    float ll = bf2f(e ? (u16)(p0 >> 16) : (u16)(p0 & 0xFFFF));
                    float lh = bf2f(e ? (u16)(p1 >> 16) : (u16)(p1 & 0xFFFF));
                    float hl = bf2f(e ? (u16)(p2 >> 16) : (u16)(p2 & 0xFFFF));
                    float hh = bf2f(e ? (u16)(p3 >> 16) : (u16)(p3 & 0xFFFF));
                    long ob = (((long)(b * Cc + c) * Hh + 2 * i) * Wf + 2 * j);
                    *(float2*)(out + ob) =
                        make_float2((ll + lh + hl + hh) * 0.5f, (ll + lh - hl - hh) * 0.5f);
                    *(float2*)(out + ob + Wf) =
                        make_float2((ll - lh + hl - hh) * 0.5f, (ll - lh - hl + hh) * 0.5f);
                }
            }
        }
#undef GLOADA
#undef LWRITEA
}

extern "C" void kernel_launch(void* const* d_in, const int* in_sizes, int n_in,
                              void* d_out, int out_size, void* d_ws, size_t ws_size,
                              hipStream_t stream) {
    const float* x     = (const float*)d_in[0];
    const float* w_c1  = (const float*)d_in[1];
    const float* bn1_g = (const float*)d_in[3];
    const float* bn1_b = (const float*)d_in[4];
    const float* dw_w  = (const float*)d_in[5];
    const float* dw_b  = (const float*)d_in[6];
    const float* gn_g  = (const float*)d_in[7];
    const float* gn_b  = (const float*)d_in[8];
    const float* pw1_w = (const float*)d_in[9];
    const float* pw1_b = (const float*)d_in[10];
    const float* pw2_w = (const float*)d_in[11];
    const float* pw2_b = (const float*)d_in[12];
    const float* w_c2  = (const float*)d_in[13];
    const float* bn2_g = (const float*)d_in[15];
    const float* bn2_b = (const float*)d_in[16];
    float* out = (float*)d_out;

    const size_t n128 = (size_t)Bq * Cc * HW2;
    u16* bufA = (u16*)d_ws;        // conv1 raw out [b][px][128]
    u16* bufH = bufA + n128;       // post BN1+gelu (= residual)
    u16* bufD = bufH + n128;       // dwconv raw out
    u16* bufP = bufD + n128;       // pw1 out
    u16* bufY = bufP + n128;       // pw2 out (= conv2 input)
    u16* wb   = bufY + n128;       // bf16 weights: W'c1|pw1g|pw2|w_c2
    float* stats = (float*)(wb + 163840);
    size_t need = (5 * n128 + 163840) * 2 + 41000 * 4;
    if (ws_size < need) return;

    float* bn1_sum = stats;            // 128 x16 padded
    float* bn1_sq  = stats + 2048;
    float* ln_sum  = stats + 4096;     // 8x64 x16 padded
    float* ln_sq   = stats + 12288;
    float* csum    = stats + 20480;    // 128 x16 padded
    float* M2      = stats + 22528;    // 128x128 dense
    float* scsh    = stats + 38912;    // 512 scale | 512 shift
    float* wbv     = stats + 39936;
    float* wgs     = stats + 40064;

    hipMemsetAsync(stats, 0, 38912 * sizeof(float), stream);

    // 0. weights -> bf16 (w_c1 with DWT folded; pw1 pre-scaled by gn_g)
    k_wconv<<<640, 256, 0, stream>>>(w_c1, pw1_w, pw2_w, w_c2, gn_g, wb);
    k_wvec<<<1, 128, 0, stream>>>(pw1_w, gn_g, gn_b, wbv, wgs);

    // 1. fused DWT + conv1 + BN1 stats (reads x directly)
    k_conv1<<<dim3(1, 128, 8), 256, 0, stream>>>(x, wb, bufA, bn1_sum, bn1_sq);

    // 2. BN1 apply + gelu -> bufH
    k_bn1_gelu<<<8192, 256, 0, stream>>>(bufA, bufH, bn1_sum, bn1_sq, bn1_g, bn1_b);

    // 3. depthwise 3x3 + fused LN stats
    k_dwconv<<<dim3(8, 128, 8), 256, 0, stream>>>(bufH, bufD, dw_w, dw_b, ln_sum, ln_sq);

    // 4. pw1 on RAW bufD, LN folded into weights/affine, + gelu
    k_mfma<1><<<dim3(1, 128, 8), 256, 0, stream>>>(
        bufD, wb + 65536, bufP, pw1_b, nullptr, wbv, wgs, ln_sum, ln_sq,
        128, 128, (long)HW2 * 128, 0, (long)HW2 * 128);

    // 5. pw2 + bias + residual -> bufY
    k_mfma<2><<<dim3(1, 128, 8), 256, 0, stream>>>(
        bufP, wb + 81920, bufY, pw2_b, bufH, nullptr, nullptr, nullptr, nullptr,
        128, 128, (long)HW2 * 128, 0, (long)HW2 * 128);

    // 6. BN2 stats via second moment
    k_moment<<<128, 256, 0, stream>>>(bufY, M2, csum);
    k_statcomb<<<512, 128, 0, stream>>>(w_c2, M2, csum, bn2_g, bn2_b, scsh);

    // 7. conv2 + BN2 + gelu + IDWT -> out
    k_conv2_idwt<<<dim3(256, 8), 256, 0, stream>>>(bufY, wb + 98304, scsh, out);
}

// Round 9
// 485.377 us; speedup vs baseline: 1.8987x; 1.1480x over previous
//
#include <hip/hip_runtime.h>
#include <hip/hip_bf16.h>

typedef unsigned short u16;
typedef unsigned int u32;
typedef __attribute__((ext_vector_type(8))) short short8;
typedef __attribute__((ext_vector_type(4))) float f32x4;

#define Bq 8
#define Cc 128
#define C4 512
#define Hh 256
#define Wf 256
#define H2 128
#define W2 128
#define HW2 16384
#define NPIX 131072.0f

// tanh-approx GELU: max abs err ~1e-3, well under the 0.134 budget
__device__ __forceinline__ float gelu_f(float x) {
    float u = 1.5957691216057308f * (x + 0.044715f * x * x * x);
    float t = 1.0f - 2.0f / (__expf(u) + 1.0f);
    return 0.5f * x * (1.0f + t);
}
__device__ __forceinline__ float bf2f(u16 u) {
    union { float f; u32 i; } v; v.i = ((u32)u) << 16; return v.f;
}
__device__ __forceinline__ u16 f2bf(float f) {
    union { float f; u32 i; } v; v.f = f;
    u32 r = v.i + 0x7FFFu + ((v.i >> 16) & 1u);
    return (u16)(r >> 16);
}

// ---- weights f32 -> bf16. w_c1 gets the DWT folded in (stride-2 2x2 conv) ----
__global__ __launch_bounds__(256) void k_wconv(const float* __restrict__ w_c1,
                                               const float* __restrict__ pw1,
                                               const float* __restrict__ pw2,
                                               const float* __restrict__ w_c2,
                                               const float* __restrict__ gn_g,
                                               u16* __restrict__ wb) {
    int i = blockIdx.x * 256 + threadIdx.x;   // 0..163839
    float v;
    if (i < 65536) {
        int o = i >> 9, kn = i & 511;
        int c = kn >> 2, dy = (kn >> 1) & 1, dx = kn & 1;
        float sdy = dy ? -1.f : 1.f, sdx = dx ? -1.f : 1.f;
        const float* wr = w_c1 + o * 512 + c;
        v = 0.5f * (wr[0] + sdy * wr[128] + sdx * wr[256] + sdy * sdx * wr[384]);
    } else if (i < 81920) v = pw1[i - 65536] * gn_g[(i - 65536) & 127];
    else if (i < 98304) v = pw2[i - 81920];
    else v = w_c2[i - 98304];
    wb[i] = f2bf(v);
}

// ---- LN-fold vectors: wgs[o]=sum_c w*g, wbv[o]=sum_c w*b ----
__global__ __launch_bounds__(128) void k_wvec(const float* __restrict__ pw1,
                                              const float* __restrict__ gg,
                                              const float* __restrict__ gb,
                                              float* __restrict__ wbv,
                                              float* __restrict__ wgs) {
    int o = threadIdx.x;
    float a = 0.f, bv = 0.f;
    for (int c = 0; c < 128; ++c) {
        float w = pw1[o * 128 + c];
        a += w * gg[c];
        bv += w * gb[c];
    }
    wgs[o] = a;
    wbv[o] = bv;
}

// ---- fused DWT+conv1+BN1-stats: reads x f32 NCHW directly ----
__global__ __launch_bounds__(256) void k_conv1(const float* __restrict__ x,
                                               const u16* __restrict__ Wt,
                                               u16* __restrict__ Cout,
                                               float* __restrict__ statS,
                                               float* __restrict__ statQ) {
    __shared__ __align__(16) u16 lds[16384];   // A 16KB | B 16KB, then C bounce
    __shared__ float sblk[128], qblk[128];
    const int t = threadIdx.x;
    const int lane = t & 63, w = t >> 6, wr = w >> 1, wc = w & 1;
    const int b = blockIdx.z, i = blockIdx.y;   // lowres row
    if (t < 128) { sblk[t] = 0.f; qblk[t] = 0.f; }

    uint4 rb[4];
#pragma unroll
    for (int ii = 0; ii < 4; ++ii) {
        int s = ii * 256 + t;
        rb[ii] = *(const uint4*)(Wt + (long)(s >> 3) * 512 + (s & 7) * 8);
    }
    const int r15 = lane & 15, kq = lane >> 4;
    const int colblk = t & 7, cc = (t >> 3) & 15, dy = t >> 7;
    const int kbase = cc * 4 + dy * 2;
    const int gG = kbase >> 3, e2 = (kbase & 7) * 2;

    f32x4 acc[4][4];
#pragma unroll
    for (int a2 = 0; a2 < 4; ++a2)
#pragma unroll
        for (int j2 = 0; j2 < 4; ++j2) acc[a2][j2] = (f32x4){0.f, 0.f, 0.f, 0.f};

    for (int k0 = 0; k0 < 512; k0 += 64) {
        const int c0 = k0 >> 2;
        const float* xp = x + (((long)(b * Cc + c0 + cc)) * Hh + (2 * i + dy)) * Wf;
        __syncthreads();
#pragma unroll
        for (int fi = 0; fi < 8; ++fi) {
            int col = fi * 32 + colblk * 4;
            float4 v = *(const float4*)(xp + col);
            int j0 = col >> 1;
            u32 p0 = (u32)f2bf(v.x) | ((u32)f2bf(v.y) << 16);
            u32 p1 = (u32)f2bf(v.z) | ((u32)f2bf(v.w) << 16);
            *(u32*)((char*)lds + j0 * 128 + 16 * (gG ^ (j0 & 7)) + e2) = p0;
            *(u32*)((char*)lds + (j0 + 1) * 128 + 16 * (gG ^ ((j0 + 1) & 7)) + e2) = p1;
        }
#pragma unroll
        for (int ii = 0; ii < 4; ++ii) {
            int s = ii * 256 + t;
            int row_ = s >> 3, ch_ = s & 7;
            *(uint4*)((char*)lds + 16384 + row_ * 128 + 16 * (ch_ ^ (row_ & 7))) = rb[ii];
        }
        __syncthreads();
        if (k0 + 64 < 512) {
#pragma unroll
            for (int ii = 0; ii < 4; ++ii) {
                int s = ii * 256 + t;
                rb[ii] = *(const uint4*)(Wt + (long)(s >> 3) * 512 + (k0 + 64) + (s & 7) * 8);
            }
        }
#pragma unroll
        for (int ks = 0; ks < 2; ++ks) {
            short8 af[4], bfv[4];
            const int ch = ks * 4 + kq;
#pragma unroll
            for (int mi = 0; mi < 4; ++mi) {
                int row = wr * 64 + mi * 16 + r15;
                af[mi] = *(const short8*)((const char*)lds + row * 128 + 16 * (ch ^ (row & 7)));
            }
#pragma unroll
            for (int ni = 0; ni < 4; ++ni) {
                int row = wc * 64 + ni * 16 + r15;
                bfv[ni] = *(const short8*)((const char*)lds + 16384 + row * 128 + 16 * (ch ^ (row & 7)));
            }
#pragma unroll
            for (int mi = 0; mi < 4; ++mi)
#pragma unroll
                for (int ni = 0; ni < 4; ++ni)
                    acc[mi][ni] = __builtin_amdgcn_mfma_f32_16x16x32_bf16(
                        af[mi], bfv[ni], acc[mi][ni], 0, 0, 0);
        }
    }
    __syncthreads();

#pragma unroll
    for (int mi = 0; mi < 4; ++mi)
#pragma unroll
        for (int ni = 0; ni < 4; ++ni)
#pragma unroll
            for (int r = 0; r < 4; ++r) {
                int row = wr * 64 + mi * 16 + kq * 4 + r;
                int col = wc * 64 + ni * 16 + r15;
                lds[row * 128 + (col ^ ((row & 7) << 3))] = f2bf(acc[mi][ni][r]);
            }
#pragma unroll
    for (int ni = 0; ni < 4; ++ni) {
        float s = 0.f, q2 = 0.f;
#pragma unroll
        for (int mi = 0; mi < 4; ++mi)
#pragma unroll
            for (int r = 0; r < 4; ++r) {
                float v = acc[mi][ni][r];
                s += v; q2 += v * v;
            }
        s += __shfl_down(s, 32); s += __shfl_down(s, 16);
        q2 += __shfl_down(q2, 32); q2 += __shfl_down(q2, 16);
        if (lane < 16) {
            int col = wc * 64 + ni * 16 + r15;
            atomicAdd(&sblk[col], s);
            atomicAdd(&qblk[col], q2);
        }
    }
    __syncthreads();
    {
        u16* Cb = Cout + (long)b * HW2 * 128;
        int row = t >> 1, half = (t & 1) * 64;
        int sx = (row & 7) << 3;
        long gbase = (long)(i * 128 + row) * 128;
#pragma unroll
        for (int q = 0; q < 8; ++q) {
            int c = half + q * 8;
            *(uint4*)(Cb + gbase + c) = *(const uint4*)(lds + row * 128 + (c ^ sx));
        }
    }
    if (t < 128) {
        atomicAdd(statS + (long)t * 16, sblk[t]);
        atomicAdd(statQ + (long)t * 16, qblk[t]);
    }
}

// ---- BN1 apply + gelu: bufA -> bufH (padded stats) ----
__global__ __launch_bounds__(256) void k_bn1_gelu(const u16* __restrict__ in,
                                                  u16* __restrict__ out,
                                                  const float* __restrict__ sum,
                                                  const float* __restrict__ sq,
                                                  const float* __restrict__ g,
                                                  const float* __restrict__ bb) {
    long e = ((long)blockIdx.x * 256 + threadIdx.x) * 8;
    int c0 = (int)(e & 127);
    uint4 raw = *(const uint4*)(in + e);
    u16* pv = (u16*)&raw;
    const float invN = 1.0f / 131072.0f;
#pragma unroll
    for (int u = 0; u < 8; ++u) {
        int c = c0 + u;
        float mu = sum[(long)c * 16] * invN;
        float var = sq[(long)c * 16] * invN - mu * mu;
        float rscale = rsqrtf(var + 1e-5f);
        float sc = rscale * g[c], sh = bb[c] - mu * sc;
        pv[u] = f2bf(gelu_f(bf2f(pv[u]) * sc + sh));
    }
    *(uint4*)(out + e) = raw;
}

// ---- depthwise 3x3 NHWC bf16 + fused LN stats (64 padded slots/batch) ----
__global__ __launch_bounds__(256) void k_dwconv(const u16* __restrict__ x,
                                                u16* __restrict__ y,
                                                const float* __restrict__ w,
                                                const float* __restrict__ bias,
                                                float* __restrict__ lnS,
                                                float* __restrict__ lnQ) {
    __shared__ float wl2[1152];
    const int t = threadIdx.x;
    for (int idx = t; idx < 1152; idx += 256) {
        int c = idx / 9, tap = idx - c * 9;
        wl2[tap * 128 + (c & 7) * 16 + (c >> 3)] = w[idx];
    }
    __syncthreads();
    const int cg = t & 15, jj = t >> 4;
    const int j = blockIdx.x * 16 + jj, i = blockIdx.y, b = blockIdx.z;
    const u16* xb = x + (long)b * HW2 * 128 + cg * 8;
    uint4 raw[3][3];
    const uint4 z4 = make_uint4(0u, 0u, 0u, 0u);
#pragma unroll
    for (int r = 0; r < 3; ++r) {
        int row = i - 1 + r;
#pragma unroll
        for (int q = 0; q < 3; ++q) {
            int col = j - 1 + q;
            bool ok = (row >= 0) & (row < H2) & (col >= 0) & (col < W2);
            raw[r][q] = ok ? *(const uint4*)(xb + ((long)row * W2 + col) * 128) : z4;
        }
    }
    float acc[8];
#pragma unroll
    for (int u = 0; u < 8; ++u) acc[u] = bias[cg * 8 + u];
#pragma unroll
    for (int r = 0; r < 3; ++r)
#pragma unroll
        for (int q = 0; q < 3; ++q) {
            const u16* pv = (const u16*)&raw[r][q];
            const int tap = r * 3 + q;
#pragma unroll
            for (int u = 0; u < 8; ++u)
                acc[u] = fmaf(bf2f(pv[u]), wl2[tap * 128 + u * 16 + cg], acc[u]);
        }
    uint4 outv; u16* ov = (u16*)&outv;
    float s = 0.f, q2 = 0.f;
#pragma unroll
    for (int u = 0; u < 8; ++u) {
        ov[u] = f2bf(acc[u]);
        s += acc[u]; q2 += acc[u] * acc[u];
    }
    *(uint4*)(y + ((long)b * HW2 + (long)i * W2 + j) * 128 + cg * 8) = outv;
#pragma unroll
    for (int off = 32; off; off >>= 1) {
        s += __shfl_down(s, off);
        q2 += __shfl_down(q2, off);
    }
    __shared__ float r1[4], r2[4];
    if ((t & 63) == 0) { r1[t >> 6] = s; r2[t >> 6] = q2; }
    __syncthreads();
    if (t == 0) {
        int slot = (blockIdx.y * 8 + blockIdx.x) & 63;
        atomicAdd(lnS + ((long)b * 64 + slot) * 16, r1[0] + r1[1] + r1[2] + r1[3]);
        atomicAdd(lnQ + ((long)b * 64 + slot) * 16, r2[0] + r2[1] + r2[2] + r2[3]);
    }
}

// ---- fused MLP: pw1 (LN-folded affine + gelu) then pw2 (+bias +residual) ----
// One 128px x 128ch tile per block; intermediate lives only in LDS.
__global__ __launch_bounds__(256) void k_mlp(const u16* __restrict__ D,
                                             const u16* __restrict__ Wp1,
                                             const u16* __restrict__ Wp2,
                                             const float* __restrict__ b1,
                                             const float* __restrict__ b2,
                                             const u16* __restrict__ resH,
                                             u16* __restrict__ Yout,
                                             const float* __restrict__ lnS,
                                             const float* __restrict__ lnQ,
                                             const float* __restrict__ wbv,
                                             const float* __restrict__ wgs) {
    __shared__ __align__(16) u16 lA[16384];   // [2 chunk][128 row][64 k]
    __shared__ __align__(16) u16 lB[16384];
    __shared__ float s1[128], s2[128], lnred[2];
    const int t = threadIdx.x;
    const int lane = t & 63, w = t >> 6, wr = w >> 1, wc = w & 1;
    const int r15 = lane & 15, kq = lane >> 4;
    const int b = blockIdx.z, m0 = blockIdx.y * 128;

    if (t < 64) {
        float s = lnS[((long)b * 64 + t) * 16];
        float q = lnQ[((long)b * 64 + t) * 16];
#pragma unroll
        for (int off = 32; off; off >>= 1) {
            s += __shfl_down(s, off);
            q += __shfl_down(q, off);
        }
        if (t == 0) { lnred[0] = s; lnred[1] = q; }
    }
    __syncthreads();
    const float invN = 1.0f / 2097152.0f;
    float mu = lnred[0] * invN;
    float var = lnred[1] * invN - mu * mu;
    const float rs = rsqrtf(var + 1e-5f);
    if (t < 128) {
        s1[t] = b1[t] + wbv[t] - mu * rs * wgs[t];
        s2[t] = b2[t];
    }

    const u16* Ab = D + ((long)b * HW2 + m0) * 128;
    uint4 ga[8], gb[8];
#pragma unroll
    for (int i = 0; i < 8; ++i) {
        int s = i * 256 + t, row = s >> 4, seg = s & 15;
        ga[i] = *(const uint4*)(Ab + (long)row * 128 + seg * 8);
        gb[i] = *(const uint4*)(Wp1 + (long)row * 128 + seg * 8);
    }
#pragma unroll
    for (int i = 0; i < 8; ++i) {
        int s = i * 256 + t, row = s >> 4, seg = s & 15;
        int off = (seg >> 3) * 16384 + row * 128 + 16 * ((seg & 7) ^ (row & 7));
        *(uint4*)((char*)lA + off) = ga[i];
        *(uint4*)((char*)lB + off) = gb[i];
    }
    __syncthreads();

    f32x4 acc[4][4];
#pragma unroll
    for (int i = 0; i < 4; ++i)
#pragma unroll
        for (int j = 0; j < 4; ++j) acc[i][j] = (f32x4){0.f, 0.f, 0.f, 0.f};
#pragma unroll
    for (int chunk = 0; chunk < 2; ++chunk)
#pragma unroll
        for (int ks = 0; ks < 2; ++ks) {
            const int ch = ks * 4 + kq;
            short8 af[4], bfv[4];
#pragma unroll
            for (int mi = 0; mi < 4; ++mi) {
                int row = wr * 64 + mi * 16 + r15;
                af[mi] = *(const short8*)((const char*)lA + chunk * 16384 +
                                          row * 128 + 16 * (ch ^ (row & 7)));
            }
#pragma unroll
            for (int ni = 0; ni < 4; ++ni) {
                int row = wc * 64 + ni * 16 + r15;
                bfv[ni] = *(const short8*)((const char*)lB + chunk * 16384 +
                                           row * 128 + 16 * (ch ^ (row & 7)));
            }
#pragma unroll
            for (int mi = 0; mi < 4; ++mi)
#pragma unroll
                for (int ni = 0; ni < 4; ++ni)
                    acc[mi][ni] = __builtin_amdgcn_mfma_f32_16x16x32_bf16(
                        af[mi], bfv[ni], acc[mi][ni], 0, 0, 0);
        }
    // prefetch pw2 weights while GEMM1 drains
#pragma unroll
    for (int i = 0; i < 8; ++i) {
        int s = i * 256 + t, row = s >> 4, seg = s & 15;
        gb[i] = *(const uint4*)(Wp2 + (long)row * 128 + seg * 8);
    }
    __syncthreads();   // all lA/lB reads complete

    // bounce1: gelu(rs*acc + s1[ch]) -> lA in GEMM-A k-major layout (k = ch)
#pragma unroll
    for (int mi = 0; mi < 4; ++mi)
#pragma unroll
        for (int ni = 0; ni < 4; ++ni)
#pragma unroll
            for (int r = 0; r < 4; ++r) {
                int row = wr * 64 + mi * 16 + kq * 4 + r;   // px
                int col = wc * 64 + ni * 16 + r15;          // ch (= k of GEMM2)
                float v = gelu_f(rs * acc[mi][ni][r] + s1[col]);
                lA[(col >> 6) * 8192 + row * 64 +
                   8 * (((col >> 3) & 7) ^ (row & 7)) + (col & 7)] = f2bf(v);
            }
#pragma unroll
    for (int i = 0; i < 8; ++i) {
        int s = i * 256 + t, row = s >> 4, seg = s & 15;
        int off = (seg >> 3) * 16384 + row * 128 + 16 * ((seg & 7) ^ (row & 7));
        *(uint4*)((char*)lB + off) = gb[i];
    }
    __syncthreads();

    // GEMM2
#pragma unroll
    for (int i = 0; i < 4; ++i)
#pragma unroll
        for (int j = 0; j < 4; ++j) acc[i][j] = (f32x4){0.f, 0.f, 0.f, 0.f};
#pragma unroll
    for (int chunk = 0; chunk < 2; ++chunk)
#pragma unroll
        for (int ks = 0; ks < 2; ++ks) {
            const int ch = ks * 4 + kq;
            short8 af[4], bfv[4];
#pragma unroll
            for (int mi = 0; mi < 4; ++mi) {
                int row = wr * 64 + mi * 16 + r15;
                af[mi] = *(const short8*)((const char*)lA + chunk * 16384 +
                                          row * 128 + 16 * (ch ^ (row & 7)));
            }
#pragma unroll
            for (int ni = 0; ni < 4; ++ni) {
                int row = wc * 64 + ni * 16 + r15;
                bfv[ni] = *(const short8*)((const char*)lB + chunk * 16384 +
                                           row * 128 + 16 * (ch ^ (row & 7)));
            }
#pragma unroll
            for (int mi = 0; mi < 4; ++mi)
#pragma unroll
                for (int ni = 0; ni < 4; ++ni)
                    acc[mi][ni] = __builtin_amdgcn_mfma_f32_16x16x32_bf16(
                        af[mi], bfv[ni], acc[mi][ni], 0, 0, 0);
        }
    __syncthreads();   // lA reads done; reuse flat for bounce2

#pragma unroll
    for (int mi = 0; mi < 4; ++mi)
#pragma unroll
        for (int ni = 0; ni < 4; ++ni)
#pragma unroll
            for (int r = 0; r < 4; ++r) {
                int row = wr * 64 + mi * 16 + kq * 4 + r;
                int col = wc * 64 + ni * 16 + r15;
                lA[row * 128 + (col ^ ((row & 7) << 3))] = f2bf(acc[mi][ni][r]);
            }
    __syncthreads();

    const u16* Rb = resH + ((long)b * HW2 + m0) * 128;
    u16* Cb = Yout + ((long)b * HW2 + m0) * 128;
    {
        int row = t >> 1, half = (t & 1) * 64;
        int sx = (row & 7) << 3;
#pragma unroll
        for (int q = 0; q < 8; ++q) {
            int c = half + q * 8;
            uint4 raw = *(const uint4*)(lA + row * 128 + (c ^ sx));
            uint4 rr = *(const uint4*)(Rb + (long)row * 128 + c);
            u16* pv = (u16*)&raw;
            const u16* rv = (const u16*)&rr;
#pragma unroll
            for (int u = 0; u < 8; ++u)
                pv[u] = f2bf(bf2f(pv[u]) + s2[c + u] + bf2f(rv[u]));
            *(uint4*)(Cb + (long)row * 128 + c) = raw;
        }
    }
}

// ---- second moment M2 = Y^T Y (128x128) + col-sums; 128 blocks x 1024 px ----
__global__ __launch_bounds__(256) void k_moment(const u16* __restrict__ Y,
                                                float* __restrict__ M2,
                                                float* __restrict__ csum) {
    __shared__ __align__(16) u16 T[8192];
    __shared__ float cred[16][16][8];
    const int t = threadIdx.x;
    const int lane = t & 63, w = t >> 6, wr = w >> 1, wc = w & 1;
    const int r15 = lane & 15, kq = lane >> 4;
    const long px0 = (long)blockIdx.x * 1024;
    float cs[8] = {};

    f32x4 acc[4][4];
#pragma unroll
    for (int i = 0; i < 4; ++i)
#pragma unroll
        for (int j = 0; j < 4; ++j) acc[i][j] = (f32x4){0.f, 0.f, 0.f, 0.f};

    for (int it = 0; it < 16; ++it) {
        uint4 rv[4];
#pragma unroll
        for (int i = 0; i < 4; ++i) {
            int s = i * 256 + t;
            int px = s >> 4, ch8 = (s & 15) * 8;
            rv[i] = *(const uint4*)(Y + (px0 + it * 64 + px) * 128 + ch8);
        }
#pragma unroll
        for (int i = 0; i < 4; ++i) {
            const u16* pv = (const u16*)&rv[i];
#pragma unroll
            for (int u = 0; u < 8; ++u) cs[u] += bf2f(pv[u]);
        }
        __syncthreads();
#pragma unroll
        for (int i = 0; i < 4; ++i) {
            int s = i * 256 + t;
            int px = s >> 4, ch8 = (s & 15) * 8;
            const u16* pv = (const u16*)&rv[i];
#pragma unroll
            for (int u = 0; u < 8; ++u) {
                int row = ch8 + u;
                T[row * 64 + 8 * ((px >> 3) ^ (row & 7)) + (px & 7)] = pv[u];
            }
        }
        __syncthreads();
#pragma unroll
        for (int ks = 0; ks < 2; ++ks) {
            const int ch = ks * 4 + kq;
            short8 af[4], bfv[4];
#pragma unroll
            for (int mi = 0; mi < 4; ++mi) {
                int row = wr * 64 + mi * 16 + r15;
                af[mi] = *(const short8*)(T + row * 64 + 8 * (ch ^ (row & 7)));
            }
#pragma unroll
            for (int ni = 0; ni < 4; ++ni) {
                int row = wc * 64 + ni * 16 + r15;
                bfv[ni] = *(const short8*)(T + row * 64 + 8 * (ch ^ (row & 7)));
            }
#pragma unroll
            for (int mi = 0; mi < 4; ++mi)
#pragma unroll
                for (int ni = 0; ni < 4; ++ni)
                    acc[mi][ni] = __builtin_amdgcn_mfma_f32_16x16x32_bf16(
                        af[mi], bfv[ni], acc[mi][ni], 0, 0, 0);
        }
    }
    {
        int g = t & 15, m = t >> 4;
#pragma unroll
        for (int u = 0; u < 8; ++u) cred[m][g][u] = cs[u];
    }
    __syncthreads();
    if (t < 128) {
        float s = 0.f;
#pragma unroll
        for (int m = 0; m < 16; ++m) s += cred[m][t >> 3][t & 7];
        atomicAdd(csum + (long)t * 16, s);
    }
#pragma unroll
    for (int mi = 0; mi < 4; ++mi)
#pragma unroll
        for (int ni = 0; ni < 4; ++ni)
#pragma unroll
            for (int r = 0; r < 4; ++r) {
                int row = wr * 64 + mi * 16 + kq * 4 + r;
                int col = wc * 64 + ni * 16 + r15;
                atomicAdd(M2 + row * 128 + col, acc[mi][ni][r]);
            }
}

// ---- combine: per-out-channel BN2 scale/shift ----
__global__ __launch_bounds__(128) void k_statcomb(const float* __restrict__ w_c2,
                                                  const float* __restrict__ M2,
                                                  const float* __restrict__ csum,
                                                  const float* __restrict__ g,
                                                  const float* __restrict__ bb,
                                                  float* __restrict__ scsh) {
    __shared__ float wl[128];
    __shared__ float red[2][2];
    const int o = blockIdx.x, c = threadIdx.x;
    wl[c] = w_c2[o * 128 + c];
    __syncthreads();
    const float* m2r = M2 + c * 128;
    float tmp = 0.f;
#pragma unroll
    for (int c2 = 0; c2 < 128; c2 += 4) {
        float4 m = *(const float4*)(m2r + c2);
        tmp += m.x * wl[c2] + m.y * wl[c2 + 1] + m.z * wl[c2 + 2] + m.w * wl[c2 + 3];
    }
    float s2p = wl[c] * tmp;
    float mup = wl[c] * csum[(long)c * 16];
#pragma unroll
    for (int off = 32; off; off >>= 1) {
        s2p += __shfl_down(s2p, off);
        mup += __shfl_down(mup, off);
    }
    if ((c & 63) == 0) { red[0][c >> 6] = s2p; red[1][c >> 6] = mup; }
    __syncthreads();
    if (c == 0) {
        float s2 = (red[0][0] + red[0][1]) / NPIX;
        float mu = (red[1][0] + red[1][1]) / NPIX;
        float var = s2 - mu * mu;
        float rs = rsqrtf(var + 1e-5f);
        float sc = g[o] * rs;
        scsh[o] = sc;
        scsh[512 + o] = bb[o] - mu * sc;
    }
}

// ---- conv2 + BN2 + GELU + IDWT -> out f32 NCHW; 512 threads (8 waves, 2x4) ----
// Halved per-thread state vs 256-thr version: no register spill.
__global__ __launch_bounds__(512) void k_conv2_idwt(const u16* __restrict__ Y,
                                                    const u16* __restrict__ Wc,
                                                    const float* __restrict__ scsh,
                                                    float* __restrict__ out) {
    __shared__ __align__(16) u16 lA[16384];  // [2 chunk][128 row][64 k]
    __shared__ __align__(16) u16 lB[8192];   // [2 chunk][64 row][64 k]
    __shared__ float sparam[1024];
    const int t = threadIdx.x;
    const int lane = t & 63, w = t >> 6, wr = w & 1, wc = w >> 1;  // wr 0..1, wc 0..3
    const int r15 = lane & 15, kq = lane >> 4;
    const int b = blockIdx.y, n0 = blockIdx.x;
#pragma unroll
    for (int u = 0; u < 2; ++u) sparam[t + u * 512] = scsh[t + u * 512];

    const u16* Yb = Y + ((long)b * HW2 + (long)n0 * 64) * 128;
    uint4 rb2[2], ra4[4];
#pragma unroll
    for (int i = 0; i < 2; ++i) {
        int s = i * 512 + t, row = s >> 4, seg = s & 15;
        rb2[i] = *(const uint4*)(Yb + (long)row * 128 + seg * 8);
    }
#define GLOADA(q)                                                                \
    {                                                                            \
        _Pragma("unroll")                                                        \
        for (int i = 0; i < 4; ++i) {                                            \
            int s = i * 512 + t, row = s >> 4, seg = s & 15;                     \
            ra4[i] = *(const uint4*)(Wc + (long)((q) * 128 + row) * 128 + seg * 8); \
        }                                                                        \
    }
#define LWRITEA()                                                                \
    {                                                                            \
        _Pragma("unroll")                                                        \
        for (int i = 0; i < 4; ++i) {                                            \
            int s = i * 512 + t, row = s >> 4, seg = s & 15;                     \
            *(uint4*)((char*)lA + (seg >> 3) * 16384 + row * 128 +               \
                      16 * ((seg & 7) ^ (row & 7))) = ra4[i];                    \
        }                                                                        \
    }
    GLOADA(0)
#pragma unroll
    for (int i = 0; i < 2; ++i) {
        int s = i * 512 + t, row = s >> 4, seg = s & 15;
        *(uint4*)((char*)lB + (seg >> 3) * 8192 + row * 128 +
                  16 * ((seg & 7) ^ (row & 7))) = rb2[i];
    }
    LWRITEA()
    __syncthreads();

    u32 sbp[4][4][2];   // [q][mi][rp]
#pragma unroll
    for (int q = 0; q < 4; ++q) {
        f32x4 acc[4];
#pragma unroll
        for (int mi = 0; mi < 4; ++mi) acc[mi] = (f32x4){0.f, 0.f, 0.f, 0.f};
#pragma unroll
        for (int chunk = 0; chunk < 2; ++chunk)
#pragma unroll
            for (int ks = 0; ks < 2; ++ks) {
                const int ch = ks * 4 + kq;
                short8 af[4], bfv;
#pragma unroll
                for (int mi = 0; mi < 4; ++mi) {
                    int row = wr * 64 + mi * 16 + r15;
                    af[mi] = *(const short8*)((const char*)lA + chunk * 16384 +
                                              row * 128 + 16 * (ch ^ (row & 7)));
                }
                {
                    int row = wc * 16 + r15;
                    bfv = *(const short8*)((const char*)lB + chunk * 8192 +
                                           row * 128 + 16 * (ch ^ (row & 7)));
                }
#pragma unroll
                for (int mi = 0; mi < 4; ++mi)
                    acc[mi] = __builtin_amdgcn_mfma_f32_16x16x32_bf16(
                        af[mi], bfv, acc[mi], 0, 0, 0);
            }
        if (q < 3) GLOADA(q + 1)
#pragma unroll
        for (int mi = 0; mi < 4; ++mi)
#pragma unroll
            for (int rp = 0; rp < 2; ++rp) {
                int c0 = q * 128 + wr * 64 + mi * 16 + kq * 4 + rp * 2;
                float v0 = gelu_f(acc[mi][rp * 2] * sparam[c0] + sparam[512 + c0]);
                float v1 = gelu_f(acc[mi][rp * 2 + 1] * sparam[c0 + 1] + sparam[512 + c0 + 1]);
                sbp[q][mi][rp] = (u32)f2bf(v0) | ((u32)f2bf(v1) << 16);
            }
        if (q < 3) {
            __syncthreads();
            LWRITEA()
            __syncthreads();
        }
    }
    const int i = n0 >> 1;
    const int j = (n0 & 1) * 64 + wc * 16 + r15;
#pragma unroll
    for (int mi = 0; mi < 4; ++mi)
#pragma unroll
        for (int rp = 0; rp < 2; ++rp) {
            u32 p0 = sbp[0][mi][rp], p1 = sbp[1][mi][rp];
            u32 p2 = sbp[2][mi][rp], p3 = sbp[3][mi][rp];
#pragma unroll
            for (int e = 0; e < 2; ++e) {
                int c = wr * 64 + mi * 16 + kq * 4 + rp * 2 + e;
                float ll = bf2f(e ? (u16)(p0 >> 16) : (u16)(p0 & 0xFFFF));
                float lh = bf2f(e ? (u16)(p1 >> 16) : (u16)(p1 & 0xFFFF));
                float hl = bf2f(e ? (u16)(p2 >> 16) : (u16)(p2 & 0xFFFF));
                float hh = bf2f(e ? (u16)(p3 >> 16) : (u16)(p3 & 0xFFFF));
                long ob = (((long)(b * Cc + c) * Hh + 2 * i) * Wf + 2 * j);
                *(float2*)(out + ob) =
                    make_float2((ll + lh + hl + hh) * 0.5f, (ll + lh - hl - hh) * 0.5f);
                *(float2*)(out + ob + Wf) =
                    make_float2((ll - lh + hl - hh) * 0.5f, (ll - lh - hl + hh) * 0.5f);
            }
        }
#undef GLOADA
#undef LWRITEA
}

extern "C" void kernel_launch(void* const* d_in, const int* in_sizes, int n_in,
                              void* d_out, int out_size, void* d_ws, size_t ws_size,
                              hipStream_t stream) {
    const float* x     = (const float*)d_in[0];
    const float* w_c1  = (const float*)d_in[1];
    const float* bn1_g = (const float*)d_in[3];
    const float* bn1_b = (const float*)d_in[4];
    const float* dw_w  = (const float*)d_in[5];
    const float* dw_b  = (const float*)d_in[6];
    const float* gn_g  = (const float*)d_in[7];
    const float* gn_b  = (const float*)d_in[8];
    const float* pw1_w = (const float*)d_in[9];
    const float* pw1_b = (const float*)d_in[10];
    const float* pw2_w = (const float*)d_in[11];
    const float* pw2_b = (const float*)d_in[12];
    const float* w_c2  = (const float*)d_in[13];
    const float* bn2_g = (const float*)d_in[15];
    const float* bn2_b = (const float*)d_in[16];
    float* out = (float*)d_out;

    const size_t n128 = (size_t)Bq * Cc * HW2;
    u16* bufA = (u16*)d_ws;        // conv1 raw out [b][px][128]
    u16* bufH = bufA + n128;       // post BN1+gelu (= residual)
    u16* bufD = bufH + n128;       // dwconv raw out
    u16* bufY = bufD + n128;       // MLP out (= conv2 input)
    u16* wb   = bufY + n128;       // bf16 weights: W'c1|pw1g|pw2|w_c2
    float* stats = (float*)(wb + 163840);
    size_t need = (4 * n128 + 163840) * 2 + 41000 * 4;
    if (ws_size < need) return;

    float* bn1_sum = stats;            // 128 x16 padded
    float* bn1_sq  = stats + 2048;
    float* ln_sum  = stats + 4096;     // 8x64 x16 padded
    float* ln_sq   = stats + 12288;
    float* csum    = stats + 20480;    // 128 x16 padded
    float* M2      = stats + 22528;    // 128x128 dense
    float* scsh    = stats + 38912;    // 512 scale | 512 shift
    float* wbv     = stats + 39936;
    float* wgs     = stats + 40064;

    hipMemsetAsync(stats, 0, 38912 * sizeof(float), stream);

    // 0. weights -> bf16 (w_c1 with DWT folded; pw1 pre-scaled by gn_g)
    k_wconv<<<640, 256, 0, stream>>>(w_c1, pw1_w, pw2_w, w_c2, gn_g, wb);
    k_wvec<<<1, 128, 0, stream>>>(pw1_w, gn_g, gn_b, wbv, wgs);

    // 1. fused DWT + conv1 + BN1 stats (reads x directly)
    k_conv1<<<dim3(1, 128, 8), 256, 0, stream>>>(x, wb, bufA, bn1_sum, bn1_sq);

    // 2. BN1 apply + gelu -> bufH
    k_bn1_gelu<<<8192, 256, 0, stream>>>(bufA, bufH, bn1_sum, bn1_sq, bn1_g, bn1_b);

    // 3. depthwise 3x3 + fused LN stats
    k_dwconv<<<dim3(8, 128, 8), 256, 0, stream>>>(bufH, bufD, dw_w, dw_b, ln_sum, ln_sq);

    // 4+5. fused MLP: pw1 (LN-folded + gelu) -> pw2 (+bias +residual) -> bufY
    k_mlp<<<dim3(1, 128, 8), 256, 0, stream>>>(
        bufD, wb + 65536, wb + 81920, pw1_b, pw2_b, bufH, bufY,
        ln_sum, ln_sq, wbv, wgs);

    // 6. BN2 stats via second moment
    k_moment<<<128, 256, 0, stream>>>(bufY, M2, csum);
    k_statcomb<<<512, 128, 0, stream>>>(w_c2, M2, csum, bn2_g, bn2_b, scsh);

    // 7. conv2 + BN2 + gelu + IDWT -> out (512-thread, spill-free)
    k_conv2_idwt<<<dim3(256, 8), 512, 0, stream>>>(bufY, wb + 98304, scsh, out);
}

// Round 10
// 476.518 us; speedup vs baseline: 1.9340x; 1.0186x over previous
//
#include <hip/hip_runtime.h>
#include <hip/hip_bf16.h>

typedef unsigned short u16;
typedef unsigned int u32;
typedef __attribute__((ext_vector_type(8))) short short8;
typedef __attribute__((ext_vector_type(4))) float f32x4;

#define Bq 8
#define Cc 128
#define C4 512
#define Hh 256
#define Wf 256
#define H2 128
#define W2 128
#define HW2 16384
#define NPIX 131072.0f

// tanh-approx GELU: max abs err ~1e-3, well under the 0.134 budget
__device__ __forceinline__ float gelu_f(float x) {
    float u = 1.5957691216057308f * (x + 0.044715f * x * x * x);
    float t = 1.0f - 2.0f / (__expf(u) + 1.0f);
    return 0.5f * x * (1.0f + t);
}
__device__ __forceinline__ float bf2f(u16 u) {
    union { float f; u32 i; } v; v.i = ((u32)u) << 16; return v.f;
}
__device__ __forceinline__ u16 f2bf(float f) {
    union { float f; u32 i; } v; v.f = f;
    u32 r = v.i + 0x7FFFu + ((v.i >> 16) & 1u);
    return (u16)(r >> 16);
}

// ---- weights f32 -> bf16. w_c1 gets the DWT folded in (stride-2 2x2 conv) ----
__global__ __launch_bounds__(256) void k_wconv(const float* __restrict__ w_c1,
                                               const float* __restrict__ pw1,
                                               const float* __restrict__ pw2,
                                               const float* __restrict__ w_c2,
                                               const float* __restrict__ gn_g,
                                               u16* __restrict__ wb) {
    int i = blockIdx.x * 256 + threadIdx.x;   // 0..163839
    float v;
    if (i < 65536) {
        int o = i >> 9, kn = i & 511;
        int c = kn >> 2, dy = (kn >> 1) & 1, dx = kn & 1;
        float sdy = dy ? -1.f : 1.f, sdx = dx ? -1.f : 1.f;
        const float* wr = w_c1 + o * 512 + c;
        v = 0.5f * (wr[0] + sdy * wr[128] + sdx * wr[256] + sdy * sdx * wr[384]);
    } else if (i < 81920) v = pw1[i - 65536] * gn_g[(i - 65536) & 127];
    else if (i < 98304) v = pw2[i - 81920];
    else v = w_c2[i - 98304];
    wb[i] = f2bf(v);
}

// ---- LN-fold vectors: wgs[o]=sum_c w*g, wbv[o]=sum_c w*b ----
__global__ __launch_bounds__(128) void k_wvec(const float* __restrict__ pw1,
                                              const float* __restrict__ gg,
                                              const float* __restrict__ gb,
                                              float* __restrict__ wbv,
                                              float* __restrict__ wgs) {
    int o = threadIdx.x;
    float a = 0.f, bv = 0.f;
    for (int c = 0; c < 128; ++c) {
        float w = pw1[o * 128 + c];
        a += w * gg[c];
        bv += w * gb[c];
    }
    wgs[o] = a;
    wbv[o] = bv;
}

// ---- fused DWT+conv1+BN1-stats: reads x f32 NCHW directly ----
// 512 threads (8 waves, 2 wr x 4 wc), full register double-buffer of x AND W.
__global__ __launch_bounds__(512) void k_conv1(const float* __restrict__ x,
                                               const u16* __restrict__ Wt,
                                               u16* __restrict__ Cout,
                                               float* __restrict__ statS,
                                               float* __restrict__ statQ) {
    __shared__ __align__(16) u16 lds[16384];   // A 16KB | B 16KB, then C bounce 32KB
    __shared__ float sblk[128], qblk[128];
    const int t = threadIdx.x;
    const int lane = t & 63, w = t >> 6, wr = w & 1, wc = w >> 1;   // wr 0..1, wc 0..3
    const int b = blockIdx.z, i = blockIdx.y;   // lowres row
    if (t < 128) { sblk[t] = 0.f; qblk[t] = 0.f; }

    const int r15 = lane & 15, kq = lane >> 4;
    // staging coords: 512 thr = half(2) x dy(2) x cc(16) x colblk(8)
    const int half = t >> 8;
    const int colblk = t & 7, cc = (t >> 3) & 15, dy = (t >> 7) & 1;
    const int kbase = cc * 4 + dy * 2;
    const int gG = kbase >> 3, e2 = (kbase & 7) * 2;

    float4 xv[4];
    uint4 rb[2];
    {   // preload k0 = 0
        const float* xp = x + (((long)(b * Cc + cc)) * Hh + (2 * i + dy)) * Wf;
#pragma unroll
        for (int q = 0; q < 4; ++q) {
            int col = (half * 4 + q) * 32 + colblk * 4;
            xv[q] = *(const float4*)(xp + col);
        }
#pragma unroll
        for (int ii = 0; ii < 2; ++ii) {
            int s = ii * 512 + t;
            rb[ii] = *(const uint4*)(Wt + (long)(s >> 3) * 512 + (s & 7) * 8);
        }
    }

    f32x4 acc[4][2];
#pragma unroll
    for (int a2 = 0; a2 < 4; ++a2)
#pragma unroll
        for (int j2 = 0; j2 < 2; ++j2) acc[a2][j2] = (f32x4){0.f, 0.f, 0.f, 0.f};

    for (int k0 = 0; k0 < 512; k0 += 64) {
        __syncthreads();   // previous tile's frag reads complete
        // write staged registers to LDS (A: f32->bf16 pack; B: raw)
#pragma unroll
        for (int q = 0; q < 4; ++q) {
            int col = (half * 4 + q) * 32 + colblk * 4;
            int j0 = col >> 1;
            u32 p0 = (u32)f2bf(xv[q].x) | ((u32)f2bf(xv[q].y) << 16);
            u32 p1 = (u32)f2bf(xv[q].z) | ((u32)f2bf(xv[q].w) << 16);
            *(u32*)((char*)lds + j0 * 128 + 16 * (gG ^ (j0 & 7)) + e2) = p0;
            *(u32*)((char*)lds + (j0 + 1) * 128 + 16 * (gG ^ ((j0 + 1) & 7)) + e2) = p1;
        }
#pragma unroll
        for (int ii = 0; ii < 2; ++ii) {
            int s = ii * 512 + t;
            int row_ = s >> 3, ch_ = s & 7;
            *(uint4*)((char*)lds + 16384 + row_ * 128 + 16 * (ch_ ^ (row_ & 7))) = rb[ii];
        }
        __syncthreads();
        if (k0 + 64 < 512) {   // prefetch next tile BEFORE MFMA (hides HBM latency)
            const int c0n = (k0 + 64) >> 2;
            const float* xp = x + (((long)(b * Cc + c0n + cc)) * Hh + (2 * i + dy)) * Wf;
#pragma unroll
            for (int q = 0; q < 4; ++q) {
                int col = (half * 4 + q) * 32 + colblk * 4;
                xv[q] = *(const float4*)(xp + col);
            }
#pragma unroll
            for (int ii = 0; ii < 2; ++ii) {
                int s = ii * 512 + t;
                rb[ii] = *(const uint4*)(Wt + (long)(s >> 3) * 512 + (k0 + 64) + (s & 7) * 8);
            }
        }
#pragma unroll
        for (int ks = 0; ks < 2; ++ks) {
            short8 af[4], bfv[2];
            const int ch = ks * 4 + kq;
#pragma unroll
            for (int mi = 0; mi < 4; ++mi) {
                int row = wr * 64 + mi * 16 + r15;
                af[mi] = *(const short8*)((const char*)lds + row * 128 + 16 * (ch ^ (row & 7)));
            }
#pragma unroll
            for (int ni = 0; ni < 2; ++ni) {
                int row = wc * 32 + ni * 16 + r15;
                bfv[ni] = *(const short8*)((const char*)lds + 16384 + row * 128 + 16 * (ch ^ (row & 7)));
            }
#pragma unroll
            for (int mi = 0; mi < 4; ++mi)
#pragma unroll
                for (int ni = 0; ni < 2; ++ni)
                    acc[mi][ni] = __builtin_amdgcn_mfma_f32_16x16x32_bf16(
                        af[mi], bfv[ni], acc[mi][ni], 0, 0, 0);
        }
    }
    __syncthreads();

    // bounce C (bf16) into lds: [row=px][col=o ^ swz]
#pragma unroll
    for (int mi = 0; mi < 4; ++mi)
#pragma unroll
        for (int ni = 0; ni < 2; ++ni)
#pragma unroll
            for (int r = 0; r < 4; ++r) {
                int row = wr * 64 + mi * 16 + kq * 4 + r;
                int col = wc * 32 + ni * 16 + r15;
                lds[row * 128 + (col ^ ((row & 7) << 3))] = f2bf(acc[mi][ni][r]);
            }
    // per-col (out-channel) stats
#pragma unroll
    for (int ni = 0; ni < 2; ++ni) {
        float s = 0.f, q2 = 0.f;
#pragma unroll
        for (int mi = 0; mi < 4; ++mi)
#pragma unroll
            for (int r = 0; r < 4; ++r) {
                float v = acc[mi][ni][r];
                s += v; q2 += v * v;
            }
        s += __shfl_down(s, 32); s += __shfl_down(s, 16);
        q2 += __shfl_down(q2, 32); q2 += __shfl_down(q2, 16);
        if (lane < 16) {
            int col = wc * 32 + ni * 16 + r15;
            atomicAdd(&sblk[col], s);
            atomicAdd(&qblk[col], q2);
        }
    }
    __syncthreads();
    // coalesced store (512 thr: 4 uint4 each)
    {
        u16* Cb = Cout + (long)b * HW2 * 128;
        int row = t >> 2, quarter = (t & 3) * 32;
        int sx = (row & 7) << 3;
        long gbase = (long)(i * 128 + row) * 128;
#pragma unroll
        for (int q = 0; q < 4; ++q) {
            int c = quarter + q * 8;
            *(uint4*)(Cb + gbase + c) = *(const uint4*)(lds + row * 128 + (c ^ sx));
        }
    }
    if (t < 128) {
        atomicAdd(statS + (long)t * 16, sblk[t]);
        atomicAdd(statQ + (long)t * 16, qblk[t]);
    }
}

// ---- BN1 apply + gelu: bufA -> bufH (padded stats) ----
__global__ __launch_bounds__(256) void k_bn1_gelu(const u16* __restrict__ in,
                                                  u16* __restrict__ out,
                                                  const float* __restrict__ sum,
                                                  const float* __restrict__ sq,
                                                  const float* __restrict__ g,
                                                  const float* __restrict__ bb) {
    long e = ((long)blockIdx.x * 256 + threadIdx.x) * 8;
    int c0 = (int)(e & 127);
    uint4 raw = *(const uint4*)(in + e);
    u16* pv = (u16*)&raw;
    const float invN = 1.0f / 131072.0f;
#pragma unroll
    for (int u = 0; u < 8; ++u) {
        int c = c0 + u;
        float mu = sum[(long)c * 16] * invN;
        float var = sq[(long)c * 16] * invN - mu * mu;
        float rscale = rsqrtf(var + 1e-5f);
        float sc = rscale * g[c], sh = bb[c] - mu * sc;
        pv[u] = f2bf(gelu_f(bf2f(pv[u]) * sc + sh));
    }
    *(uint4*)(out + e) = raw;
}

// ---- depthwise 3x3 NHWC bf16 + fused LN stats (64 padded slots/batch) ----
__global__ __launch_bounds__(256) void k_dwconv(const u16* __restrict__ x,
                                                u16* __restrict__ y,
                                                const float* __restrict__ w,
                                                const float* __restrict__ bias,
                                                float* __restrict__ lnS,
                                                float* __restrict__ lnQ) {
    __shared__ float wl2[1152];
    const int t = threadIdx.x;
    for (int idx = t; idx < 1152; idx += 256) {
        int c = idx / 9, tap = idx - c * 9;
        wl2[tap * 128 + (c & 7) * 16 + (c >> 3)] = w[idx];
    }
    __syncthreads();
    const int cg = t & 15, jj = t >> 4;
    const int j = blockIdx.x * 16 + jj, i = blockIdx.y, b = blockIdx.z;
    const u16* xb = x + (long)b * HW2 * 128 + cg * 8;
    uint4 raw[3][3];
    const uint4 z4 = make_uint4(0u, 0u, 0u, 0u);
#pragma unroll
    for (int r = 0; r < 3; ++r) {
        int row = i - 1 + r;
#pragma unroll
        for (int q = 0; q < 3; ++q) {
            int col = j - 1 + q;
            bool ok = (row >= 0) & (row < H2) & (col >= 0) & (col < W2);
            raw[r][q] = ok ? *(const uint4*)(xb + ((long)row * W2 + col) * 128) : z4;
        }
    }
    float acc[8];
#pragma unroll
    for (int u = 0; u < 8; ++u) acc[u] = bias[cg * 8 + u];
#pragma unroll
    for (int r = 0; r < 3; ++r)
#pragma unroll
        for (int q = 0; q < 3; ++q) {
            const u16* pv = (const u16*)&raw[r][q];
            const int tap = r * 3 + q;
#pragma unroll
            for (int u = 0; u < 8; ++u)
                acc[u] = fmaf(bf2f(pv[u]), wl2[tap * 128 + u * 16 + cg], acc[u]);
        }
    uint4 outv; u16* ov = (u16*)&outv;
    float s = 0.f, q2 = 0.f;
#pragma unroll
    for (int u = 0; u < 8; ++u) {
        ov[u] = f2bf(acc[u]);
        s += acc[u]; q2 += acc[u] * acc[u];
    }
    *(uint4*)(y + ((long)b * HW2 + (long)i * W2 + j) * 128 + cg * 8) = outv;
#pragma unroll
    for (int off = 32; off; off >>= 1) {
        s += __shfl_down(s, off);
        q2 += __shfl_down(q2, off);
    }
    __shared__ float r1[4], r2[4];
    if ((t & 63) == 0) { r1[t >> 6] = s; r2[t >> 6] = q2; }
    __syncthreads();
    if (t == 0) {
        int slot = (blockIdx.y * 8 + blockIdx.x) & 63;
        atomicAdd(lnS + ((long)b * 64 + slot) * 16, r1[0] + r1[1] + r1[2] + r1[3]);
        atomicAdd(lnQ + ((long)b * 64 + slot) * 16, r2[0] + r2[1] + r2[2] + r2[3]);
    }
}

// ---- fused MLP: pw1 (LN-folded affine + gelu) then pw2 (+bias +residual) ----
__global__ __launch_bounds__(256) void k_mlp(const u16* __restrict__ D,
                                             const u16* __restrict__ Wp1,
                                             const u16* __restrict__ Wp2,
                                             const float* __restrict__ b1,
                                             const float* __restrict__ b2,
                                             const u16* __restrict__ resH,
                                             u16* __restrict__ Yout,
                                             const float* __restrict__ lnS,
                                             const float* __restrict__ lnQ,
                                             const float* __restrict__ wbv,
                                             const float* __restrict__ wgs) {
    __shared__ __align__(16) u16 lA[16384];   // [2 chunk][128 row][64 k]
    __shared__ __align__(16) u16 lB[16384];
    __shared__ float s1[128], s2[128], lnred[2];
    const int t = threadIdx.x;
    const int lane = t & 63, w = t >> 6, wr = w >> 1, wc = w & 1;
    const int r15 = lane & 15, kq = lane >> 4;
    const int b = blockIdx.z, m0 = blockIdx.y * 128;

    if (t < 64) {
        float s = lnS[((long)b * 64 + t) * 16];
        float q = lnQ[((long)b * 64 + t) * 16];
#pragma unroll
        for (int off = 32; off; off >>= 1) {
            s += __shfl_down(s, off);
            q += __shfl_down(q, off);
        }
        if (t == 0) { lnred[0] = s; lnred[1] = q; }
    }
    __syncthreads();
    const float invN = 1.0f / 2097152.0f;
    float mu = lnred[0] * invN;
    float var = lnred[1] * invN - mu * mu;
    const float rs = rsqrtf(var + 1e-5f);
    if (t < 128) {
        s1[t] = b1[t] + wbv[t] - mu * rs * wgs[t];
        s2[t] = b2[t];
    }

    const u16* Ab = D + ((long)b * HW2 + m0) * 128;
    uint4 ga[8], gb[8];
#pragma unroll
    for (int i = 0; i < 8; ++i) {
        int s = i * 256 + t, row = s >> 4, seg = s & 15;
        ga[i] = *(const uint4*)(Ab + (long)row * 128 + seg * 8);
        gb[i] = *(const uint4*)(Wp1 + (long)row * 128 + seg * 8);
    }
#pragma unroll
    for (int i = 0; i < 8; ++i) {
        int s = i * 256 + t, row = s >> 4, seg = s & 15;
        int off = (seg >> 3) * 16384 + row * 128 + 16 * ((seg & 7) ^ (row & 7));
        *(uint4*)((char*)lA + off) = ga[i];
        *(uint4*)((char*)lB + off) = gb[i];
    }
    __syncthreads();

    f32x4 acc[4][4];
#pragma unroll
    for (int i = 0; i < 4; ++i)
#pragma unroll
        for (int j = 0; j < 4; ++j) acc[i][j] = (f32x4){0.f, 0.f, 0.f, 0.f};
#pragma unroll
    for (int chunk = 0; chunk < 2; ++chunk)
#pragma unroll
        for (int ks = 0; ks < 2; ++ks) {
            const int ch = ks * 4 + kq;
            short8 af[4], bfv[4];
#pragma unroll
            for (int mi = 0; mi < 4; ++mi) {
                int row = wr * 64 + mi * 16 + r15;
                af[mi] = *(const short8*)((const char*)lA + chunk * 16384 +
                                          row * 128 + 16 * (ch ^ (row & 7)));
            }
#pragma unroll
            for (int ni = 0; ni < 4; ++ni) {
                int row = wc * 64 + ni * 16 + r15;
                bfv[ni] = *(const short8*)((const char*)lB + chunk * 16384 +
                                           row * 128 + 16 * (ch ^ (row & 7)));
            }
#pragma unroll
            for (int mi = 0; mi < 4; ++mi)
#pragma unroll
                for (int ni = 0; ni < 4; ++ni)
                    acc[mi][ni] = __builtin_amdgcn_mfma_f32_16x16x32_bf16(
                        af[mi], bfv[ni], acc[mi][ni], 0, 0, 0);
        }
    // prefetch pw2 weights while GEMM1 drains
#pragma unroll
    for (int i = 0; i < 8; ++i) {
        int s = i * 256 + t, row = s >> 4, seg = s & 15;
        gb[i] = *(const uint4*)(Wp2 + (long)row * 128 + seg * 8);
    }
    __syncthreads();   // all lA/lB reads complete

    // bounce1: gelu(rs*acc + s1[ch]) -> lA in GEMM-A k-major layout (k = ch)
#pragma unroll
    for (int mi = 0; mi < 4; ++mi)
#pragma unroll
        for (int ni = 0; ni < 4; ++ni)
#pragma unroll
            for (int r = 0; r < 4; ++r) {
                int row = wr * 64 + mi * 16 + kq * 4 + r;   // px
                int col = wc * 64 + ni * 16 + r15;          // ch (= k of GEMM2)
                float v = gelu_f(rs * acc[mi][ni][r] + s1[col]);
                lA[(col >> 6) * 8192 + row * 64 +
                   8 * (((col >> 3) & 7) ^ (row & 7)) + (col & 7)] = f2bf(v);
            }
#pragma unroll
    for (int i = 0; i < 8; ++i) {
        int s = i * 256 + t, row = s >> 4, seg = s & 15;
        int off = (seg >> 3) * 16384 + row * 128 + 16 * ((seg & 7) ^ (row & 7));
        *(uint4*)((char*)lB + off) = gb[i];
    }
    __syncthreads();

    // GEMM2
#pragma unroll
    for (int i = 0; i < 4; ++i)
#pragma unroll
        for (int j = 0; j < 4; ++j) acc[i][j] = (f32x4){0.f, 0.f, 0.f, 0.f};
#pragma unroll
    for (int chunk = 0; chunk < 2; ++chunk)
#pragma unroll
        for (int ks = 0; ks < 2; ++ks) {
            const int ch = ks * 4 + kq;
            short8 af[4], bfv[4];
#pragma unroll
            for (int mi = 0; mi < 4; ++mi) {
                int row = wr * 64 + mi * 16 + r15;
                af[mi] = *(const short8*)((const char*)lA + chunk * 16384 +
                                          row * 128 + 16 * (ch ^ (row & 7)));
            }
#pragma unroll
            for (int ni = 0; ni < 4; ++ni) {
                int row = wc * 64 + ni * 16 + r15;
                bfv[ni] = *(const short8*)((const char*)lB + chunk * 16384 +
                                           row * 128 + 16 * (ch ^ (row & 7)));
            }
#pragma unroll
            for (int mi = 0; mi < 4; ++mi)
#pragma unroll
                for (int ni = 0; ni < 4; ++ni)
                    acc[mi][ni] = __builtin_amdgcn_mfma_f32_16x16x32_bf16(
                        af[mi], bfv[ni], acc[mi][ni], 0, 0, 0);
        }
    __syncthreads();   // lA reads done; reuse flat for bounce2

#pragma unroll
    for (int mi = 0; mi < 4; ++mi)
#pragma unroll
        for (int ni = 0; ni < 4; ++ni)
#pragma unroll
            for (int r = 0; r < 4; ++r) {
                int row = wr * 64 + mi * 16 + kq * 4 + r;
                int col = wc * 64 + ni * 16 + r15;
                lA[row * 128 + (col ^ ((row & 7) << 3))] = f2bf(acc[mi][ni][r]);
            }
    __syncthreads();

    const u16* Rb = resH + ((long)b * HW2 + m0) * 128;
    u16* Cb = Yout + ((long)b * HW2 + m0) * 128;
    {
        int row = t >> 1, half = (t & 1) * 64;
        int sx = (row & 7) << 3;
#pragma unroll
        for (int q = 0; q < 8; ++q) {
            int c = half + q * 8;
            uint4 raw = *(const uint4*)(lA + row * 128 + (c ^ sx));
            uint4 rr = *(const uint4*)(Rb + (long)row * 128 + c);
            u16* pv = (u16*)&raw;
            const u16* rv = (const u16*)&rr;
#pragma unroll
            for (int u = 0; u < 8; ++u)
                pv[u] = f2bf(bf2f(pv[u]) + s2[c + u] + bf2f(rv[u]));
            *(uint4*)(Cb + (long)row * 128 + c) = raw;
        }
    }
}

// ---- second moment M2 = Y^T Y (128x128) + col-sums; 128 blocks x 1024 px ----
__global__ __launch_bounds__(256) void k_moment(const u16* __restrict__ Y,
                                                float* __restrict__ M2,
                                                float* __restrict__ csum) {
    __shared__ __align__(16) u16 T[8192];
    __shared__ float cred[16][16][8];
    const int t = threadIdx.x;
    const int lane = t & 63, w = t >> 6, wr = w >> 1, wc = w & 1;
    const int r15 = lane & 15, kq = lane >> 4;
    const long px0 = (long)blockIdx.x * 1024;
    float cs[8] = {};

    f32x4 acc[4][4];
#pragma unroll
    for (int i = 0; i < 4; ++i)
#pragma unroll
        for (int j = 0; j < 4; ++j) acc[i][j] = (f32x4){0.f, 0.f, 0.f, 0.f};

    for (int it = 0; it < 16; ++it) {
        uint4 rv[4];
#pragma unroll
        for (int i = 0; i < 4; ++i) {
            int s = i * 256 + t;
            int px = s >> 4, ch8 = (s & 15) * 8;
            rv[i] = *(const uint4*)(Y + (px0 + it * 64 + px) * 128 + ch8);
        }
#pragma unroll
        for (int i = 0; i < 4; ++i) {
            const u16* pv = (const u16*)&rv[i];
#pragma unroll
            for (int u = 0; u < 8; ++u) cs[u] += bf2f(pv[u]);
        }
        __syncthreads();
#pragma unroll
        for (int i = 0; i < 4; ++i) {
            int s = i * 256 + t;
            int px = s >> 4, ch8 = (s & 15) * 8;
            const u16* pv = (const u16*)&rv[i];
#pragma unroll
            for (int u = 0; u < 8; ++u) {
                int row = ch8 + u;
                T[row * 64 + 8 * ((px >> 3) ^ (row & 7)) + (px & 7)] = pv[u];
            }
        }
        __syncthreads();
#pragma unroll
        for (int ks = 0; ks < 2; ++ks) {
            const int ch = ks * 4 + kq;
            short8 af[4], bfv[4];
#pragma unroll
            for (int mi = 0; mi < 4; ++mi) {
                int row = wr * 64 + mi * 16 + r15;
                af[mi] = *(const short8*)(T + row * 64 + 8 * (ch ^ (row & 7)));
            }
#pragma unroll
            for (int ni = 0; ni < 4; ++ni) {
                int row = wc * 64 + ni * 16 + r15;
                bfv[ni] = *(const short8*)(T + row * 64 + 8 * (ch ^ (row & 7)));
            }
#pragma unroll
            for (int mi = 0; mi < 4; ++mi)
#pragma unroll
                for (int ni = 0; ni < 4; ++ni)
                    acc[mi][ni] = __builtin_amdgcn_mfma_f32_16x16x32_bf16(
                        af[mi], bfv[ni], acc[mi][ni], 0, 0, 0);
        }
    }
    {
        int g = t & 15, m = t >> 4;
#pragma unroll
        for (int u = 0; u < 8; ++u) cred[m][g][u] = cs[u];
    }
    __syncthreads();
    if (t < 128) {
        float s = 0.f;
#pragma unroll
        for (int m = 0; m < 16; ++m) s += cred[m][t >> 3][t & 7];
        atomicAdd(csum + (long)t * 16, s);
    }
#pragma unroll
    for (int mi = 0; mi < 4; ++mi)
#pragma unroll
        for (int ni = 0; ni < 4; ++ni)
#pragma unroll
            for (int r = 0; r < 4; ++r) {
                int row = wr * 64 + mi * 16 + kq * 4 + r;
                int col = wc * 64 + ni * 16 + r15;
                atomicAdd(M2 + row * 128 + col, acc[mi][ni][r]);
            }
}

// ---- combine: per-out-channel BN2 scale/shift ----
__global__ __launch_bounds__(128) void k_statcomb(const float* __restrict__ w_c2,
                                                  const float* __restrict__ M2,
                                                  const float* __restrict__ csum,
                                                  const float* __restrict__ g,
                                                  const float* __restrict__ bb,
                                                  float* __restrict__ scsh) {
    __shared__ float wl[128];
    __shared__ float red[2][2];
    const int o = blockIdx.x, c = threadIdx.x;
    wl[c] = w_c2[o * 128 + c];
    __syncthreads();
    const float* m2r = M2 + c * 128;
    float tmp = 0.f;
#pragma unroll
    for (int c2 = 0; c2 < 128; c2 += 4) {
        float4 m = *(const float4*)(m2r + c2);
        tmp += m.x * wl[c2] + m.y * wl[c2 + 1] + m.z * wl[c2 + 2] + m.w * wl[c2 + 3];
    }
    float s2p = wl[c] * tmp;
    float mup = wl[c] * csum[(long)c * 16];
#pragma unroll
    for (int off = 32; off; off >>= 1) {
        s2p += __shfl_down(s2p, off);
        mup += __shfl_down(mup, off);
    }
    if ((c & 63) == 0) { red[0][c >> 6] = s2p; red[1][c >> 6] = mup; }
    __syncthreads();
    if (c == 0) {
        float s2 = (red[0][0] + red[0][1]) / NPIX;
        float mu = (red[1][0] + red[1][1]) / NPIX;
        float var = s2 - mu * mu;
        float rs = rsqrtf(var + 1e-5f);
        float sc = g[o] * rs;
        scsh[o] = sc;
        scsh[512 + o] = bb[o] - mu * sc;
    }
}

// ---- conv2 + BN2 + GELU + IDWT -> out f32 NCHW; 512 threads (8 waves, 2x4) ----
__global__ __launch_bounds__(512) void k_conv2_idwt(const u16* __restrict__ Y,
                                                    const u16* __restrict__ Wc,
                                                    const float* __restrict__ scsh,
                                                    float* __restrict__ out) {
    __shared__ __align__(16) u16 lA[16384];  // [2 chunk][128 row][64 k]
    __shared__ __align__(16) u16 lB[8192];   // [2 chunk][64 row][64 k]
    __shared__ float sparam[1024];
    const int t = threadIdx.x;
    const int lane = t & 63, w = t >> 6, wr = w & 1, wc = w >> 1;  // wr 0..1, wc 0..3
    const int r15 = lane & 15, kq = lane >> 4;
    const int b = blockIdx.y, n0 = blockIdx.x;
#pragma unroll
    for (int u = 0; u < 2; ++u) sparam[t + u * 512] = scsh[t + u * 512];

    const u16* Yb = Y + ((long)b * HW2 + (long)n0 * 64) * 128;
    uint4 rb2[2], ra4[4];
#pragma unroll
    for (int i = 0; i < 2; ++i) {
        int s = i * 512 + t, row = s >> 4, seg = s & 15;
        rb2[i] = *(const uint4*)(Yb + (long)row * 128 + seg * 8);
    }
#define GLOADA(q)                                                                \
    {                                                                            \
        _Pragma("unroll")                                                        \
        for (int i = 0; i < 4; ++i) {                                            \
            int s = i * 512 + t, row = s >> 4, seg = s & 15;                     \
            ra4[i] = *(const uint4*)(Wc + (long)((q) * 128 + row) * 128 + seg * 8); \
        }                                                                        \
    }
#define LWRITEA()                                                                \
    {                                                                            \
        _Pragma("unroll")                                                        \
        for (int i = 0; i < 4; ++i) {                                            \
            int s = i * 512 + t, row = s >> 4, seg = s & 15;                     \
            *(uint4*)((char*)lA + (seg >> 3) * 16384 + row * 128 +               \
                      16 * ((seg & 7) ^ (row & 7))) = ra4[i];                    \
        }                                                                        \
    }
    GLOADA(0)
#pragma unroll
    for (int i = 0; i < 2; ++i) {
        int s = i * 512 + t, row = s >> 4, seg = s & 15;
        *(uint4*)((char*)lB + (seg >> 3) * 8192 + row * 128 +
                  16 * ((seg & 7) ^ (row & 7))) = rb2[i];
    }
    LWRITEA()
    __syncthreads();

    u32 sbp[4][4][2];   // [q][mi][rp]
#pragma unroll
    for (int q = 0; q < 4; ++q) {
        f32x4 acc[4];
#pragma unroll
        for (int mi = 0; mi < 4; ++mi) acc[mi] = (f32x4){0.f, 0.f, 0.f, 0.f};
#pragma unroll
        for (int chunk = 0; chunk < 2; ++chunk)
#pragma unroll
            for (int ks = 0; ks < 2; ++ks) {
                const int ch = ks * 4 + kq;
                short8 af[4], bfv;
#pragma unroll
                for (int mi = 0; mi < 4; ++mi) {
                    int row = wr * 64 + mi * 16 + r15;
                    af[mi] = *(const short8*)((const char*)lA + chunk * 16384 +
                                              row * 128 + 16 * (ch ^ (row & 7)));
                }
                {
                    int row = wc * 16 + r15;
                    bfv = *(const short8*)((const char*)lB + chunk * 8192 +
                                           row * 128 + 16 * (ch ^ (row & 7)));
                }
#pragma unroll
                for (int mi = 0; mi < 4; ++mi)
                    acc[mi] = __builtin_amdgcn_mfma_f32_16x16x32_bf16(
                        af[mi], bfv, acc[mi], 0, 0, 0);
            }
        if (q < 3) GLOADA(q + 1)
#pragma unroll
        for (int mi = 0; mi < 4; ++mi)
#pragma unroll
            for (int rp = 0; rp < 2; ++rp) {
                int c0 = q * 128 + wr * 64 + mi * 16 + kq * 4 + rp * 2;
                float v0 = gelu_f(acc[mi][rp * 2] * sparam[c0] + sparam[512 + c0]);
                float v1 = gelu_f(acc[mi][rp * 2 + 1] * sparam[c0 + 1] + sparam[512 + c0 + 1]);
                sbp[q][mi][rp] = (u32)f2bf(v0) | ((u32)f2bf(v1) << 16);
            }
        if (q < 3) {
            __syncthreads();
            LWRITEA()
            __syncthreads();
        }
    }
    const int i = n0 >> 1;
    const int j = (n0 & 1) * 64 + wc * 16 + r15;
#pragma unroll
    for (int mi = 0; mi < 4; ++mi)
#pragma unroll
        for (int rp = 0; rp < 2; ++rp) {
            u32 p0 = sbp[0][mi][rp], p1 = sbp[1][mi][rp];
            u32 p2 = sbp[2][mi][rp], p3 = sbp[3][mi][rp];
#pragma unroll
            for (int e = 0; e < 2; ++e) {
                int c = wr * 64 + mi * 16 + kq * 4 + rp * 2 + e;
                float ll = bf2f(e ? (u16)(p0 >> 16) : (u16)(p0 & 0xFFFF));
                float lh = bf2f(e ? (u16)(p1 >> 16) : (u16)(p1 & 0xFFFF));
                float hl = bf2f(e ? (u16)(p2 >> 16) : (u16)(p2 & 0xFFFF));
                float hh = bf2f(e ? (u16)(p3 >> 16) : (u16)(p3 & 0xFFFF));
                long ob = (((long)(b * Cc + c) * Hh + 2 * i) * Wf + 2 * j);
                *(float2*)(out + ob) =
                    make_float2((ll + lh + hl + hh) * 0.5f, (ll + lh - hl - hh) * 0.5f);
                *(float2*)(out + ob + Wf) =
                    make_float2((ll - lh + hl - hh) * 0.5f, (ll - lh - hl + hh) * 0.5f);
            }
        }
#undef GLOADA
#undef LWRITEA
}

extern "C" void kernel_launch(void* const* d_in, const int* in_sizes, int n_in,
                              void* d_out, int out_size, void* d_ws, size_t ws_size,
                              hipStream_t stream) {
    const float* x     = (const float*)d_in[0];
    const float* w_c1  = (const float*)d_in[1];
    const float* bn1_g = (const float*)d_in[3];
    const float* bn1_b = (const float*)d_in[4];
    const float* dw_w  = (const float*)d_in[5];
    const float* dw_b  = (const float*)d_in[6];
    const float* gn_g  = (const float*)d_in[7];
    const float* gn_b  = (const float*)d_in[8];
    const float* pw1_w = (const float*)d_in[9];
    const float* pw1_b = (const float*)d_in[10];
    const float* pw2_w = (const float*)d_in[11];
    const float* pw2_b = (const float*)d_in[12];
    const float* w_c2  = (const float*)d_in[13];
    const float* bn2_g = (const float*)d_in[15];
    const float* bn2_b = (const float*)d_in[16];
    float* out = (float*)d_out;

    const size_t n128 = (size_t)Bq * Cc * HW2;
    u16* bufA = (u16*)d_ws;        // conv1 raw out [b][px][128]
    u16* bufH = bufA + n128;       // post BN1+gelu (= residual)
    u16* bufD = bufH + n128;       // dwconv raw out
    u16* bufY = bufD + n128;       // MLP out (= conv2 input)
    u16* wb   = bufY + n128;       // bf16 weights: W'c1|pw1g|pw2|w_c2
    float* stats = (float*)(wb + 163840);
    size_t need = (4 * n128 + 163840) * 2 + 41000 * 4;
    if (ws_size < need) return;

    float* bn1_sum = stats;            // 128 x16 padded
    float* bn1_sq  = stats + 2048;
    float* ln_sum  = stats + 4096;     // 8x64 x16 padded
    float* ln_sq   = stats + 12288;
    float* csum    = stats + 20480;    // 128 x16 padded
    float* M2      = stats + 22528;    // 128x128 dense
    float* scsh    = stats + 38912;    // 512 scale | 512 shift
    float* wbv     = stats + 39936;
    float* wgs     = stats + 40064;

    hipMemsetAsync(stats, 0, 38912 * sizeof(float), stream);

    // 0. weights -> bf16 (w_c1 with DWT folded; pw1 pre-scaled by gn_g)
    k_wconv<<<640, 256, 0, stream>>>(w_c1, pw1_w, pw2_w, w_c2, gn_g, wb);
    k_wvec<<<1, 128, 0, stream>>>(pw1_w, gn_g, gn_b, wbv, wgs);

    // 1. fused DWT + conv1 + BN1 stats (512-thr, x+W register double-buffer)
    k_conv1<<<dim3(1, 128, 8), 512, 0, stream>>>(x, wb, bufA, bn1_sum, bn1_sq);

    // 2. BN1 apply + gelu -> bufH
    k_bn1_gelu<<<8192, 256, 0, stream>>>(bufA, bufH, bn1_sum, bn1_sq, bn1_g, bn1_b);

    // 3. depthwise 3x3 + fused LN stats
    k_dwconv<<<dim3(8, 128, 8), 256, 0, stream>>>(bufH, bufD, dw_w, dw_b, ln_sum, ln_sq);

    // 4+5. fused MLP: pw1 (LN-folded + gelu) -> pw2 (+bias +residual) -> bufY
    k_mlp<<<dim3(1, 128, 8), 256, 0, stream>>>(
        bufD, wb + 65536, wb + 81920, pw1_b, pw2_b, bufH, bufY,
        ln_sum, ln_sq, wbv, wgs);

    // 6. BN2 stats via second moment
    k_moment<<<128, 256, 0, stream>>>(bufY, M2, csum);
    k_statcomb<<<512, 128, 0, stream>>>(w_c2, M2, csum, bn2_g, bn2_b, scsh);

    // 7. conv2 + BN2 + gelu + IDWT -> out (512-thread, spill-free)
    k_conv2_idwt<<<dim3(256, 8), 512, 0, stream>>>(bufY, wb + 98304, scsh, out);
}

// Round 11
// 423.498 us; speedup vs baseline: 2.1761x; 1.1252x over previous
//
#include <hip/hip_runtime.h>
#include <hip/hip_bf16.h>

typedef unsigned short u16;
typedef unsigned int u32;
typedef __attribute__((ext_vector_type(8))) short short8;
typedef __attribute__((ext_vector_type(4))) float f32x4;

#define Bq 8
#define Cc 128
#define C4 512
#define Hh 256
#define Wf 256
#define H2 128
#define W2 128
#define HW2 16384
#define NPIX 131072.0f

// tanh-approx GELU: max abs err ~1e-3, well under the 0.134 budget
__device__ __forceinline__ float gelu_f(float x) {
    float u = 1.5957691216057308f * (x + 0.044715f * x * x * x);
    float t = 1.0f - 2.0f / (__expf(u) + 1.0f);
    return 0.5f * x * (1.0f + t);
}
__device__ __forceinline__ float bf2f(u16 u) {
    union { float f; u32 i; } v; v.i = ((u32)u) << 16; return v.f;
}
__device__ __forceinline__ u16 f2bf(float f) {
    union { float f; u32 i; } v; v.f = f;
    u32 r = v.i + 0x7FFFu + ((v.i >> 16) & 1u);
    return (u16)(r >> 16);
}

// ---- weights f32 -> bf16. w_c1 gets the DWT folded in (stride-2 2x2 conv) ----
__global__ __launch_bounds__(256) void k_wconv(const float* __restrict__ w_c1,
                                               const float* __restrict__ pw1,
                                               const float* __restrict__ pw2,
                                               const float* __restrict__ w_c2,
                                               const float* __restrict__ gn_g,
                                               u16* __restrict__ wb) {
    int i = blockIdx.x * 256 + threadIdx.x;   // 0..163839
    float v;
    if (i < 65536) {
        int o = i >> 9, kn = i & 511;
        int c = kn >> 2, dy = (kn >> 1) & 1, dx = kn & 1;
        float sdy = dy ? -1.f : 1.f, sdx = dx ? -1.f : 1.f;
        const float* wr = w_c1 + o * 512 + c;
        v = 0.5f * (wr[0] + sdy * wr[128] + sdx * wr[256] + sdy * sdx * wr[384]);
    } else if (i < 81920) v = pw1[i - 65536] * gn_g[(i - 65536) & 127];
    else if (i < 98304) v = pw2[i - 81920];
    else v = w_c2[i - 98304];
    wb[i] = f2bf(v);
}

// ---- LN-fold vectors: wgs[o]=sum_c w*g, wbv[o]=sum_c w*b ----
__global__ __launch_bounds__(128) void k_wvec(const float* __restrict__ pw1,
                                              const float* __restrict__ gg,
                                              const float* __restrict__ gb,
                                              float* __restrict__ wbv,
                                              float* __restrict__ wgs) {
    int o = threadIdx.x;
    float a = 0.f, bv = 0.f;
    for (int c = 0; c < 128; ++c) {
        float w = pw1[o * 128 + c];
        a += w * gg[c];
        bv += w * gb[c];
    }
    wgs[o] = a;
    wbv[o] = bv;
}

// ---- fused DWT+conv1+BN1-stats: reads x f32 NCHW directly ----
// 512 threads (8 waves, 2 wr x 4 wc), full register double-buffer of x AND W.
__global__ __launch_bounds__(512) void k_conv1(const float* __restrict__ x,
                                               const u16* __restrict__ Wt,
                                               u16* __restrict__ Cout,
                                               float* __restrict__ statS,
                                               float* __restrict__ statQ) {
    __shared__ __align__(16) u16 lds[16384];   // A 16KB | B 16KB, then C bounce 32KB
    __shared__ float sblk[128], qblk[128];
    const int t = threadIdx.x;
    const int lane = t & 63, w = t >> 6, wr = w & 1, wc = w >> 1;   // wr 0..1, wc 0..3
    const int b = blockIdx.z, i = blockIdx.y;   // lowres row
    if (t < 128) { sblk[t] = 0.f; qblk[t] = 0.f; }

    const int r15 = lane & 15, kq = lane >> 4;
    const int half = t >> 8;
    const int colblk = t & 7, cc = (t >> 3) & 15, dy = (t >> 7) & 1;
    const int kbase = cc * 4 + dy * 2;
    const int gG = kbase >> 3, e2 = (kbase & 7) * 2;

    float4 xv[4];
    uint4 rb[2];
    {   // preload k0 = 0
        const float* xp = x + (((long)(b * Cc + cc)) * Hh + (2 * i + dy)) * Wf;
#pragma unroll
        for (int q = 0; q < 4; ++q) {
            int col = (half * 4 + q) * 32 + colblk * 4;
            xv[q] = *(const float4*)(xp + col);
        }
#pragma unroll
        for (int ii = 0; ii < 2; ++ii) {
            int s = ii * 512 + t;
            rb[ii] = *(const uint4*)(Wt + (long)(s >> 3) * 512 + (s & 7) * 8);
        }
    }

    f32x4 acc[4][2];
#pragma unroll
    for (int a2 = 0; a2 < 4; ++a2)
#pragma unroll
        for (int j2 = 0; j2 < 2; ++j2) acc[a2][j2] = (f32x4){0.f, 0.f, 0.f, 0.f};

    for (int k0 = 0; k0 < 512; k0 += 64) {
        __syncthreads();
#pragma unroll
        for (int q = 0; q < 4; ++q) {
            int col = (half * 4 + q) * 32 + colblk * 4;
            int j0 = col >> 1;
            u32 p0 = (u32)f2bf(xv[q].x) | ((u32)f2bf(xv[q].y) << 16);
            u32 p1 = (u32)f2bf(xv[q].z) | ((u32)f2bf(xv[q].w) << 16);
            *(u32*)((char*)lds + j0 * 128 + 16 * (gG ^ (j0 & 7)) + e2) = p0;
            *(u32*)((char*)lds + (j0 + 1) * 128 + 16 * (gG ^ ((j0 + 1) & 7)) + e2) = p1;
        }
#pragma unroll
        for (int ii = 0; ii < 2; ++ii) {
            int s = ii * 512 + t;
            int row_ = s >> 3, ch_ = s & 7;
            *(uint4*)((char*)lds + 16384 + row_ * 128 + 16 * (ch_ ^ (row_ & 7))) = rb[ii];
        }
        __syncthreads();
        if (k0 + 64 < 512) {
            const int c0n = (k0 + 64) >> 2;
            const float* xp = x + (((long)(b * Cc + c0n + cc)) * Hh + (2 * i + dy)) * Wf;
#pragma unroll
            for (int q = 0; q < 4; ++q) {
                int col = (half * 4 + q) * 32 + colblk * 4;
                xv[q] = *(const float4*)(xp + col);
            }
#pragma unroll
            for (int ii = 0; ii < 2; ++ii) {
                int s = ii * 512 + t;
                rb[ii] = *(const uint4*)(Wt + (long)(s >> 3) * 512 + (k0 + 64) + (s & 7) * 8);
            }
        }
#pragma unroll
        for (int ks = 0; ks < 2; ++ks) {
            short8 af[4], bfv[2];
            const int ch = ks * 4 + kq;
#pragma unroll
            for (int mi = 0; mi < 4; ++mi) {
                int row = wr * 64 + mi * 16 + r15;
                af[mi] = *(const short8*)((const char*)lds + row * 128 + 16 * (ch ^ (row & 7)));
            }
#pragma unroll
            for (int ni = 0; ni < 2; ++ni) {
                int row = wc * 32 + ni * 16 + r15;
                bfv[ni] = *(const short8*)((const char*)lds + 16384 + row * 128 + 16 * (ch ^ (row & 7)));
            }
#pragma unroll
            for (int mi = 0; mi < 4; ++mi)
#pragma unroll
                for (int ni = 0; ni < 2; ++ni)
                    acc[mi][ni] = __builtin_amdgcn_mfma_f32_16x16x32_bf16(
                        af[mi], bfv[ni], acc[mi][ni], 0, 0, 0);
        }
    }
    __syncthreads();

#pragma unroll
    for (int mi = 0; mi < 4; ++mi)
#pragma unroll
        for (int ni = 0; ni < 2; ++ni)
#pragma unroll
            for (int r = 0; r < 4; ++r) {
                int row = wr * 64 + mi * 16 + kq * 4 + r;
                int col = wc * 32 + ni * 16 + r15;
                lds[row * 128 + (col ^ ((row & 7) << 3))] = f2bf(acc[mi][ni][r]);
            }
#pragma unroll
    for (int ni = 0; ni < 2; ++ni) {
        float s = 0.f, q2 = 0.f;
#pragma unroll
        for (int mi = 0; mi < 4; ++mi)
#pragma unroll
            for (int r = 0; r < 4; ++r) {
                float v = acc[mi][ni][r];
                s += v; q2 += v * v;
            }
        s += __shfl_down(s, 32); s += __shfl_down(s, 16);
        q2 += __shfl_down(q2, 32); q2 += __shfl_down(q2, 16);
        if (lane < 16) {
            int col = wc * 32 + ni * 16 + r15;
            atomicAdd(&sblk[col], s);
            atomicAdd(&qblk[col], q2);
        }
    }
    __syncthreads();
    {
        u16* Cb = Cout + (long)b * HW2 * 128;
        int row = t >> 2, quarter = (t & 3) * 32;
        int sx = (row & 7) << 3;
        long gbase = (long)(i * 128 + row) * 128;
#pragma unroll
        for (int q = 0; q < 4; ++q) {
            int c = quarter + q * 8;
            *(uint4*)(Cb + gbase + c) = *(const uint4*)(lds + row * 128 + (c ^ sx));
        }
    }
    if (t < 128) {
        atomicAdd(statS + (long)t * 16, sblk[t]);
        atomicAdd(statQ + (long)t * 16, qblk[t]);
    }
}

// ---- depthwise 3x3 NHWC with fused BN1+gelu on load + LN stats ----
// Input is RAW conv1 output (bufA); transform applied once per tile element.
__global__ __launch_bounds__(256) void k_dwconv(const u16* __restrict__ xin,
                                                u16* __restrict__ y,
                                                const float* __restrict__ w,
                                                const float* __restrict__ bias,
                                                const float* __restrict__ bnS,
                                                const float* __restrict__ bnQ,
                                                const float* __restrict__ g1,
                                                const float* __restrict__ b1,
                                                float* __restrict__ lnS,
                                                float* __restrict__ lnQ) {
    __shared__ float wl2[1152];
    __shared__ float sA[128], sB[128];
    __shared__ __align__(16) u16 tile[3 * 18 * 136];   // px stride 136 (272B, 16B-aligned)
    const int t = threadIdx.x;
    if (t < 128) {
        const float invN = 1.0f / 131072.0f;
        float mu = bnS[(long)t * 16] * invN;
        float var = bnQ[(long)t * 16] * invN - mu * mu;
        float rs = rsqrtf(var + 1e-5f);
        float sc = rs * g1[t];
        sA[t] = sc;
        sB[t] = b1[t] - mu * sc;
    }
    for (int idx = t; idx < 1152; idx += 256) {
        int c = idx / 9, tap = idx - c * 9;
        wl2[tap * 128 + (c & 7) * 16 + (c >> 3)] = w[idx];
    }
    __syncthreads();
    const int jbase = blockIdx.x * 16, i = blockIdx.y, b = blockIdx.z;
    const u16* xb = xin + (long)b * HW2 * 128;
    // cooperative tile load + BN1 affine + gelu (54 slots x 16 segs)
    {
        int seg = t & 15, slot0 = t >> 4;
#pragma unroll
        for (int pass = 0; pass < 4; ++pass) {
            int slot = pass * 16 + slot0;
            if (slot < 54) {
                int r = slot / 18, p = slot - r * 18;
                int row = i - 1 + r, col = jbase - 1 + p;
                bool inb = (row >= 0) & (row < H2) & (col >= 0) & (col < W2);
                uint4 raw = inb ? *(const uint4*)(xb + ((long)row * W2 + col) * 128 + seg * 8)
                                : make_uint4(0u, 0u, 0u, 0u);
                const u16* pv = (const u16*)&raw;
                uint4 outv; u16* ov = (u16*)&outv;
#pragma unroll
                for (int u = 0; u < 8; ++u) {
                    int c = seg * 8 + u;
                    float v = inb ? gelu_f(bf2f(pv[u]) * sA[c] + sB[c]) : 0.f;
                    ov[u] = f2bf(v);
                }
                *(uint4*)(tile + slot * 136 + seg * 8) = outv;
            }
        }
    }
    __syncthreads();
    const int cg = t & 15, jj = t >> 4;
    float acc[8];
#pragma unroll
    for (int u = 0; u < 8; ++u) acc[u] = bias[cg * 8 + u];
#pragma unroll
    for (int r = 0; r < 3; ++r)
#pragma unroll
        for (int dj = 0; dj < 3; ++dj) {
            short8 vv = *(const short8*)(tile + (r * 18 + jj + dj) * 136 + cg * 8);
            const int tap = r * 3 + dj;
#pragma unroll
            for (int u = 0; u < 8; ++u)
                acc[u] = fmaf(bf2f((u16)vv[u]), wl2[tap * 128 + u * 16 + cg], acc[u]);
        }
    uint4 outv; u16* ov = (u16*)&outv;
    float s = 0.f, q2 = 0.f;
#pragma unroll
    for (int u = 0; u < 8; ++u) {
        ov[u] = f2bf(acc[u]);
        s += acc[u]; q2 += acc[u] * acc[u];
    }
    *(uint4*)(y + ((long)b * HW2 + (long)i * W2 + jbase + jj) * 128 + cg * 8) = outv;
#pragma unroll
    for (int off = 32; off; off >>= 1) {
        s += __shfl_down(s, off);
        q2 += __shfl_down(q2, off);
    }
    __shared__ float r1[4], r2[4];
    if ((t & 63) == 0) { r1[t >> 6] = s; r2[t >> 6] = q2; }
    __syncthreads();
    if (t == 0) {
        int slot = (blockIdx.y * 8 + blockIdx.x) & 63;
        atomicAdd(lnS + ((long)b * 64 + slot) * 16, r1[0] + r1[1] + r1[2] + r1[3]);
        atomicAdd(lnQ + ((long)b * 64 + slot) * 16, r2[0] + r2[1] + r2[2] + r2[3]);
    }
}

// ---- fused MLP: pw1 (LN-folded + gelu) -> pw2 (+bias + recomputed residual) ----
// Residual h = gelu(bn1(bufA)) recomputed in epilogue; bufH never materialized.
__global__ __launch_bounds__(256) void k_mlp(const u16* __restrict__ D,
                                             const u16* __restrict__ Wp1,
                                             const u16* __restrict__ Wp2,
                                             const float* __restrict__ b1p,
                                             const float* __restrict__ b2p,
                                             const u16* __restrict__ resA,
                                             u16* __restrict__ Yout,
                                             const float* __restrict__ lnS,
                                             const float* __restrict__ lnQ,
                                             const float* __restrict__ wbv,
                                             const float* __restrict__ wgs,
                                             const float* __restrict__ bnS,
                                             const float* __restrict__ bnQ,
                                             const float* __restrict__ g1,
                                             const float* __restrict__ b1v) {
    __shared__ __align__(16) u16 lA[16384];   // [2 chunk][128 row][64 k]
    __shared__ __align__(16) u16 lB[16384];
    __shared__ float s1[128], s2[128], sA[128], sB[128], lnred[2];
    const int t = threadIdx.x;
    const int lane = t & 63, w = t >> 6, wr = w >> 1, wc = w & 1;
    const int r15 = lane & 15, kq = lane >> 4;
    const int b = blockIdx.z, m0 = blockIdx.y * 128;

    if (t < 64) {
        float s = lnS[((long)b * 64 + t) * 16];
        float q = lnQ[((long)b * 64 + t) * 16];
#pragma unroll
        for (int off = 32; off; off >>= 1) {
            s += __shfl_down(s, off);
            q += __shfl_down(q, off);
        }
        if (t == 0) { lnred[0] = s; lnred[1] = q; }
    }
    __syncthreads();
    const float invN = 1.0f / 2097152.0f;
    float mu = lnred[0] * invN;
    float var = lnred[1] * invN - mu * mu;
    const float rs = rsqrtf(var + 1e-5f);
    if (t < 128) {
        s1[t] = b1p[t] + wbv[t] - mu * rs * wgs[t];
        s2[t] = b2p[t];
        const float invN1 = 1.0f / 131072.0f;
        float mu1 = bnS[(long)t * 16] * invN1;
        float var1 = bnQ[(long)t * 16] * invN1 - mu1 * mu1;
        float rs1 = rsqrtf(var1 + 1e-5f);
        float sc1 = rs1 * g1[t];
        sA[t] = sc1;
        sB[t] = b1v[t] - mu1 * sc1;
    }

    const u16* Ab = D + ((long)b * HW2 + m0) * 128;
    uint4 ga[8], gb[8];
#pragma unroll
    for (int i = 0; i < 8; ++i) {
        int s = i * 256 + t, row = s >> 4, seg = s & 15;
        ga[i] = *(const uint4*)(Ab + (long)row * 128 + seg * 8);
        gb[i] = *(const uint4*)(Wp1 + (long)row * 128 + seg * 8);
    }
#pragma unroll
    for (int i = 0; i < 8; ++i) {
        int s = i * 256 + t, row = s >> 4, seg = s & 15;
        int off = (seg >> 3) * 16384 + row * 128 + 16 * ((seg & 7) ^ (row & 7));
        *(uint4*)((char*)lA + off) = ga[i];
        *(uint4*)((char*)lB + off) = gb[i];
    }
    __syncthreads();

    f32x4 acc[4][4];
#pragma unroll
    for (int i = 0; i < 4; ++i)
#pragma unroll
        for (int j = 0; j < 4; ++j) acc[i][j] = (f32x4){0.f, 0.f, 0.f, 0.f};
#pragma unroll
    for (int chunk = 0; chunk < 2; ++chunk)
#pragma unroll
        for (int ks = 0; ks < 2; ++ks) {
            const int ch = ks * 4 + kq;
            short8 af[4], bfv[4];
#pragma unroll
            for (int mi = 0; mi < 4; ++mi) {
                int row = wr * 64 + mi * 16 + r15;
                af[mi] = *(const short8*)((const char*)lA + chunk * 16384 +
                                          row * 128 + 16 * (ch ^ (row & 7)));
            }
#pragma unroll
            for (int ni = 0; ni < 4; ++ni) {
                int row = wc * 64 + ni * 16 + r15;
                bfv[ni] = *(const short8*)((const char*)lB + chunk * 16384 +
                                           row * 128 + 16 * (ch ^ (row & 7)));
            }
#pragma unroll
            for (int mi = 0; mi < 4; ++mi)
#pragma unroll
                for (int ni = 0; ni < 4; ++ni)
                    acc[mi][ni] = __builtin_amdgcn_mfma_f32_16x16x32_bf16(
                        af[mi], bfv[ni], acc[mi][ni], 0, 0, 0);
        }
#pragma unroll
    for (int i = 0; i < 8; ++i) {
        int s = i * 256 + t, row = s >> 4, seg = s & 15;
        gb[i] = *(const uint4*)(Wp2 + (long)row * 128 + seg * 8);
    }
    __syncthreads();

    // bounce1: gelu(rs*acc + s1[ch]) -> lA in GEMM-A k-major layout (k = ch)
#pragma unroll
    for (int mi = 0; mi < 4; ++mi)
#pragma unroll
        for (int ni = 0; ni < 4; ++ni)
#pragma unroll
            for (int r = 0; r < 4; ++r) {
                int row = wr * 64 + mi * 16 + kq * 4 + r;
                int col = wc * 64 + ni * 16 + r15;
                float v = gelu_f(rs * acc[mi][ni][r] + s1[col]);
                lA[(col >> 6) * 8192 + row * 64 +
                   8 * (((col >> 3) & 7) ^ (row & 7)) + (col & 7)] = f2bf(v);
            }
#pragma unroll
    for (int i = 0; i < 8; ++i) {
        int s = i * 256 + t, row = s >> 4, seg = s & 15;
        int off = (seg >> 3) * 16384 + row * 128 + 16 * ((seg & 7) ^ (row & 7));
        *(uint4*)((char*)lB + off) = gb[i];
    }
    __syncthreads();

    // GEMM2
#pragma unroll
    for (int i = 0; i < 4; ++i)
#pragma unroll
        for (int j = 0; j < 4; ++j) acc[i][j] = (f32x4){0.f, 0.f, 0.f, 0.f};
#pragma unroll
    for (int chunk = 0; chunk < 2; ++chunk)
#pragma unroll
        for (int ks = 0; ks < 2; ++ks) {
            const int ch = ks * 4 + kq;
            short8 af[4], bfv[4];
#pragma unroll
            for (int mi = 0; mi < 4; ++mi) {
                int row = wr * 64 + mi * 16 + r15;
                af[mi] = *(const short8*)((const char*)lA + chunk * 16384 +
                                          row * 128 + 16 * (ch ^ (row & 7)));
            }
#pragma unroll
            for (int ni = 0; ni < 4; ++ni) {
                int row = wc * 64 + ni * 16 + r15;
                bfv[ni] = *(const short8*)((const char*)lB + chunk * 16384 +
                                           row * 128 + 16 * (ch ^ (row & 7)));
            }
#pragma unroll
            for (int mi = 0; mi < 4; ++mi)
#pragma unroll
                for (int ni = 0; ni < 4; ++ni)
                    acc[mi][ni] = __builtin_amdgcn_mfma_f32_16x16x32_bf16(
                        af[mi], bfv[ni], acc[mi][ni], 0, 0, 0);
        }
    __syncthreads();

#pragma unroll
    for (int mi = 0; mi < 4; ++mi)
#pragma unroll
        for (int ni = 0; ni < 4; ++ni)
#pragma unroll
            for (int r = 0; r < 4; ++r) {
                int row = wr * 64 + mi * 16 + kq * 4 + r;
                int col = wc * 64 + ni * 16 + r15;
                lA[row * 128 + (col ^ ((row & 7) << 3))] = f2bf(acc[mi][ni][r]);
            }
    __syncthreads();

    const u16* Ra = resA + ((long)b * HW2 + m0) * 128;
    u16* Cb = Yout + ((long)b * HW2 + m0) * 128;
    {
        int row = t >> 1, half = (t & 1) * 64;
        int sx = (row & 7) << 3;
#pragma unroll
        for (int q = 0; q < 8; ++q) {
            int c = half + q * 8;
            uint4 raw = *(const uint4*)(lA + row * 128 + (c ^ sx));
            uint4 rr = *(const uint4*)(Ra + (long)row * 128 + c);
            u16* pv = (u16*)&raw;
            const u16* rv = (const u16*)&rr;
#pragma unroll
            for (int u = 0; u < 8; ++u) {
                float hres = gelu_f(bf2f(rv[u]) * sA[c + u] + sB[c + u]);
                pv[u] = f2bf(bf2f(pv[u]) + s2[c + u] + hres);
            }
            *(uint4*)(Cb + (long)row * 128 + c) = raw;
        }
    }
}

// ---- second moment partials: M2p[blk] = Y_blk^T Y_blk (non-atomic stores) ----
__global__ __launch_bounds__(256) void k_moment(const u16* __restrict__ Y,
                                                float* __restrict__ M2p,
                                                float* __restrict__ csum) {
    __shared__ __align__(16) u16 T[8192];
    __shared__ float cred[16][16][8];
    const int t = threadIdx.x;
    const int lane = t & 63, w = t >> 6, wr = w >> 1, wc = w & 1;
    const int r15 = lane & 15, kq = lane >> 4;
    const long px0 = (long)blockIdx.x * 1024;
    float cs[8] = {};

    f32x4 acc[4][4];
#pragma unroll
    for (int i = 0; i < 4; ++i)
#pragma unroll
        for (int j = 0; j < 4; ++j) acc[i][j] = (f32x4){0.f, 0.f, 0.f, 0.f};

    for (int it = 0; it < 16; ++it) {
        uint4 rv[4];
#pragma unroll
        for (int i = 0; i < 4; ++i) {
            int s = i * 256 + t;
            int px = s >> 4, ch8 = (s & 15) * 8;
            rv[i] = *(const uint4*)(Y + (px0 + it * 64 + px) * 128 + ch8);
        }
#pragma unroll
        for (int i = 0; i < 4; ++i) {
            const u16* pv = (const u16*)&rv[i];
#pragma unroll
            for (int u = 0; u < 8; ++u) cs[u] += bf2f(pv[u]);
        }
        __syncthreads();
#pragma unroll
        for (int i = 0; i < 4; ++i) {
            int s = i * 256 + t;
            int px = s >> 4, ch8 = (s & 15) * 8;
            const u16* pv = (const u16*)&rv[i];
#pragma unroll
            for (int u = 0; u < 8; ++u) {
                int row = ch8 + u;
                T[row * 64 + 8 * ((px >> 3) ^ (row & 7)) + (px & 7)] = pv[u];
            }
        }
        __syncthreads();
#pragma unroll
        for (int ks = 0; ks < 2; ++ks) {
            const int ch = ks * 4 + kq;
            short8 af[4], bfv[4];
#pragma unroll
            for (int mi = 0; mi < 4; ++mi) {
                int row = wr * 64 + mi * 16 + r15;
                af[mi] = *(const short8*)(T + row * 64 + 8 * (ch ^ (row & 7)));
            }
#pragma unroll
            for (int ni = 0; ni < 4; ++ni) {
                int row = wc * 64 + ni * 16 + r15;
                bfv[ni] = *(const short8*)(T + row * 64 + 8 * (ch ^ (row & 7)));
            }
#pragma unroll
            for (int mi = 0; mi < 4; ++mi)
#pragma unroll
                for (int ni = 0; ni < 4; ++ni)
                    acc[mi][ni] = __builtin_amdgcn_mfma_f32_16x16x32_bf16(
                        af[mi], bfv[ni], acc[mi][ni], 0, 0, 0);
        }
    }
    {
        int g = t & 15, m = t >> 4;
#pragma unroll
        for (int u = 0; u < 8; ++u) cred[m][g][u] = cs[u];
    }
    __syncthreads();
    if (t < 128) {
        float s = 0.f;
#pragma unroll
        for (int m = 0; m < 16; ++m) s += cred[m][t >> 3][t & 7];
        atomicAdd(csum + (long)t * 16, s);
    }
    float* Mb = M2p + (long)blockIdx.x * 16384;
#pragma unroll
    for (int mi = 0; mi < 4; ++mi)
#pragma unroll
        for (int ni = 0; ni < 4; ++ni)
#pragma unroll
            for (int r = 0; r < 4; ++r) {
                int row = wr * 64 + mi * 16 + kq * 4 + r;
                int col = wc * 64 + ni * 16 + r15;
                Mb[row * 128 + col] = acc[mi][ni][r];
            }
}

// ---- reduce 128 M2 partials -> M2 dense ----
__global__ __launch_bounds__(256) void k_m2red(const float* __restrict__ M2p,
                                               float* __restrict__ M2) {
    int e = blockIdx.x * 256 + threadIdx.x;   // 16384 elements
    float s = 0.f;
    for (int p = 0; p < 128; ++p) s += M2p[(long)p * 16384 + e];
    M2[e] = s;
}

// ---- combine: per-out-channel BN2 scale/shift ----
__global__ __launch_bounds__(128) void k_statcomb(const float* __restrict__ w_c2,
                                                  const float* __restrict__ M2,
                                                  const float* __restrict__ csum,
                                                  const float* __restrict__ g,
                                                  const float* __restrict__ bb,
                                                  float* __restrict__ scsh) {
    __shared__ float wl[128];
    __shared__ float red[2][2];
    const int o = blockIdx.x, c = threadIdx.x;
    wl[c] = w_c2[o * 128 + c];
    __syncthreads();
    const float* m2r = M2 + c * 128;
    float tmp = 0.f;
#pragma unroll
    for (int c2 = 0; c2 < 128; c2 += 4) {
        float4 m = *(const float4*)(m2r + c2);
        tmp += m.x * wl[c2] + m.y * wl[c2 + 1] + m.z * wl[c2 + 2] + m.w * wl[c2 + 3];
    }
    float s2p = wl[c] * tmp;
    float mup = wl[c] * csum[(long)c * 16];
#pragma unroll
    for (int off = 32; off; off >>= 1) {
        s2p += __shfl_down(s2p, off);
        mup += __shfl_down(mup, off);
    }
    if ((c & 63) == 0) { red[0][c >> 6] = s2p; red[1][c >> 6] = mup; }
    __syncthreads();
    if (c == 0) {
        float s2 = (red[0][0] + red[0][1]) / NPIX;
        float mu = (red[1][0] + red[1][1]) / NPIX;
        float var = s2 - mu * mu;
        float rs = rsqrtf(var + 1e-5f);
        float sc = g[o] * rs;
        scsh[o] = sc;
        scsh[512 + o] = bb[o] - mu * sc;
    }
}

// ---- conv2 + BN2 + GELU + IDWT -> out f32 NCHW; 512 threads (8 waves, 2x4) ----
__global__ __launch_bounds__(512) void k_conv2_idwt(const u16* __restrict__ Y,
                                                    const u16* __restrict__ Wc,
                                                    const float* __restrict__ scsh,
                                                    float* __restrict__ out) {
    __shared__ __align__(16) u16 lA[16384];  // [2 chunk][128 row][64 k]
    __shared__ __align__(16) u16 lB[8192];   // [2 chunk][64 row][64 k]
    __shared__ float sparam[1024];
    const int t = threadIdx.x;
    const int lane = t & 63, w = t >> 6, wr = w & 1, wc = w >> 1;  // wr 0..1, wc 0..3
    const int r15 = lane & 15, kq = lane >> 4;
    const int b = blockIdx.y, n0 = blockIdx.x;
#pragma unroll
    for (int u = 0; u < 2; ++u) sparam[t + u * 512] = scsh[t + u * 512];

    const u16* Yb = Y + ((long)b * HW2 + (long)n0 * 64) * 128;
    uint4 rb2[2], ra4[4];
#pragma unroll
    for (int i = 0; i < 2; ++i) {
        int s = i * 512 + t, row = s >> 4, seg = s & 15;
        rb2[i] = *(const uint4*)(Yb + (long)row * 128 + seg * 8);
    }
#define GLOADA(q)                                                                \
    {                                                                            \
        _Pragma("unroll")                                                        \
        for (int i = 0; i < 4; ++i) {                                            \
            int s = i * 512 + t, row = s >> 4, seg = s & 15;                     \
            ra4[i] = *(const uint4*)(Wc + (long)((q) * 128 + row) * 128 + seg * 8); \
        }                                                                        \
    }
#define LWRITEA()                                                                \
    {                                                                            \
        _Pragma("unroll")                                                        \
        for (int i = 0; i < 4; ++i) {                                            \
            int s = i * 512 + t, row = s >> 4, seg = s & 15;                     \
            *(uint4*)((char*)lA + (seg >> 3) * 16384 + row * 128 +               \
                      16 * ((seg & 7) ^ (row & 7))) = ra4[i];                    \
        }                                                                        \
    }
    GLOADA(0)
#pragma unroll
    for (int i = 0; i < 2; ++i) {
        int s = i * 512 + t, row = s >> 4, seg = s & 15;
        *(uint4*)((char*)lB + (seg >> 3) * 8192 + row * 128 +
                  16 * ((seg & 7) ^ (row & 7))) = rb2[i];
    }
    LWRITEA()
    __syncthreads();

    u32 sbp[4][4][2];   // [q][mi][rp]
#pragma unroll
    for (int q = 0; q < 4; ++q) {
        f32x4 acc[4];
#pragma unroll
        for (int mi = 0; mi < 4; ++mi) acc[mi] = (f32x4){0.f, 0.f, 0.f, 0.f};
#pragma unroll
        for (int chunk = 0; chunk < 2; ++chunk)
#pragma unroll
            for (int ks = 0; ks < 2; ++ks) {
                const int ch = ks * 4 + kq;
                short8 af[4], bfv;
#pragma unroll
                for (int mi = 0; mi < 4; ++mi) {
                    int row = wr * 64 + mi * 16 + r15;
                    af[mi] = *(const short8*)((const char*)lA + chunk * 16384 +
                                              row * 128 + 16 * (ch ^ (row & 7)));
                }
                {
                    int row = wc * 16 + r15;
                    bfv = *(const short8*)((const char*)lB + chunk * 8192 +
                                           row * 128 + 16 * (ch ^ (row & 7)));
                }
#pragma unroll
                for (int mi = 0; mi < 4; ++mi)
                    acc[mi] = __builtin_amdgcn_mfma_f32_16x16x32_bf16(
                        af[mi], bfv, acc[mi], 0, 0, 0);
            }
        if (q < 3) GLOADA(q + 1)
#pragma unroll
        for (int mi = 0; mi < 4; ++mi)
#pragma unroll
            for (int rp = 0; rp < 2; ++rp) {
                int c0 = q * 128 + wr * 64 + mi * 16 + kq * 4 + rp * 2;
                float v0 = gelu_f(acc[mi][rp * 2] * sparam[c0] + sparam[512 + c0]);
                float v1 = gelu_f(acc[mi][rp * 2 + 1] * sparam[c0 + 1] + sparam[512 + c0 + 1]);
                sbp[q][mi][rp] = (u32)f2bf(v0) | ((u32)f2bf(v1) << 16);
            }
        if (q < 3) {
            __syncthreads();
            LWRITEA()
            __syncthreads();
        }
    }
    const int i = n0 >> 1;
    const int j = (n0 & 1) * 64 + wc * 16 + r15;
#pragma unroll
    for (int mi = 0; mi < 4; ++mi)
#pragma unroll
        for (int rp = 0; rp < 2; ++rp) {
            u32 p0 = sbp[0][mi][rp], p1 = sbp[1][mi][rp];
            u32 p2 = sbp[2][mi][rp], p3 = sbp[3][mi][rp];
#pragma unroll
            for (int e = 0; e < 2; ++e) {
                int c = wr * 64 + mi * 16 + kq * 4 + rp * 2 + e;
                float ll = bf2f(e ? (u16)(p0 >> 16) : (u16)(p0 & 0xFFFF));
                float lh = bf2f(e ? (u16)(p1 >> 16) : (u16)(p1 & 0xFFFF));
                float hl = bf2f(e ? (u16)(p2 >> 16) : (u16)(p2 & 0xFFFF));
                float hh = bf2f(e ? (u16)(p3 >> 16) : (u16)(p3 & 0xFFFF));
                long ob = (((long)(b * Cc + c) * Hh + 2 * i) * Wf + 2 * j);
                *(float2*)(out + ob) =
                    make_float2((ll + lh + hl + hh) * 0.5f, (ll + lh - hl - hh) * 0.5f);
                *(float2*)(out + ob + Wf) =
                    make_float2((ll - lh + hl - hh) * 0.5f, (ll - lh - hl + hh) * 0.5f);
            }
        }
#undef GLOADA
#undef LWRITEA
}

extern "C" void kernel_launch(void* const* d_in, const int* in_sizes, int n_in,
                              void* d_out, int out_size, void* d_ws, size_t ws_size,
                              hipStream_t stream) {
    const float* x     = (const float*)d_in[0];
    const float* w_c1  = (const float*)d_in[1];
    const float* bn1_g = (const float*)d_in[3];
    const float* bn1_b = (const float*)d_in[4];
    const float* dw_w  = (const float*)d_in[5];
    const float* dw_b  = (const float*)d_in[6];
    const float* gn_g  = (const float*)d_in[7];
    const float* gn_b  = (const float*)d_in[8];
    const float* pw1_w = (const float*)d_in[9];
    const float* pw1_b = (const float*)d_in[10];
    const float* pw2_w = (const float*)d_in[11];
    const float* pw2_b = (const float*)d_in[12];
    const float* w_c2  = (const float*)d_in[13];
    const float* bn2_g = (const float*)d_in[15];
    const float* bn2_b = (const float*)d_in[16];
    float* out = (float*)d_out;

    const size_t n128 = (size_t)Bq * Cc * HW2;
    u16* bufA = (u16*)d_ws;        // conv1 raw out [b][px][128] (also MLP residual src)
    u16* bufD = bufA + n128;       // dwconv out (post BN1+gelu conv)
    u16* bufY = bufD + n128;       // MLP out (= conv2 input)
    u16* wb   = bufY + n128;       // bf16 weights: W'c1|pw1g|pw2|w_c2
    float* stats = (float*)(wb + 163840);
    float* M2p = stats + 49152;    // 128 x 16384 f32 partials (8 MB)
    size_t need = (3 * n128 + 163840) * 2 + (49152 + 128 * 16384) * 4;
    if (ws_size < need) return;

    float* bn1_sum = stats;            // 128 x16 padded
    float* bn1_sq  = stats + 2048;
    float* ln_sum  = stats + 4096;     // 8x64 x16 padded
    float* ln_sq   = stats + 12288;
    float* csum    = stats + 20480;    // 128 x16 padded
    float* M2      = stats + 22528;    // 128x128 dense (written by k_m2red)
    float* scsh    = stats + 38912;    // 512 scale | 512 shift
    float* wbv     = stats + 39936;
    float* wgs     = stats + 40064;

    hipMemsetAsync(stats, 0, 22528 * sizeof(float), stream);

    // 0. weights -> bf16 (w_c1 with DWT folded; pw1 pre-scaled by gn_g)
    k_wconv<<<640, 256, 0, stream>>>(w_c1, pw1_w, pw2_w, w_c2, gn_g, wb);
    k_wvec<<<1, 128, 0, stream>>>(pw1_w, gn_g, gn_b, wbv, wgs);

    // 1. fused DWT + conv1 + BN1 stats
    k_conv1<<<dim3(1, 128, 8), 512, 0, stream>>>(x, wb, bufA, bn1_sum, bn1_sq);

    // 2. depthwise 3x3 with fused BN1+gelu on load + LN stats (bufH eliminated)
    k_dwconv<<<dim3(8, 128, 8), 256, 0, stream>>>(bufA, bufD, dw_w, dw_b,
                                                  bn1_sum, bn1_sq, bn1_g, bn1_b,
                                                  ln_sum, ln_sq);

    // 3. fused MLP: pw1 (LN-folded + gelu) -> pw2 (+bias + recomputed residual)
    k_mlp<<<dim3(1, 128, 8), 256, 0, stream>>>(
        bufD, wb + 65536, wb + 81920, pw1_b, pw2_b, bufA, bufY,
        ln_sum, ln_sq, wbv, wgs, bn1_sum, bn1_sq, bn1_g, bn1_b);

    // 4. BN2 stats: per-block M2 partials (non-atomic) + reduce + combine
    k_moment<<<128, 256, 0, stream>>>(bufY, M2p, csum);
    k_m2red<<<64, 256, 0, stream>>>(M2p, M2);
    k_statcomb<<<512, 128, 0, stream>>>(w_c2, M2, csum, bn2_g, bn2_b, scsh);

    // 5. conv2 + BN2 + gelu + IDWT -> out
    k_conv2_idwt<<<dim3(256, 8), 512, 0, stream>>>(bufY, wb + 98304, scsh, out);
}

// Round 12
// 410.676 us; speedup vs baseline: 2.2441x; 1.0312x over previous
//
#include <hip/hip_runtime.h>
#include <hip/hip_bf16.h>

typedef unsigned short u16;
typedef unsigned int u32;
typedef unsigned long long u64;
typedef __attribute__((ext_vector_type(8))) short short8;
typedef __attribute__((ext_vector_type(4))) float f32x4;

#define Bq 8
#define Cc 128
#define C4 512
#define Hh 256
#define Wf 256
#define H2 128
#define W2 128
#define HW2 16384
#define NPIX 131072.0f

// tanh-approx GELU: max abs err ~1e-3, well under the 0.134 budget
__device__ __forceinline__ float gelu_f(float x) {
    float u = 1.5957691216057308f * (x + 0.044715f * x * x * x);
    float t = 1.0f - 2.0f / (__expf(u) + 1.0f);
    return 0.5f * x * (1.0f + t);
}
__device__ __forceinline__ float bf2f(u16 u) {
    union { float f; u32 i; } v; v.i = ((u32)u) << 16; return v.f;
}
__device__ __forceinline__ u16 f2bf(float f) {
    union { float f; u32 i; } v; v.f = f;
    u32 r = v.i + 0x7FFFu + ((v.i >> 16) & 1u);
    return (u16)(r >> 16);
}

// ---- weights f32 -> bf16 (+ LN-fold vectors in block 640) ----
__global__ __launch_bounds__(256) void k_wconv(const float* __restrict__ w_c1,
                                               const float* __restrict__ pw1,
                                               const float* __restrict__ pw2,
                                               const float* __restrict__ w_c2,
                                               const float* __restrict__ gn_g,
                                               const float* __restrict__ gn_b,
                                               u16* __restrict__ wb,
                                               float* __restrict__ wbv,
                                               float* __restrict__ wgs) {
    if (blockIdx.x == 640) {
        int o = threadIdx.x;
        if (o < 128) {
            float a = 0.f, bv = 0.f;
            for (int c = 0; c < 128; ++c) {
                float w_ = pw1[o * 128 + c];
                a += w_ * gn_g[c];
                bv += w_ * gn_b[c];
            }
            wgs[o] = a;
            wbv[o] = bv;
        }
        return;
    }
    int i = blockIdx.x * 256 + threadIdx.x;   // 0..163839
    float v;
    if (i < 65536) {
        int o = i >> 9, kn = i & 511;
        int c = kn >> 2, dy = (kn >> 1) & 1, dx = kn & 1;
        float sdy = dy ? -1.f : 1.f, sdx = dx ? -1.f : 1.f;
        const float* wr = w_c1 + o * 512 + c;
        v = 0.5f * (wr[0] + sdy * wr[128] + sdx * wr[256] + sdy * sdx * wr[384]);
    } else if (i < 81920) v = pw1[i - 65536] * gn_g[(i - 65536) & 127];
    else if (i < 98304) v = pw2[i - 81920];
    else v = w_c2[i - 98304];
    wb[i] = f2bf(v);
}

// ---- fused DWT+conv1+BN1-stats: reads x f32 NCHW directly ----
// 512 threads (8 waves, 2 wr x 4 wc), full register double-buffer of x AND W.
__global__ __launch_bounds__(512) void k_conv1(const float* __restrict__ x,
                                               const u16* __restrict__ Wt,
                                               u16* __restrict__ Cout,
                                               float* __restrict__ statS,
                                               float* __restrict__ statQ) {
    __shared__ __align__(16) u16 lds[16384];   // A 16KB | B 16KB, then C bounce 32KB
    __shared__ float sblk[128], qblk[128];
    const int t = threadIdx.x;
    const int lane = t & 63, w = t >> 6, wr = w & 1, wc = w >> 1;   // wr 0..1, wc 0..3
    const int b = blockIdx.z, i = blockIdx.y;   // lowres row
    if (t < 128) { sblk[t] = 0.f; qblk[t] = 0.f; }

    const int r15 = lane & 15, kq = lane >> 4;
    const int half = t >> 8;
    const int colblk = t & 7, cc = (t >> 3) & 15, dy = (t >> 7) & 1;
    const int kbase = cc * 4 + dy * 2;
    const int gG = kbase >> 3, e2 = (kbase & 7) * 2;

    float4 xv[4];
    uint4 rb[2];
    {   // preload k0 = 0
        const float* xp = x + (((long)(b * Cc + cc)) * Hh + (2 * i + dy)) * Wf;
#pragma unroll
        for (int q = 0; q < 4; ++q) {
            int col = (half * 4 + q) * 32 + colblk * 4;
            xv[q] = *(const float4*)(xp + col);
        }
#pragma unroll
        for (int ii = 0; ii < 2; ++ii) {
            int s = ii * 512 + t;
            rb[ii] = *(const uint4*)(Wt + (long)(s >> 3) * 512 + (s & 7) * 8);
        }
    }

    f32x4 acc[4][2];
#pragma unroll
    for (int a2 = 0; a2 < 4; ++a2)
#pragma unroll
        for (int j2 = 0; j2 < 2; ++j2) acc[a2][j2] = (f32x4){0.f, 0.f, 0.f, 0.f};

    for (int k0 = 0; k0 < 512; k0 += 64) {
        __syncthreads();
#pragma unroll
        for (int q = 0; q < 4; ++q) {
            int col = (half * 4 + q) * 32 + colblk * 4;
            int j0 = col >> 1;
            u32 p0 = (u32)f2bf(xv[q].x) | ((u32)f2bf(xv[q].y) << 16);
            u32 p1 = (u32)f2bf(xv[q].z) | ((u32)f2bf(xv[q].w) << 16);
            *(u32*)((char*)lds + j0 * 128 + 16 * (gG ^ (j0 & 7)) + e2) = p0;
            *(u32*)((char*)lds + (j0 + 1) * 128 + 16 * (gG ^ ((j0 + 1) & 7)) + e2) = p1;
        }
#pragma unroll
        for (int ii = 0; ii < 2; ++ii) {
            int s = ii * 512 + t;
            int row_ = s >> 3, ch_ = s & 7;
            *(uint4*)((char*)lds + 16384 + row_ * 128 + 16 * (ch_ ^ (row_ & 7))) = rb[ii];
        }
        __syncthreads();
        if (k0 + 64 < 512) {
            const int c0n = (k0 + 64) >> 2;
            const float* xp = x + (((long)(b * Cc + c0n + cc)) * Hh + (2 * i + dy)) * Wf;
#pragma unroll
            for (int q = 0; q < 4; ++q) {
                int col = (half * 4 + q) * 32 + colblk * 4;
                xv[q] = *(const float4*)(xp + col);
            }
#pragma unroll
            for (int ii = 0; ii < 2; ++ii) {
                int s = ii * 512 + t;
                rb[ii] = *(const uint4*)(Wt + (long)(s >> 3) * 512 + (k0 + 64) + (s & 7) * 8);
            }
        }
#pragma unroll
        for (int ks = 0; ks < 2; ++ks) {
            short8 af[4], bfv[2];
            const int ch = ks * 4 + kq;
#pragma unroll
            for (int mi = 0; mi < 4; ++mi) {
                int row = wr * 64 + mi * 16 + r15;
                af[mi] = *(const short8*)((const char*)lds + row * 128 + 16 * (ch ^ (row & 7)));
            }
#pragma unroll
            for (int ni = 0; ni < 2; ++ni) {
                int row = wc * 32 + ni * 16 + r15;
                bfv[ni] = *(const short8*)((const char*)lds + 16384 + row * 128 + 16 * (ch ^ (row & 7)));
            }
#pragma unroll
            for (int mi = 0; mi < 4; ++mi)
#pragma unroll
                for (int ni = 0; ni < 2; ++ni)
                    acc[mi][ni] = __builtin_amdgcn_mfma_f32_16x16x32_bf16(
                        af[mi], bfv[ni], acc[mi][ni], 0, 0, 0);
        }
    }
    __syncthreads();

#pragma unroll
    for (int mi = 0; mi < 4; ++mi)
#pragma unroll
        for (int ni = 0; ni < 2; ++ni)
#pragma unroll
            for (int r = 0; r < 4; ++r) {
                int row = wr * 64 + mi * 16 + kq * 4 + r;
                int col = wc * 32 + ni * 16 + r15;
                lds[row * 128 + (col ^ ((row & 7) << 3))] = f2bf(acc[mi][ni][r]);
            }
#pragma unroll
    for (int ni = 0; ni < 2; ++ni) {
        float s = 0.f, q2 = 0.f;
#pragma unroll
        for (int mi = 0; mi < 4; ++mi)
#pragma unroll
            for (int r = 0; r < 4; ++r) {
                float v = acc[mi][ni][r];
                s += v; q2 += v * v;
            }
        s += __shfl_down(s, 32); s += __shfl_down(s, 16);
        q2 += __shfl_down(q2, 32); q2 += __shfl_down(q2, 16);
        if (lane < 16) {
            int col = wc * 32 + ni * 16 + r15;
            atomicAdd(&sblk[col], s);
            atomicAdd(&qblk[col], q2);
        }
    }
    __syncthreads();
    {
        u16* Cb = Cout + (long)b * HW2 * 128;
        int row = t >> 2, quarter = (t & 3) * 32;
        int sx = (row & 7) << 3;
        long gbase = (long)(i * 128 + row) * 128;
#pragma unroll
        for (int q = 0; q < 4; ++q) {
            int c = quarter + q * 8;
            *(uint4*)(Cb + gbase + c) = *(const uint4*)(lds + row * 128 + (c ^ sx));
        }
    }
    if (t < 128) {
        atomicAdd(statS + (long)t * 16, sblk[t]);
        atomicAdd(statQ + (long)t * 16, qblk[t]);
    }
}

// ---- depthwise 3x3 NHWC, 4-row tile (halo 1.69x), fused BN1+gelu + LN stats ----
__global__ __launch_bounds__(256) void k_dwconv(const u16* __restrict__ xin,
                                                u16* __restrict__ y,
                                                const float* __restrict__ w,
                                                const float* __restrict__ bias,
                                                const float* __restrict__ bnS,
                                                const float* __restrict__ bnQ,
                                                const float* __restrict__ g1,
                                                const float* __restrict__ b1,
                                                float* __restrict__ lnS,
                                                float* __restrict__ lnQ) {
    __shared__ float wl2[1152];
    __shared__ float sA[128], sB[128];
    __shared__ __align__(16) u16 tile[108 * 136];   // 6 rows x 18 cols halo
    const int t = threadIdx.x;
    if (t < 128) {
        const float invN = 1.0f / 131072.0f;
        float mu = bnS[(long)t * 16] * invN;
        float var = bnQ[(long)t * 16] * invN - mu * mu;
        float rs = rsqrtf(var + 1e-5f);
        float sc = rs * g1[t];
        sA[t] = sc;
        sB[t] = b1[t] - mu * sc;
    }
    for (int idx = t; idx < 1152; idx += 256) {
        int c = idx / 9, tap = idx - c * 9;
        wl2[tap * 128 + (c & 7) * 16 + (c >> 3)] = w[idx];
    }
    __syncthreads();
    const int jbase = blockIdx.x * 16, i0 = blockIdx.y * 4, b = blockIdx.z;
    const u16* xb = xin + (long)b * HW2 * 128;
    // cooperative halo load + BN1 affine + gelu (108 slots x 16 segs)
    {
        int seg = t & 15, slot0 = t >> 4;
#pragma unroll
        for (int pass = 0; pass < 7; ++pass) {
            int slot = pass * 16 + slot0;
            if (slot < 108) {
                int r = slot / 18, p = slot - r * 18;
                int row = i0 - 1 + r, col = jbase - 1 + p;
                bool inb = (row >= 0) & (row < H2) & (col >= 0) & (col < W2);
                uint4 raw = inb ? *(const uint4*)(xb + ((long)row * W2 + col) * 128 + seg * 8)
                                : make_uint4(0u, 0u, 0u, 0u);
                const u16* pv = (const u16*)&raw;
                uint4 outv; u16* ov = (u16*)&outv;
#pragma unroll
                for (int u = 0; u < 8; ++u) {
                    int c = seg * 8 + u;
                    float v = inb ? gelu_f(bf2f(pv[u]) * sA[c] + sB[c]) : 0.f;
                    ov[u] = f2bf(v);
                }
                *(uint4*)(tile + slot * 136 + seg * 8) = outv;
            }
        }
    }
    __syncthreads();
    const int cg = t & 15, jj = t >> 4;
    float s = 0.f, q2 = 0.f;
    float wreg[9];
#pragma unroll
    for (int tap = 0; tap < 9; ++tap) {
        // preload per-thread weight rows are channel-dependent: handled inline below
        wreg[tap] = 0.f;   // placeholder to keep array (unused)
    }
    float bi[8];
#pragma unroll
    for (int u = 0; u < 8; ++u) bi[u] = bias[cg * 8 + u];
#pragma unroll
    for (int dr = 0; dr < 4; ++dr) {
        float acc[8];
#pragma unroll
        for (int u = 0; u < 8; ++u) acc[u] = bi[u];
#pragma unroll
        for (int r = 0; r < 3; ++r)
#pragma unroll
            for (int dj = 0; dj < 3; ++dj) {
                short8 vv = *(const short8*)(tile + ((dr + r) * 18 + jj + dj) * 136 + cg * 8);
                const int tap = r * 3 + dj;
#pragma unroll
                for (int u = 0; u < 8; ++u)
                    acc[u] = fmaf(bf2f((u16)vv[u]), wl2[tap * 128 + u * 16 + cg], acc[u]);
            }
        uint4 outv; u16* ov = (u16*)&outv;
#pragma unroll
        for (int u = 0; u < 8; ++u) {
            ov[u] = f2bf(acc[u]);
            s += acc[u]; q2 += acc[u] * acc[u];
        }
        *(uint4*)(y + ((long)b * HW2 + (long)(i0 + dr) * W2 + jbase + jj) * 128 + cg * 8) = outv;
    }
#pragma unroll
    for (int off = 32; off; off >>= 1) {
        s += __shfl_down(s, off);
        q2 += __shfl_down(q2, off);
    }
    __shared__ float r1[4], r2[4];
    if ((t & 63) == 0) { r1[t >> 6] = s; r2[t >> 6] = q2; }
    __syncthreads();
    if (t == 0) {
        int slot = (blockIdx.y * 8 + blockIdx.x) & 63;
        atomicAdd(lnS + ((long)b * 64 + slot) * 16, r1[0] + r1[1] + r1[2] + r1[3]);
        atomicAdd(lnQ + ((long)b * 64 + slot) * 16, r2[0] + r2[1] + r2[2] + r2[3]);
    }
}

// ---- fused MLP: pw1 (LN-folded + gelu) -> pw2 (+bias + recomputed residual) ----
__global__ __launch_bounds__(256) void k_mlp(const u16* __restrict__ D,
                                             const u16* __restrict__ Wp1,
                                             const u16* __restrict__ Wp2,
                                             const float* __restrict__ b1p,
                                             const float* __restrict__ b2p,
                                             const u16* __restrict__ resA,
                                             u16* __restrict__ Yout,
                                             const float* __restrict__ lnS,
                                             const float* __restrict__ lnQ,
                                             const float* __restrict__ wbv,
                                             const float* __restrict__ wgs,
                                             const float* __restrict__ bnS,
                                             const float* __restrict__ bnQ,
                                             const float* __restrict__ g1,
                                             const float* __restrict__ b1v) {
    __shared__ __align__(16) u16 lA[16384];   // [2 chunk][128 row][64 k]
    __shared__ __align__(16) u16 lB[16384];
    __shared__ float s1[128], s2[128], sA[128], sB[128], lnred[2];
    const int t = threadIdx.x;
    const int lane = t & 63, w = t >> 6, wr = w >> 1, wc = w & 1;
    const int r15 = lane & 15, kq = lane >> 4;
    const int b = blockIdx.z, m0 = blockIdx.y * 128;

    if (t < 64) {
        float s = lnS[((long)b * 64 + t) * 16];
        float q = lnQ[((long)b * 64 + t) * 16];
#pragma unroll
        for (int off = 32; off; off >>= 1) {
            s += __shfl_down(s, off);
            q += __shfl_down(q, off);
        }
        if (t == 0) { lnred[0] = s; lnred[1] = q; }
    }
    __syncthreads();
    const float invN = 1.0f / 2097152.0f;
    float mu = lnred[0] * invN;
    float var = lnred[1] * invN - mu * mu;
    const float rs = rsqrtf(var + 1e-5f);
    if (t < 128) {
        s1[t] = b1p[t] + wbv[t] - mu * rs * wgs[t];
        s2[t] = b2p[t];
        const float invN1 = 1.0f / 131072.0f;
        float mu1 = bnS[(long)t * 16] * invN1;
        float var1 = bnQ[(long)t * 16] * invN1 - mu1 * mu1;
        float rs1 = rsqrtf(var1 + 1e-5f);
        float sc1 = rs1 * g1[t];
        sA[t] = sc1;
        sB[t] = b1v[t] - mu1 * sc1;
    }

    const u16* Ab = D + ((long)b * HW2 + m0) * 128;
    uint4 ga[8], gb[8];
#pragma unroll
    for (int i = 0; i < 8; ++i) {
        int s = i * 256 + t, row = s >> 4, seg = s & 15;
        ga[i] = *(const uint4*)(Ab + (long)row * 128 + seg * 8);
        gb[i] = *(const uint4*)(Wp1 + (long)row * 128 + seg * 8);
    }
#pragma unroll
    for (int i = 0; i < 8; ++i) {
        int s = i * 256 + t, row = s >> 4, seg = s & 15;
        int off = (seg >> 3) * 16384 + row * 128 + 16 * ((seg & 7) ^ (row & 7));
        *(uint4*)((char*)lA + off) = ga[i];
        *(uint4*)((char*)lB + off) = gb[i];
    }
    __syncthreads();

    f32x4 acc[4][4];
#pragma unroll
    for (int i = 0; i < 4; ++i)
#pragma unroll
        for (int j = 0; j < 4; ++j) acc[i][j] = (f32x4){0.f, 0.f, 0.f, 0.f};
#pragma unroll
    for (int chunk = 0; chunk < 2; ++chunk)
#pragma unroll
        for (int ks = 0; ks < 2; ++ks) {
            const int ch = ks * 4 + kq;
            short8 af[4], bfv[4];
#pragma unroll
            for (int mi = 0; mi < 4; ++mi) {
                int row = wr * 64 + mi * 16 + r15;
                af[mi] = *(const short8*)((const char*)lA + chunk * 16384 +
                                          row * 128 + 16 * (ch ^ (row & 7)));
            }
#pragma unroll
            for (int ni = 0; ni < 4; ++ni) {
                int row = wc * 64 + ni * 16 + r15;
                bfv[ni] = *(const short8*)((const char*)lB + chunk * 16384 +
                                           row * 128 + 16 * (ch ^ (row & 7)));
            }
#pragma unroll
            for (int mi = 0; mi < 4; ++mi)
#pragma unroll
                for (int ni = 0; ni < 4; ++ni)
                    acc[mi][ni] = __builtin_amdgcn_mfma_f32_16x16x32_bf16(
                        af[mi], bfv[ni], acc[mi][ni], 0, 0, 0);
        }
#pragma unroll
    for (int i = 0; i < 8; ++i) {
        int s = i * 256 + t, row = s >> 4, seg = s & 15;
        gb[i] = *(const uint4*)(Wp2 + (long)row * 128 + seg * 8);
    }
    __syncthreads();

    // bounce1: gelu(rs*acc + s1[ch]) -> lA in GEMM-A k-major layout (k = ch)
#pragma unroll
    for (int mi = 0; mi < 4; ++mi)
#pragma unroll
        for (int ni = 0; ni < 4; ++ni)
#pragma unroll
            for (int r = 0; r < 4; ++r) {
                int row = wr * 64 + mi * 16 + kq * 4 + r;
                int col = wc * 64 + ni * 16 + r15;
                float v = gelu_f(rs * acc[mi][ni][r] + s1[col]);
                lA[(col >> 6) * 8192 + row * 64 +
                   8 * (((col >> 3) & 7) ^ (row & 7)) + (col & 7)] = f2bf(v);
            }
#pragma unroll
    for (int i = 0; i < 8; ++i) {
        int s = i * 256 + t, row = s >> 4, seg = s & 15;
        int off = (seg >> 3) * 16384 + row * 128 + 16 * ((seg & 7) ^ (row & 7));
        *(uint4*)((char*)lB + off) = gb[i];
    }
    __syncthreads();

    // GEMM2
#pragma unroll
    for (int i = 0; i < 4; ++i)
#pragma unroll
        for (int j = 0; j < 4; ++j) acc[i][j] = (f32x4){0.f, 0.f, 0.f, 0.f};
#pragma unroll
    for (int chunk = 0; chunk < 2; ++chunk)
#pragma unroll
        for (int ks = 0; ks < 2; ++ks) {
            const int ch = ks * 4 + kq;
            short8 af[4], bfv[4];
#pragma unroll
            for (int mi = 0; mi < 4; ++mi) {
                int row = wr * 64 + mi * 16 + r15;
                af[mi] = *(const short8*)((const char*)lA + chunk * 16384 +
                                          row * 128 + 16 * (ch ^ (row & 7)));
            }
#pragma unroll
            for (int ni = 0; ni < 4; ++ni) {
                int row = wc * 64 + ni * 16 + r15;
                bfv[ni] = *(const short8*)((const char*)lB + chunk * 16384 +
                                           row * 128 + 16 * (ch ^ (row & 7)));
            }
#pragma unroll
            for (int mi = 0; mi < 4; ++mi)
#pragma unroll
                for (int ni = 0; ni < 4; ++ni)
                    acc[mi][ni] = __builtin_amdgcn_mfma_f32_16x16x32_bf16(
                        af[mi], bfv[ni], acc[mi][ni], 0, 0, 0);
        }
    __syncthreads();

#pragma unroll
    for (int mi = 0; mi < 4; ++mi)
#pragma unroll
        for (int ni = 0; ni < 4; ++ni)
#pragma unroll
            for (int r = 0; r < 4; ++r) {
                int row = wr * 64 + mi * 16 + kq * 4 + r;
                int col = wc * 64 + ni * 16 + r15;
                lA[row * 128 + (col ^ ((row & 7) << 3))] = f2bf(acc[mi][ni][r]);
            }
    __syncthreads();

    const u16* Ra = resA + ((long)b * HW2 + m0) * 128;
    u16* Cb = Yout + ((long)b * HW2 + m0) * 128;
    {
        int row = t >> 1, half = (t & 1) * 64;
        int sx = (row & 7) << 3;
#pragma unroll
        for (int q = 0; q < 8; ++q) {
            int c = half + q * 8;
            uint4 raw = *(const uint4*)(lA + row * 128 + (c ^ sx));
            uint4 rr = *(const uint4*)(Ra + (long)row * 128 + c);
            u16* pv = (u16*)&raw;
            const u16* rv = (const u16*)&rr;
#pragma unroll
            for (int u = 0; u < 8; ++u) {
                float hres = gelu_f(bf2f(rv[u]) * sA[c + u] + sB[c + u]);
                pv[u] = f2bf(bf2f(pv[u]) + s2[c + u] + hres);
            }
            *(uint4*)(Cb + (long)row * 128 + c) = raw;
        }
    }
}

// ---- second moment partials: M2p[blk] = Y_blk^T Y_blk (non-atomic stores) ----
__global__ __launch_bounds__(256) void k_moment(const u16* __restrict__ Y,
                                                float* __restrict__ M2p,
                                                float* __restrict__ csum) {
    __shared__ __align__(16) u16 T[8192];
    __shared__ float cred[16][16][8];
    const int t = threadIdx.x;
    const int lane = t & 63, w = t >> 6, wr = w >> 1, wc = w & 1;
    const int r15 = lane & 15, kq = lane >> 4;
    const long px0 = (long)blockIdx.x * 1024;
    float cs[8] = {};

    f32x4 acc[4][4];
#pragma unroll
    for (int i = 0; i < 4; ++i)
#pragma unroll
        for (int j = 0; j < 4; ++j) acc[i][j] = (f32x4){0.f, 0.f, 0.f, 0.f};

    for (int it = 0; it < 16; ++it) {
        uint4 rv[4];
#pragma unroll
        for (int i = 0; i < 4; ++i) {
            int s = i * 256 + t;
            int px = s >> 4, ch8 = (s & 15) * 8;
            rv[i] = *(const uint4*)(Y + (px0 + it * 64 + px) * 128 + ch8);
        }
#pragma unroll
        for (int i = 0; i < 4; ++i) {
            const u16* pv = (const u16*)&rv[i];
#pragma unroll
            for (int u = 0; u < 8; ++u) cs[u] += bf2f(pv[u]);
        }
        __syncthreads();
#pragma unroll
        for (int i = 0; i < 4; ++i) {
            int s = i * 256 + t;
            int px = s >> 4, ch8 = (s & 15) * 8;
            const u16* pv = (const u16*)&rv[i];
#pragma unroll
            for (int u = 0; u < 8; ++u) {
                int row = ch8 + u;
                T[row * 64 + 8 * ((px >> 3) ^ (row & 7)) + (px & 7)] = pv[u];
            }
        }
        __syncthreads();
#pragma unroll
        for (int ks = 0; ks < 2; ++ks) {
            const int ch = ks * 4 + kq;
            short8 af[4], bfv[4];
#pragma unroll
            for (int mi = 0; mi < 4; ++mi) {
                int row = wr * 64 + mi * 16 + r15;
                af[mi] = *(const short8*)(T + row * 64 + 8 * (ch ^ (row & 7)));
            }
#pragma unroll
            for (int ni = 0; ni < 4; ++ni) {
                int row = wc * 64 + ni * 16 + r15;
                bfv[ni] = *(const short8*)(T + row * 64 + 8 * (ch ^ (row & 7)));
            }
#pragma unroll
            for (int mi = 0; mi < 4; ++mi)
#pragma unroll
                for (int ni = 0; ni < 4; ++ni)
                    acc[mi][ni] = __builtin_amdgcn_mfma_f32_16x16x32_bf16(
                        af[mi], bfv[ni], acc[mi][ni], 0, 0, 0);
        }
    }
    {
        int g = t & 15, m = t >> 4;
#pragma unroll
        for (int u = 0; u < 8; ++u) cred[m][g][u] = cs[u];
    }
    __syncthreads();
    if (t < 128) {
        float s = 0.f;
#pragma unroll
        for (int m = 0; m < 16; ++m) s += cred[m][t >> 3][t & 7];
        atomicAdd(csum + (long)t * 16, s);
    }
    float* Mb = M2p + (long)blockIdx.x * 16384;
#pragma unroll
    for (int mi = 0; mi < 4; ++mi)
#pragma unroll
        for (int ni = 0; ni < 4; ++ni)
#pragma unroll
            for (int r = 0; r < 4; ++r) {
                int row = wr * 64 + mi * 16 + kq * 4 + r;
                int col = wc * 64 + ni * 16 + r15;
                Mb[row * 128 + col] = acc[mi][ni][r];
            }
}

// ---- reduce 128 M2 partials -> M2 dense ----
__global__ __launch_bounds__(256) void k_m2red(const float* __restrict__ M2p,
                                               float* __restrict__ M2) {
    int e = blockIdx.x * 256 + threadIdx.x;   // 16384 elements
    float s = 0.f;
    for (int p = 0; p < 128; ++p) s += M2p[(long)p * 16384 + e];
    M2[e] = s;
}

// ---- combine: per-out-channel BN2 scale/shift ----
__global__ __launch_bounds__(128) void k_statcomb(const float* __restrict__ w_c2,
                                                  const float* __restrict__ M2,
                                                  const float* __restrict__ csum,
                                                  const float* __restrict__ g,
                                                  const float* __restrict__ bb,
                                                  float* __restrict__ scsh) {
    __shared__ float wl[128];
    __shared__ float red[2][2];
    const int o = blockIdx.x, c = threadIdx.x;
    wl[c] = w_c2[o * 128 + c];
    __syncthreads();
    const float* m2r = M2 + c * 128;
    float tmp = 0.f;
#pragma unroll
    for (int c2 = 0; c2 < 128; c2 += 4) {
        float4 m = *(const float4*)(m2r + c2);
        tmp += m.x * wl[c2] + m.y * wl[c2 + 1] + m.z * wl[c2 + 2] + m.w * wl[c2 + 3];
    }
    float s2p = wl[c] * tmp;
    float mup = wl[c] * csum[(long)c * 16];
#pragma unroll
    for (int off = 32; off; off >>= 1) {
        s2p += __shfl_down(s2p, off);
        mup += __shfl_down(mup, off);
    }
    if ((c & 63) == 0) { red[0][c >> 6] = s2p; red[1][c >> 6] = mup; }
    __syncthreads();
    if (c == 0) {
        float s2 = (red[0][0] + red[0][1]) / NPIX;
        float mu = (red[1][0] + red[1][1]) / NPIX;
        float var = s2 - mu * mu;
        float rs = rsqrtf(var + 1e-5f);
        float sc = g[o] * rs;
        scsh[o] = sc;
        scsh[512 + o] = bb[o] - mu * sc;
    }
}

// ---- conv2 + BN2 + GELU + IDWT -> out f32 NCHW; 512 threads, NT stores ----
__global__ __launch_bounds__(512) void k_conv2_idwt(const u16* __restrict__ Y,
                                                    const u16* __restrict__ Wc,
                                                    const float* __restrict__ scsh,
                                                    float* __restrict__ out) {
    __shared__ __align__(16) u16 lA[16384];  // [2 chunk][128 row][64 k]
    __shared__ __align__(16) u16 lB[8192];   // [2 chunk][64 row][64 k]
    __shared__ float sparam[1024];
    const int t = threadIdx.x;
    const int lane = t & 63, w = t >> 6, wr = w & 1, wc = w >> 1;  // wr 0..1, wc 0..3
    const int r15 = lane & 15, kq = lane >> 4;
    const int b = blockIdx.y, n0 = blockIdx.x;
#pragma unroll
    for (int u = 0; u < 2; ++u) sparam[t + u * 512] = scsh[t + u * 512];

    const u16* Yb = Y + ((long)b * HW2 + (long)n0 * 64) * 128;
    uint4 rb2[2], ra4[4];
#pragma unroll
    for (int i = 0; i < 2; ++i) {
        int s = i * 512 + t, row = s >> 4, seg = s & 15;
        rb2[i] = *(const uint4*)(Yb + (long)row * 128 + seg * 8);
    }
#define GLOADA(q)                                                                \
    {                                                                            \
        _Pragma("unroll")                                                        \
        for (int i = 0; i < 4; ++i) {                                            \
            int s = i * 512 + t, row = s >> 4, seg = s & 15;                     \
            ra4[i] = *(const uint4*)(Wc + (long)((q) * 128 + row) * 128 + seg * 8); \
        }                                                                        \
    }
#define LWRITEA()                                                                \
    {                                                                            \
        _Pragma("unroll")                                                        \
        for (int i = 0; i < 4; ++i) {                                            \
            int s = i * 512 + t, row = s >> 4, seg = s & 15;                     \
            *(uint4*)((char*)lA + (seg >> 3) * 16384 + row * 128 +               \
                      16 * ((seg & 7) ^ (row & 7))) = ra4[i];                    \
        }                                                                        \
    }
    GLOADA(0)
#pragma unroll
    for (int i = 0; i < 2; ++i) {
        int s = i * 512 + t, row = s >> 4, seg = s & 15;
        *(uint4*)((char*)lB + (seg >> 3) * 8192 + row * 128 +
                  16 * ((seg & 7) ^ (row & 7))) = rb2[i];
    }
    LWRITEA()
    __syncthreads();

    u32 sbp[4][4][2];   // [q][mi][rp]
#pragma unroll
    for (int q = 0; q < 4; ++q) {
        f32x4 acc[4];
#pragma unroll
        for (int mi = 0; mi < 4; ++mi) acc[mi] = (f32x4){0.f, 0.f, 0.f, 0.f};
#pragma unroll
        for (int chunk = 0; chunk < 2; ++chunk)
#pragma unroll
            for (int ks = 0; ks < 2; ++ks) {
                const int ch = ks * 4 + kq;
                short8 af[4], bfv;
#pragma unroll
                for (int mi = 0; mi < 4; ++mi) {
                    int row = wr * 64 + mi * 16 + r15;
                    af[mi] = *(const short8*)((const char*)lA + chunk * 16384 +
                                              row * 128 + 16 * (ch ^ (row & 7)));
                }
                {
                    int row = wc * 16 + r15;
                    bfv = *(const short8*)((const char*)lB + chunk * 8192 +
                                           row * 128 + 16 * (ch ^ (row & 7)));
                }
#pragma unroll
                for (int mi = 0; mi < 4; ++mi)
                    acc[mi] = __builtin_amdgcn_mfma_f32_16x16x32_bf16(
                        af[mi], bfv, acc[mi], 0, 0, 0);
            }
        if (q < 3) GLOADA(q + 1)
#pragma unroll
        for (int mi = 0; mi < 4; ++mi)
#pragma unroll
            for (int rp = 0; rp < 2; ++rp) {
                int c0 = q * 128 + wr * 64 + mi * 16 + kq * 4 + rp * 2;
                float v0 = gelu_f(acc[mi][rp * 2] * sparam[c0] + sparam[512 + c0]);
                float v1 = gelu_f(acc[mi][rp * 2 + 1] * sparam[c0 + 1] + sparam[512 + c0 + 1]);
                sbp[q][mi][rp] = (u32)f2bf(v0) | ((u32)f2bf(v1) << 16);
            }
        if (q < 3) {
            __syncthreads();
            LWRITEA()
            __syncthreads();
        }
    }
    const int i = n0 >> 1;
    const int j = (n0 & 1) * 64 + wc * 16 + r15;
#pragma unroll
    for (int mi = 0; mi < 4; ++mi)
#pragma unroll
        for (int rp = 0; rp < 2; ++rp) {
            u32 p0 = sbp[0][mi][rp], p1 = sbp[1][mi][rp];
            u32 p2 = sbp[2][mi][rp], p3 = sbp[3][mi][rp];
#pragma unroll
            for (int e = 0; e < 2; ++e) {
                int c = wr * 64 + mi * 16 + kq * 4 + rp * 2 + e;
                float ll = bf2f(e ? (u16)(p0 >> 16) : (u16)(p0 & 0xFFFF));
                float lh = bf2f(e ? (u16)(p1 >> 16) : (u16)(p1 & 0xFFFF));
                float hl = bf2f(e ? (u16)(p2 >> 16) : (u16)(p2 & 0xFFFF));
                float hh = bf2f(e ? (u16)(p3 >> 16) : (u16)(p3 & 0xFFFF));
                long ob = (((long)(b * Cc + c) * Hh + 2 * i) * Wf + 2 * j);
                union { float2 v; u64 u; } w0, w1;
                w0.v = make_float2((ll + lh + hl + hh) * 0.5f, (ll + lh - hl - hh) * 0.5f);
                w1.v = make_float2((ll - lh + hl - hh) * 0.5f, (ll - lh - hl + hh) * 0.5f);
                __builtin_nontemporal_store(w0.u, (u64*)(out + ob));
                __builtin_nontemporal_store(w1.u, (u64*)(out + ob + Wf));
            }
        }
#undef GLOADA
#undef LWRITEA
}

extern "C" void kernel_launch(void* const* d_in, const int* in_sizes, int n_in,
                              void* d_out, int out_size, void* d_ws, size_t ws_size,
                              hipStream_t stream) {
    const float* x     = (const float*)d_in[0];
    const float* w_c1  = (const float*)d_in[1];
    const float* bn1_g = (const float*)d_in[3];
    const float* bn1_b = (const float*)d_in[4];
    const float* dw_w  = (const float*)d_in[5];
    const float* dw_b  = (const float*)d_in[6];
    const float* gn_g  = (const float*)d_in[7];
    const float* gn_b  = (const float*)d_in[8];
    const float* pw1_w = (const float*)d_in[9];
    const float* pw1_b = (const float*)d_in[10];
    const float* pw2_w = (const float*)d_in[11];
    const float* pw2_b = (const float*)d_in[12];
    const float* w_c2  = (const float*)d_in[13];
    const float* bn2_g = (const float*)d_in[15];
    const float* bn2_b = (const float*)d_in[16];
    float* out = (float*)d_out;

    const size_t n128 = (size_t)Bq * Cc * HW2;
    u16* bufA = (u16*)d_ws;        // conv1 raw out [b][px][128] (also MLP residual src)
    u16* bufD = bufA + n128;       // dwconv out (post BN1+gelu conv)
    u16* bufY = bufD + n128;       // MLP out (= conv2 input)
    u16* wb   = bufY + n128;       // bf16 weights: W'c1|pw1g|pw2|w_c2
    float* stats = (float*)(wb + 163840);
    float* M2p = stats + 49152;    // 128 x 16384 f32 partials (8 MB)
    size_t need = (3 * n128 + 163840) * 2 + (49152 + 128 * 16384) * 4;
    if (ws_size < need) return;

    float* bn1_sum = stats;            // 128 x16 padded
    float* bn1_sq  = stats + 2048;
    float* ln_sum  = stats + 4096;     // 8x64 x16 padded
    float* ln_sq   = stats + 12288;
    float* csum    = stats + 20480;    // 128 x16 padded
    float* M2      = stats + 22528;    // 128x128 dense (written by k_m2red)
    float* scsh    = stats + 38912;    // 512 scale | 512 shift
    float* wbv     = stats + 39936;
    float* wgs     = stats + 40064;

    hipMemsetAsync(stats, 0, 22528 * sizeof(float), stream);

    // 0. weights -> bf16 + LN-fold vectors (merged, block 640)
    k_wconv<<<641, 256, 0, stream>>>(w_c1, pw1_w, pw2_w, w_c2, gn_g, gn_b,
                                     wb, wbv, wgs);

    // 1. fused DWT + conv1 + BN1 stats
    k_conv1<<<dim3(1, 128, 8), 512, 0, stream>>>(x, wb, bufA, bn1_sum, bn1_sq);

    // 2. depthwise 3x3, 4-row tiles, fused BN1+gelu on load + LN stats
    k_dwconv<<<dim3(8, 32, 8), 256, 0, stream>>>(bufA, bufD, dw_w, dw_b,
                                                 bn1_sum, bn1_sq, bn1_g, bn1_b,
                                                 ln_sum, ln_sq);

    // 3. fused MLP: pw1 (LN-folded + gelu) -> pw2 (+bias + recomputed residual)
    k_mlp<<<dim3(1, 128, 8), 256, 0, stream>>>(
        bufD, wb + 65536, wb + 81920, pw1_b, pw2_b, bufA, bufY,
        ln_sum, ln_sq, wbv, wgs, bn1_sum, bn1_sq, bn1_g, bn1_b);

    // 4. BN2 stats: per-block M2 partials (non-atomic) + reduce + combine
    k_moment<<<128, 256, 0, stream>>>(bufY, M2p, csum);
    k_m2red<<<64, 256, 0, stream>>>(M2p, M2);
    k_statcomb<<<512, 128, 0, stream>>>(w_c2, M2, csum, bn2_g, bn2_b, scsh);

    // 5. conv2 + BN2 + gelu + IDWT -> out (NT stores)
    k_conv2_idwt<<<dim3(256, 8), 512, 0, stream>>>(bufY, wb + 98304, scsh, out);
}

// Round 13
// 394.141 us; speedup vs baseline: 2.3382x; 1.0420x over previous
//
#include <hip/hip_runtime.h>
#include <hip/hip_bf16.h>

typedef unsigned short u16;
typedef unsigned int u32;
typedef unsigned long long u64;
typedef __attribute__((ext_vector_type(8))) short short8;
typedef __attribute__((ext_vector_type(4))) float f32x4;

#define Bq 8
#define Cc 128
#define C4 512
#define Hh 256
#define Wf 256
#define H2 128
#define W2 128
#define HW2 16384
#define NPIX 131072.0f

__device__ __forceinline__ float gelu_f(float x) {
    float u = 1.5957691216057308f * (x + 0.044715f * x * x * x);
    float t = 1.0f - 2.0f / (__expf(u) + 1.0f);
    return 0.5f * x * (1.0f + t);
}
__device__ __forceinline__ float bf2f(u16 u) {
    union { float f; u32 i; } v; v.i = ((u32)u) << 16; return v.f;
}
__device__ __forceinline__ u16 f2bf(float f) {
    union { float f; u32 i; } v; v.f = f;
    u32 r = v.i + 0x7FFFu + ((v.i >> 16) & 1u);
    return (u16)(r >> 16);
}

// ---- weights f32 -> bf16; block 640: zero stats + LN-fold vectors ----
__global__ __launch_bounds__(256) void k_wconv(const float* __restrict__ w_c1,
                                               const float* __restrict__ pw1,
                                               const float* __restrict__ pw2,
                                               const float* __restrict__ w_c2,
                                               const float* __restrict__ gn_g,
                                               const float* __restrict__ gn_b,
                                               u16* __restrict__ wb,
                                               float* __restrict__ wbv,
                                               float* __restrict__ wgs,
                                               float* __restrict__ stats0) {
    if (blockIdx.x == 640) {
        for (int e = threadIdx.x; e < 22528; e += 256) stats0[e] = 0.f;
        int o = threadIdx.x;
        if (o < 128) {
            float a = 0.f, bv = 0.f;
            for (int c = 0; c < 128; ++c) {
                float w_ = pw1[o * 128 + c];
                a += w_ * gn_g[c];
                bv += w_ * gn_b[c];
            }
            wgs[o] = a;
            wbv[o] = bv;
        }
        return;
    }
    int i = blockIdx.x * 256 + threadIdx.x;   // 0..163839
    float v;
    if (i < 65536) {
        int o = i >> 9, kn = i & 511;
        int c = kn >> 2, dy = (kn >> 1) & 1, dx = kn & 1;
        float sdy = dy ? -1.f : 1.f, sdx = dx ? -1.f : 1.f;
        const float* wr = w_c1 + o * 512 + c;
        v = 0.5f * (wr[0] + sdy * wr[128] + sdx * wr[256] + sdy * sdx * wr[384]);
    } else if (i < 81920) v = pw1[i - 65536] * gn_g[(i - 65536) & 127];
    else if (i < 98304) v = pw2[i - 81920];
    else v = w_c2[i - 98304];
    wb[i] = f2bf(v);
}

// ---- fused DWT+conv1+BN1-stats: reads x f32 NCHW directly (512 thr) ----
__global__ __launch_bounds__(512) void k_conv1(const float* __restrict__ x,
                                               const u16* __restrict__ Wt,
                                               u16* __restrict__ Cout,
                                               float* __restrict__ statS,
                                               float* __restrict__ statQ) {
    __shared__ __align__(16) u16 lds[16384];
    __shared__ float sblk[128], qblk[128];
    const int t = threadIdx.x;
    const int lane = t & 63, w = t >> 6, wr = w & 1, wc = w >> 1;
    const int b = blockIdx.z, i = blockIdx.y;
    if (t < 128) { sblk[t] = 0.f; qblk[t] = 0.f; }

    const int r15 = lane & 15, kq = lane >> 4;
    const int half = t >> 8;
    const int colblk = t & 7, cc = (t >> 3) & 15, dy = (t >> 7) & 1;
    const int kbase = cc * 4 + dy * 2;
    const int gG = kbase >> 3, e2 = (kbase & 7) * 2;

    float4 xv[4];
    uint4 rb[2];
    {
        const float* xp = x + (((long)(b * Cc + cc)) * Hh + (2 * i + dy)) * Wf;
#pragma unroll
        for (int q = 0; q < 4; ++q) {
            int col = (half * 4 + q) * 32 + colblk * 4;
            xv[q] = *(const float4*)(xp + col);
        }
#pragma unroll
        for (int ii = 0; ii < 2; ++ii) {
            int s = ii * 512 + t;
            rb[ii] = *(const uint4*)(Wt + (long)(s >> 3) * 512 + (s & 7) * 8);
        }
    }

    f32x4 acc[4][2];
#pragma unroll
    for (int a2 = 0; a2 < 4; ++a2)
#pragma unroll
        for (int j2 = 0; j2 < 2; ++j2) acc[a2][j2] = (f32x4){0.f, 0.f, 0.f, 0.f};

    for (int k0 = 0; k0 < 512; k0 += 64) {
        __syncthreads();
#pragma unroll
        for (int q = 0; q < 4; ++q) {
            int col = (half * 4 + q) * 32 + colblk * 4;
            int j0 = col >> 1;
            u32 p0 = (u32)f2bf(xv[q].x) | ((u32)f2bf(xv[q].y) << 16);
            u32 p1 = (u32)f2bf(xv[q].z) | ((u32)f2bf(xv[q].w) << 16);
            *(u32*)((char*)lds + j0 * 128 + 16 * (gG ^ (j0 & 7)) + e2) = p0;
            *(u32*)((char*)lds + (j0 + 1) * 128 + 16 * (gG ^ ((j0 + 1) & 7)) + e2) = p1;
        }
#pragma unroll
        for (int ii = 0; ii < 2; ++ii) {
            int s = ii * 512 + t;
            int row_ = s >> 3, ch_ = s & 7;
            *(uint4*)((char*)lds + 16384 + row_ * 128 + 16 * (ch_ ^ (row_ & 7))) = rb[ii];
        }
        __syncthreads();
        if (k0 + 64 < 512) {
            const int c0n = (k0 + 64) >> 2;
            const float* xp = x + (((long)(b * Cc + c0n + cc)) * Hh + (2 * i + dy)) * Wf;
#pragma unroll
            for (int q = 0; q < 4; ++q) {
                int col = (half * 4 + q) * 32 + colblk * 4;
                xv[q] = *(const float4*)(xp + col);
            }
#pragma unroll
            for (int ii = 0; ii < 2; ++ii) {
                int s = ii * 512 + t;
                rb[ii] = *(const uint4*)(Wt + (long)(s >> 3) * 512 + (k0 + 64) + (s & 7) * 8);
            }
        }
#pragma unroll
        for (int ks = 0; ks < 2; ++ks) {
            short8 af[4], bfv[2];
            const int ch = ks * 4 + kq;
#pragma unroll
            for (int mi = 0; mi < 4; ++mi) {
                int row = wr * 64 + mi * 16 + r15;
                af[mi] = *(const short8*)((const char*)lds + row * 128 + 16 * (ch ^ (row & 7)));
            }
#pragma unroll
            for (int ni = 0; ni < 2; ++ni) {
                int row = wc * 32 + ni * 16 + r15;
                bfv[ni] = *(const short8*)((const char*)lds + 16384 + row * 128 + 16 * (ch ^ (row & 7)));
            }
#pragma unroll
            for (int mi = 0; mi < 4; ++mi)
#pragma unroll
                for (int ni = 0; ni < 2; ++ni)
                    acc[mi][ni] = __builtin_amdgcn_mfma_f32_16x16x32_bf16(
                        af[mi], bfv[ni], acc[mi][ni], 0, 0, 0);
        }
    }
    __syncthreads();

#pragma unroll
    for (int mi = 0; mi < 4; ++mi)
#pragma unroll
        for (int ni = 0; ni < 2; ++ni)
#pragma unroll
            for (int r = 0; r < 4; ++r) {
                int row = wr * 64 + mi * 16 + kq * 4 + r;
                int col = wc * 32 + ni * 16 + r15;
                lds[row * 128 + (col ^ ((row & 7) << 3))] = f2bf(acc[mi][ni][r]);
            }
#pragma unroll
    for (int ni = 0; ni < 2; ++ni) {
        float s = 0.f, q2 = 0.f;
#pragma unroll
        for (int mi = 0; mi < 4; ++mi)
#pragma unroll
            for (int r = 0; r < 4; ++r) {
                float v = acc[mi][ni][r];
                s += v; q2 += v * v;
            }
        s += __shfl_down(s, 32); s += __shfl_down(s, 16);
        q2 += __shfl_down(q2, 32); q2 += __shfl_down(q2, 16);
        if (lane < 16) {
            int col = wc * 32 + ni * 16 + r15;
            atomicAdd(&sblk[col], s);
            atomicAdd(&qblk[col], q2);
        }
    }
    __syncthreads();
    {
        u16* Cb = Cout + (long)b * HW2 * 128;
        int row = t >> 2, quarter = (t & 3) * 32;
        int sx = (row & 7) << 3;
        long gbase = (long)(i * 128 + row) * 128;
#pragma unroll
        for (int q = 0; q < 4; ++q) {
            int c = quarter + q * 8;
            *(uint4*)(Cb + gbase + c) = *(const uint4*)(lds + row * 128 + (c ^ sx));
        }
    }
    if (t < 128) {
        atomicAdd(statS + (long)t * 16, sblk[t]);
        atomicAdd(statQ + (long)t * 16, qblk[t]);
    }
}

// ---- depthwise 3x3 NHWC, 4-row tile, fused BN1+gelu + LN stats ----
__global__ __launch_bounds__(256) void k_dwconv(const u16* __restrict__ xin,
                                                u16* __restrict__ y,
                                                const float* __restrict__ w,
                                                const float* __restrict__ bias,
                                                const float* __restrict__ bnS,
                                                const float* __restrict__ bnQ,
                                                const float* __restrict__ g1,
                                                const float* __restrict__ b1,
                                                float* __restrict__ lnS,
                                                float* __restrict__ lnQ) {
    __shared__ float wl2[1152];
    __shared__ float sA[128], sB[128];
    __shared__ __align__(16) u16 tile[108 * 136];
    const int t = threadIdx.x;
    if (t < 128) {
        const float invN = 1.0f / 131072.0f;
        float mu = bnS[(long)t * 16] * invN;
        float var = bnQ[(long)t * 16] * invN - mu * mu;
        float rs = rsqrtf(var + 1e-5f);
        float sc = rs * g1[t];
        sA[t] = sc;
        sB[t] = b1[t] - mu * sc;
    }
    for (int idx = t; idx < 1152; idx += 256) {
        int c = idx / 9, tap = idx - c * 9;
        wl2[tap * 128 + (c & 7) * 16 + (c >> 3)] = w[idx];
    }
    __syncthreads();
    const int jbase = blockIdx.x * 16, i0 = blockIdx.y * 4, b = blockIdx.z;
    const u16* xb = xin + (long)b * HW2 * 128;
    {
        int seg = t & 15, slot0 = t >> 4;
#pragma unroll
        for (int pass = 0; pass < 7; ++pass) {
            int slot = pass * 16 + slot0;
            if (slot < 108) {
                int r = slot / 18, p = slot - r * 18;
                int row = i0 - 1 + r, col = jbase - 1 + p;
                bool inb = (row >= 0) & (row < H2) & (col >= 0) & (col < W2);
                uint4 raw = inb ? *(const uint4*)(xb + ((long)row * W2 + col) * 128 + seg * 8)
                                : make_uint4(0u, 0u, 0u, 0u);
                const u16* pv = (const u16*)&raw;
                uint4 outv; u16* ov = (u16*)&outv;
#pragma unroll
                for (int u = 0; u < 8; ++u) {
                    int c = seg * 8 + u;
                    float v = inb ? gelu_f(bf2f(pv[u]) * sA[c] + sB[c]) : 0.f;
                    ov[u] = f2bf(v);
                }
                *(uint4*)(tile + slot * 136 + seg * 8) = outv;
            }
        }
    }
    __syncthreads();
    const int cg = t & 15, jj = t >> 4;
    float s = 0.f, q2 = 0.f;
    float bi[8];
#pragma unroll
    for (int u = 0; u < 8; ++u) bi[u] = bias[cg * 8 + u];
#pragma unroll
    for (int dr = 0; dr < 4; ++dr) {
        float acc[8];
#pragma unroll
        for (int u = 0; u < 8; ++u) acc[u] = bi[u];
#pragma unroll
        for (int r = 0; r < 3; ++r)
#pragma unroll
            for (int dj = 0; dj < 3; ++dj) {
                short8 vv = *(const short8*)(tile + ((dr + r) * 18 + jj + dj) * 136 + cg * 8);
                const int tap = r * 3 + dj;
#pragma unroll
                for (int u = 0; u < 8; ++u)
                    acc[u] = fmaf(bf2f((u16)vv[u]), wl2[tap * 128 + u * 16 + cg], acc[u]);
            }
        uint4 outv; u16* ov = (u16*)&outv;
#pragma unroll
        for (int u = 0; u < 8; ++u) {
            ov[u] = f2bf(acc[u]);
            s += acc[u]; q2 += acc[u] * acc[u];
        }
        *(uint4*)(y + ((long)b * HW2 + (long)(i0 + dr) * W2 + jbase + jj) * 128 + cg * 8) = outv;
    }
#pragma unroll
    for (int off = 32; off; off >>= 1) {
        s += __shfl_down(s, off);
        q2 += __shfl_down(q2, off);
    }
    __shared__ float r1[4], r2[4];
    if ((t & 63) == 0) { r1[t >> 6] = s; r2[t >> 6] = q2; }
    __syncthreads();
    if (t == 0) {
        int slot = (blockIdx.y * 8 + blockIdx.x) & 63;
        atomicAdd(lnS + ((long)b * 64 + slot) * 16, r1[0] + r1[1] + r1[2] + r1[3]);
        atomicAdd(lnQ + ((long)b * 64 + slot) * 16, r2[0] + r2[1] + r2[2] + r2[3]);
    }
}

// ---- fused MLP (512 thr, 8 waves 2x4): pw1 -> pw2, residual recomputed ----
__global__ __launch_bounds__(512) void k_mlp(const u16* __restrict__ D,
                                             const u16* __restrict__ Wp1,
                                             const u16* __restrict__ Wp2,
                                             const float* __restrict__ b1p,
                                             const float* __restrict__ b2p,
                                             const u16* __restrict__ resA,
                                             u16* __restrict__ Yout,
                                             const float* __restrict__ lnS,
                                             const float* __restrict__ lnQ,
                                             const float* __restrict__ wbv,
                                             const float* __restrict__ wgs,
                                             const float* __restrict__ bnS,
                                             const float* __restrict__ bnQ,
                                             const float* __restrict__ g1,
                                             const float* __restrict__ b1v) {
    __shared__ __align__(16) u16 lA[16384];   // [2 chunk][128 row][64 k]
    __shared__ __align__(16) u16 lB[16384];
    __shared__ float s1[128], s2[128], sA[128], sB[128], lnred[2];
    const int t = threadIdx.x;
    const int lane = t & 63, w = t >> 6, wr = w & 1, wc = w >> 1;  // wr 0..1, wc 0..3
    const int r15 = lane & 15, kq = lane >> 4;
    const int b = blockIdx.z, m0 = blockIdx.y * 128;

    if (t < 64) {
        float s = lnS[((long)b * 64 + t) * 16];
        float q = lnQ[((long)b * 64 + t) * 16];
#pragma unroll
        for (int off = 32; off; off >>= 1) {
            s += __shfl_down(s, off);
            q += __shfl_down(q, off);
        }
        if (t == 0) { lnred[0] = s; lnred[1] = q; }
    }
    __syncthreads();
    const float invN = 1.0f / 2097152.0f;
    float mu = lnred[0] * invN;
    float var = lnred[1] * invN - mu * mu;
    const float rs = rsqrtf(var + 1e-5f);
    if (t < 128) {
        s1[t] = b1p[t] + wbv[t] - mu * rs * wgs[t];
        s2[t] = b2p[t];
        const float invN1 = 1.0f / 131072.0f;
        float mu1 = bnS[(long)t * 16] * invN1;
        float var1 = bnQ[(long)t * 16] * invN1 - mu1 * mu1;
        float rs1 = rsqrtf(var1 + 1e-5f);
        float sc1 = rs1 * g1[t];
        sA[t] = sc1;
        sB[t] = b1v[t] - mu1 * sc1;
    }

    const u16* Ab = D + ((long)b * HW2 + m0) * 128;
    uint4 ga[4], gb[4];
#pragma unroll
    for (int i = 0; i < 4; ++i) {
        int s = i * 512 + t, row = s >> 4, seg = s & 15;
        ga[i] = *(const uint4*)(Ab + (long)row * 128 + seg * 8);
        gb[i] = *(const uint4*)(Wp1 + (long)row * 128 + seg * 8);
    }
#pragma unroll
    for (int i = 0; i < 4; ++i) {
        int s = i * 512 + t, row = s >> 4, seg = s & 15;
        int off = (seg >> 3) * 16384 + row * 128 + 16 * ((seg & 7) ^ (row & 7));
        *(uint4*)((char*)lA + off) = ga[i];
        *(uint4*)((char*)lB + off) = gb[i];
    }
    __syncthreads();

    f32x4 acc[4][2];
#pragma unroll
    for (int i = 0; i < 4; ++i)
#pragma unroll
        for (int j = 0; j < 2; ++j) acc[i][j] = (f32x4){0.f, 0.f, 0.f, 0.f};
#pragma unroll
    for (int chunk = 0; chunk < 2; ++chunk)
#pragma unroll
        for (int ks = 0; ks < 2; ++ks) {
            const int ch = ks * 4 + kq;
            short8 af[4], bfv[2];
#pragma unroll
            for (int mi = 0; mi < 4; ++mi) {
                int row = wr * 64 + mi * 16 + r15;
                af[mi] = *(const short8*)((const char*)lA + chunk * 16384 +
                                          row * 128 + 16 * (ch ^ (row & 7)));
            }
#pragma unroll
            for (int ni = 0; ni < 2; ++ni) {
                int row = wc * 32 + ni * 16 + r15;
                bfv[ni] = *(const short8*)((const char*)lB + chunk * 16384 +
                                           row * 128 + 16 * (ch ^ (row & 7)));
            }
#pragma unroll
            for (int mi = 0; mi < 4; ++mi)
#pragma unroll
                for (int ni = 0; ni < 2; ++ni)
                    acc[mi][ni] = __builtin_amdgcn_mfma_f32_16x16x32_bf16(
                        af[mi], bfv[ni], acc[mi][ni], 0, 0, 0);
        }
    // prefetch pw2 weights while GEMM1 drains
#pragma unroll
    for (int i = 0; i < 4; ++i) {
        int s = i * 512 + t, row = s >> 4, seg = s & 15;
        gb[i] = *(const uint4*)(Wp2 + (long)row * 128 + seg * 8);
    }
    __syncthreads();   // all lA/lB reads complete

    // bounce1: gelu(rs*acc + s1[ch]) -> lA in GEMM-A k-major layout (k = ch)
#pragma unroll
    for (int mi = 0; mi < 4; ++mi)
#pragma unroll
        for (int ni = 0; ni < 2; ++ni)
#pragma unroll
            for (int r = 0; r < 4; ++r) {
                int row = wr * 64 + mi * 16 + kq * 4 + r;   // px
                int col = wc * 32 + ni * 16 + r15;          // ch (= k of GEMM2)
                float v = gelu_f(rs * acc[mi][ni][r] + s1[col]);
                lA[(col >> 6) * 8192 + row * 64 +
                   8 * (((col >> 3) & 7) ^ (row & 7)) + (col & 7)] = f2bf(v);
            }
#pragma unroll
    for (int i = 0; i < 4; ++i) {
        int s = i * 512 + t, row = s >> 4, seg = s & 15;
        int off = (seg >> 3) * 16384 + row * 128 + 16 * ((seg & 7) ^ (row & 7));
        *(uint4*)((char*)lB + off) = gb[i];
    }
    __syncthreads();

    // GEMM2
#pragma unroll
    for (int i = 0; i < 4; ++i)
#pragma unroll
        for (int j = 0; j < 2; ++j) acc[i][j] = (f32x4){0.f, 0.f, 0.f, 0.f};
#pragma unroll
    for (int chunk = 0; chunk < 2; ++chunk)
#pragma unroll
        for (int ks = 0; ks < 2; ++ks) {
            const int ch = ks * 4 + kq;
            short8 af[4], bfv[2];
#pragma unroll
            for (int mi = 0; mi < 4; ++mi) {
                int row = wr * 64 + mi * 16 + r15;
                af[mi] = *(const short8*)((const char*)lA + chunk * 16384 +
                                          row * 128 + 16 * (ch ^ (row & 7)));
            }
#pragma unroll
            for (int ni = 0; ni < 2; ++ni) {
                int row = wc * 32 + ni * 16 + r15;
                bfv[ni] = *(const short8*)((const char*)lB + chunk * 16384 +
                                           row * 128 + 16 * (ch ^ (row & 7)));
            }
#pragma unroll
            for (int mi = 0; mi < 4; ++mi)
#pragma unroll
                for (int ni = 0; ni < 2; ++ni)
                    acc[mi][ni] = __builtin_amdgcn_mfma_f32_16x16x32_bf16(
                        af[mi], bfv[ni], acc[mi][ni], 0, 0, 0);
        }
    __syncthreads();   // lA reads done; reuse flat for bounce2

#pragma unroll
    for (int mi = 0; mi < 4; ++mi)
#pragma unroll
        for (int ni = 0; ni < 2; ++ni)
#pragma unroll
            for (int r = 0; r < 4; ++r) {
                int row = wr * 64 + mi * 16 + kq * 4 + r;
                int col = wc * 32 + ni * 16 + r15;
                lA[row * 128 + (col ^ ((row & 7) << 3))] = f2bf(acc[mi][ni][r]);
            }
    __syncthreads();

    const u16* Ra = resA + ((long)b * HW2 + m0) * 128;
    u16* Cb = Yout + ((long)b * HW2 + m0) * 128;
    {
        int row = t >> 2, quarter = (t & 3) * 32;
        int sx = (row & 7) << 3;
#pragma unroll
        for (int q = 0; q < 4; ++q) {
            int c = quarter + q * 8;
            uint4 raw = *(const uint4*)(lA + row * 128 + (c ^ sx));
            uint4 rr = *(const uint4*)(Ra + (long)row * 128 + c);
            u16* pv = (u16*)&raw;
            const u16* rv = (const u16*)&rr;
#pragma unroll
            for (int u = 0; u < 8; ++u) {
                float hres = gelu_f(bf2f(rv[u]) * sA[c + u] + sB[c + u]);
                pv[u] = f2bf(bf2f(pv[u]) + s2[c + u] + hres);
            }
            *(uint4*)(Cb + (long)row * 128 + c) = raw;
        }
    }
}

// ---- second moment partials: M2p[blk] = Y_blk^T Y_blk (non-atomic stores) ----
__global__ __launch_bounds__(256) void k_moment(const u16* __restrict__ Y,
                                                float* __restrict__ M2p,
                                                float* __restrict__ csum) {
    __shared__ __align__(16) u16 T[8192];
    __shared__ float cred[16][16][8];
    const int t = threadIdx.x;
    const int lane = t & 63, w = t >> 6, wr = w >> 1, wc = w & 1;
    const int r15 = lane & 15, kq = lane >> 4;
    const long px0 = (long)blockIdx.x * 1024;
    float cs[8] = {};

    f32x4 acc[4][4];
#pragma unroll
    for (int i = 0; i < 4; ++i)
#pragma unroll
        for (int j = 0; j < 4; ++j) acc[i][j] = (f32x4){0.f, 0.f, 0.f, 0.f};

    for (int it = 0; it < 16; ++it) {
        uint4 rv[4];
#pragma unroll
        for (int i = 0; i < 4; ++i) {
            int s = i * 256 + t;
            int px = s >> 4, ch8 = (s & 15) * 8;
            rv[i] = *(const uint4*)(Y + (px0 + it * 64 + px) * 128 + ch8);
        }
#pragma unroll
        for (int i = 0; i < 4; ++i) {
            const u16* pv = (const u16*)&rv[i];
#pragma unroll
            for (int u = 0; u < 8; ++u) cs[u] += bf2f(pv[u]);
        }
        __syncthreads();
#pragma unroll
        for (int i = 0; i < 4; ++i) {
            int s = i * 256 + t;
            int px = s >> 4, ch8 = (s & 15) * 8;
            const u16* pv = (const u16*)&rv[i];
#pragma unroll
            for (int u = 0; u < 8; ++u) {
                int row = ch8 + u;
                T[row * 64 + 8 * ((px >> 3) ^ (row & 7)) + (px & 7)] = pv[u];
            }
        }
        __syncthreads();
#pragma unroll
        for (int ks = 0; ks < 2; ++ks) {
            const int ch = ks * 4 + kq;
            short8 af[4], bfv[4];
#pragma unroll
            for (int mi = 0; mi < 4; ++mi) {
                int row = wr * 64 + mi * 16 + r15;
                af[mi] = *(const short8*)(T + row * 64 + 8 * (ch ^ (row & 7)));
            }
#pragma unroll
            for (int ni = 0; ni < 4; ++ni) {
                int row = wc * 64 + ni * 16 + r15;
                bfv[ni] = *(const short8*)(T + row * 64 + 8 * (ch ^ (row & 7)));
            }
#pragma unroll
            for (int mi = 0; mi < 4; ++mi)
#pragma unroll
                for (int ni = 0; ni < 4; ++ni)
                    acc[mi][ni] = __builtin_amdgcn_mfma_f32_16x16x32_bf16(
                        af[mi], bfv[ni], acc[mi][ni], 0, 0, 0);
        }
    }
    {
        int g = t & 15, m = t >> 4;
#pragma unroll
        for (int u = 0; u < 8; ++u) cred[m][g][u] = cs[u];
    }
    __syncthreads();
    if (t < 128) {
        float s = 0.f;
#pragma unroll
        for (int m = 0; m < 16; ++m) s += cred[m][t >> 3][t & 7];
        atomicAdd(csum + (long)t * 16, s);
    }
    float* Mb = M2p + (long)blockIdx.x * 16384;
#pragma unroll
    for (int mi = 0; mi < 4; ++mi)
#pragma unroll
        for (int ni = 0; ni < 4; ++ni)
#pragma unroll
            for (int r = 0; r < 4; ++r) {
                int row = wr * 64 + mi * 16 + kq * 4 + r;
                int col = wc * 64 + ni * 16 + r15;
                Mb[row * 128 + col] = acc[mi][ni][r];
            }
}

// ---- reduce 128 M2 partials -> M2 dense ----
__global__ __launch_bounds__(256) void k_m2red(const float* __restrict__ M2p,
                                               float* __restrict__ M2) {
    int e = blockIdx.x * 256 + threadIdx.x;
    float s = 0.f;
    for (int p = 0; p < 128; ++p) s += M2p[(long)p * 16384 + e];
    M2[e] = s;
}

// ---- combine: per-out-channel BN2 scale/shift ----
__global__ __launch_bounds__(128) void k_statcomb(const float* __restrict__ w_c2,
                                                  const float* __restrict__ M2,
                                                  const float* __restrict__ csum,
                                                  const float* __restrict__ g,
                                                  const float* __restrict__ bb,
                                                  float* __restrict__ scsh) {
    __shared__ float wl[128];
    __shared__ float red[2][2];
    const int o = blockIdx.x, c = threadIdx.x;
    wl[c] = w_c2[o * 128 + c];
    __syncthreads();
    const float* m2r = M2 + c * 128;
    float tmp = 0.f;
#pragma unroll
    for (int c2 = 0; c2 < 128; c2 += 4) {
        float4 m = *(const float4*)(m2r + c2);
        tmp += m.x * wl[c2] + m.y * wl[c2 + 1] + m.z * wl[c2 + 2] + m.w * wl[c2 + 3];
    }
    float s2p = wl[c] * tmp;
    float mup = wl[c] * csum[(long)c * 16];
#pragma unroll
    for (int off = 32; off; off >>= 1) {
        s2p += __shfl_down(s2p, off);
        mup += __shfl_down(mup, off);
    }
    if ((c & 63) == 0) { red[0][c >> 6] = s2p; red[1][c >> 6] = mup; }
    __syncthreads();
    if (c == 0) {
        float s2 = (red[0][0] + red[0][1]) / NPIX;
        float mu = (red[1][0] + red[1][1]) / NPIX;
        float var = s2 - mu * mu;
        float rs = rsqrtf(var + 1e-5f);
        float sc = g[o] * rs;
        scsh[o] = sc;
        scsh[512 + o] = bb[o] - mu * sc;
    }
}

// ---- conv2 + BN2 + GELU + IDWT -> out f32 NCHW; 512 threads, NT stores ----
__global__ __launch_bounds__(512) void k_conv2_idwt(const u16* __restrict__ Y,
                                                    const u16* __restrict__ Wc,
                                                    const float* __restrict__ scsh,
                                                    float* __restrict__ out) {
    __shared__ __align__(16) u16 lA[16384];
    __shared__ __align__(16) u16 lB[8192];
    __shared__ float sparam[1024];
    const int t = threadIdx.x;
    const int lane = t & 63, w = t >> 6, wr = w & 1, wc = w >> 1;
    const int r15 = lane & 15, kq = lane >> 4;
    const int b = blockIdx.y, n0 = blockIdx.x;
#pragma unroll
    for (int u = 0; u < 2; ++u) sparam[t + u * 512] = scsh[t + u * 512];

    const u16* Yb = Y + ((long)b * HW2 + (long)n0 * 64) * 128;
    uint4 rb2[2], ra4[4];
#pragma unroll
    for (int i = 0; i < 2; ++i) {
        int s = i * 512 + t, row = s >> 4, seg = s & 15;
        rb2[i] = *(const uint4*)(Yb + (long)row * 128 + seg * 8);
    }
#define GLOADA(q)                                                                \
    {                                                                            \
        _Pragma("unroll")                                                        \
        for (int i = 0; i < 4; ++i) {                                            \
            int s = i * 512 + t, row = s >> 4, seg = s & 15;                     \
            ra4[i] = *(const uint4*)(Wc + (long)((q) * 128 + row) * 128 + seg * 8); \
        }                                                                        \
    }
#define LWRITEA()                                                                \
    {                                                                            \
        _Pragma("unroll")                                                        \
        for (int i = 0; i < 4; ++i) {                                            \
            int s = i * 512 + t, row = s >> 4, seg = s & 15;                     \
            *(uint4*)((char*)lA + (seg >> 3) * 16384 + row * 128 +               \
                      16 * ((seg & 7) ^ (row & 7))) = ra4[i];                    \
        }                                                                        \
    }
    GLOADA(0)
#pragma unroll
    for (int i = 0; i < 2; ++i) {
        int s = i * 512 + t, row = s >> 4, seg = s & 15;
        *(uint4*)((char*)lB + (seg >> 3) * 8192 + row * 128 +
                  16 * ((seg & 7) ^ (row & 7))) = rb2[i];
    }
    LWRITEA()
    __syncthreads();

    u32 sbp[4][4][2];
#pragma unroll
    for (int q = 0; q < 4; ++q) {
        f32x4 acc[4];
#pragma unroll
        for (int mi = 0; mi < 4; ++mi) acc[mi] = (f32x4){0.f, 0.f, 0.f, 0.f};
#pragma unroll
        for (int chunk = 0; chunk < 2; ++chunk)
#pragma unroll
            for (int ks = 0; ks < 2; ++ks) {
                const int ch = ks * 4 + kq;
                short8 af[4], bfv;
#pragma unroll
                for (int mi = 0; mi < 4; ++mi) {
                    int row = wr * 64 + mi * 16 + r15;
                    af[mi] = *(const short8*)((const char*)lA + chunk * 16384 +
                                              row * 128 + 16 * (ch ^ (row & 7)));
                }
                {
                    int row = wc * 16 + r15;
                    bfv = *(const short8*)((const char*)lB + chunk * 8192 +
                                           row * 128 + 16 * (ch ^ (row & 7)));
                }
#pragma unroll
                for (int mi = 0; mi < 4; ++mi)
                    acc[mi] = __builtin_amdgcn_mfma_f32_16x16x32_bf16(
                        af[mi], bfv, acc[mi], 0, 0, 0);
            }
        if (q < 3) GLOADA(q + 1)
#pragma unroll
        for (int mi = 0; mi < 4; ++mi)
#pragma unroll
            for (int rp = 0; rp < 2; ++rp) {
                int c0 = q * 128 + wr * 64 + mi * 16 + kq * 4 + rp * 2;
                float v0 = gelu_f(acc[mi][rp * 2] * sparam[c0] + sparam[512 + c0]);
                float v1 = gelu_f(acc[mi][rp * 2 + 1] * sparam[c0 + 1] + sparam[512 + c0 + 1]);
                sbp[q][mi][rp] = (u32)f2bf(v0) | ((u32)f2bf(v1) << 16);
            }
        if (q < 3) {
            __syncthreads();
            LWRITEA()
            __syncthreads();
        }
    }
    const int i = n0 >> 1;
    const int j = (n0 & 1) * 64 + wc * 16 + r15;
#pragma unroll
    for (int mi = 0; mi < 4; ++mi)
#pragma unroll
        for (int rp = 0; rp < 2; ++rp) {
            u32 p0 = sbp[0][mi][rp], p1 = sbp[1][mi][rp];
            u32 p2 = sbp[2][mi][rp], p3 = sbp[3][mi][rp];
#pragma unroll
            for (int e = 0; e < 2; ++e) {
                int c = wr * 64 + mi * 16 + kq * 4 + rp * 2 + e;
                float ll = bf2f(e ? (u16)(p0 >> 16) : (u16)(p0 & 0xFFFF));
                float lh = bf2f(e ? (u16)(p1 >> 16) : (u16)(p1 & 0xFFFF));
                float hl = bf2f(e ? (u16)(p2 >> 16) : (u16)(p2 & 0xFFFF));
                float hh = bf2f(e ? (u16)(p3 >> 16) : (u16)(p3 & 0xFFFF));
                long ob = (((long)(b * Cc + c) * Hh + 2 * i) * Wf + 2 * j);
                union { float2 v; u64 u; } w0, w1;
                w0.v = make_float2((ll + lh + hl + hh) * 0.5f, (ll + lh - hl - hh) * 0.5f);
                w1.v = make_float2((ll - lh + hl - hh) * 0.5f, (ll - lh - hl + hh) * 0.5f);
                __builtin_nontemporal_store(w0.u, (u64*)(out + ob));
                __builtin_nontemporal_store(w1.u, (u64*)(out + ob + Wf));
            }
        }
#undef GLOADA
#undef LWRITEA
}

extern "C" void kernel_launch(void* const* d_in, const int* in_sizes, int n_in,
                              void* d_out, int out_size, void* d_ws, size_t ws_size,
                              hipStream_t stream) {
    const float* x     = (const float*)d_in[0];
    const float* w_c1  = (const float*)d_in[1];
    const float* bn1_g = (const float*)d_in[3];
    const float* bn1_b = (const float*)d_in[4];
    const float* dw_w  = (const float*)d_in[5];
    const float* dw_b  = (const float*)d_in[6];
    const float* gn_g  = (const float*)d_in[7];
    const float* gn_b  = (const float*)d_in[8];
    const float* pw1_w = (const float*)d_in[9];
    const float* pw1_b = (const float*)d_in[10];
    const float* pw2_w = (const float*)d_in[11];
    const float* pw2_b = (const float*)d_in[12];
    const float* w_c2  = (const float*)d_in[13];
    const float* bn2_g = (const float*)d_in[15];
    const float* bn2_b = (const float*)d_in[16];
    float* out = (float*)d_out;

    const size_t n128 = (size_t)Bq * Cc * HW2;
    u16* bufA = (u16*)d_ws;
    u16* bufD = bufA + n128;
    u16* bufY = bufD + n128;
    u16* wb   = bufY + n128;
    float* stats = (float*)(wb + 163840);
    float* M2p = stats + 49152;
    size_t need = (3 * n128 + 163840) * 2 + (49152 + 128 * 16384) * 4;
    if (ws_size < need) return;

    float* bn1_sum = stats;
    float* bn1_sq  = stats + 2048;
    float* ln_sum  = stats + 4096;
    float* ln_sq   = stats + 12288;
    float* csum    = stats + 20480;
    float* M2      = stats + 22528;
    float* scsh    = stats + 38912;
    float* wbv     = stats + 39936;
    float* wgs     = stats + 40064;

    // 0. weights -> bf16 + stats zeroing + LN-fold vectors (block 640)
    k_wconv<<<641, 256, 0, stream>>>(w_c1, pw1_w, pw2_w, w_c2, gn_g, gn_b,
                                     wb, wbv, wgs, stats);

    // 1. fused DWT + conv1 + BN1 stats
    k_conv1<<<dim3(1, 128, 8), 512, 0, stream>>>(x, wb, bufA, bn1_sum, bn1_sq);

    // 2. depthwise 3x3, 4-row tiles, fused BN1+gelu on load + LN stats
    k_dwconv<<<dim3(8, 32, 8), 256, 0, stream>>>(bufA, bufD, dw_w, dw_b,
                                                 bn1_sum, bn1_sq, bn1_g, bn1_b,
                                                 ln_sum, ln_sq);

    // 3. fused MLP (512 thr): pw1 (LN-folded + gelu) -> pw2 (+bias + residual)
    k_mlp<<<dim3(1, 128, 8), 512, 0, stream>>>(
        bufD, wb + 65536, wb + 81920, pw1_b, pw2_b, bufA, bufY,
        ln_sum, ln_sq, wbv, wgs, bn1_sum, bn1_sq, bn1_g, bn1_b);

    // 4. BN2 stats: per-block M2 partials + reduce + combine
    k_moment<<<128, 256, 0, stream>>>(bufY, M2p, csum);
    k_m2red<<<64, 256, 0, stream>>>(M2p, M2);
    k_statcomb<<<512, 128, 0, stream>>>(w_c2, M2, csum, bn2_g, bn2_b, scsh);

    // 5. conv2 + BN2 + gelu + IDWT -> out (NT stores)
    k_conv2_idwt<<<dim3(256, 8), 512, 0, stream>>>(bufY, wb + 98304, scsh, out);
}

// Round 14
// 381.048 us; speedup vs baseline: 2.4186x; 1.0344x over previous
//
#include <hip/hip_runtime.h>
#include <hip/hip_bf16.h>

typedef unsigned short u16;
typedef unsigned int u32;
typedef unsigned long long u64;
typedef __attribute__((ext_vector_type(8))) short short8;
typedef __attribute__((ext_vector_type(4))) float f32x4;

#define Bq 8
#define Cc 128
#define C4 512
#define Hh 256
#define Wf 256
#define H2 128
#define W2 128
#define HW2 16384
#define NPIX 131072.0f

__device__ __forceinline__ float gelu_f(float x) {
    float u = 1.5957691216057308f * (x + 0.044715f * x * x * x);
    float t = 1.0f - 2.0f / (__expf(u) + 1.0f);
    return 0.5f * x * (1.0f + t);
}
__device__ __forceinline__ float bf2f(u16 u) {
    union { float f; u32 i; } v; v.i = ((u32)u) << 16; return v.f;
}
__device__ __forceinline__ u16 f2bf(float f) {
    union { float f; u32 i; } v; v.f = f;
    u32 r = v.i + 0x7FFFu + ((v.i >> 16) & 1u);
    return (u16)(r >> 16);
}

// ---- weights f32 -> bf16; block 640: zero stats + LN-fold vectors ----
__global__ __launch_bounds__(256) void k_wconv(const float* __restrict__ w_c1,
                                               const float* __restrict__ pw1,
                                               const float* __restrict__ pw2,
                                               const float* __restrict__ w_c2,
                                               const float* __restrict__ gn_g,
                                               const float* __restrict__ gn_b,
                                               u16* __restrict__ wb,
                                               float* __restrict__ wbv,
                                               float* __restrict__ wgs,
                                               float* __restrict__ stats0) {
    if (blockIdx.x == 640) {
        for (int e = threadIdx.x; e < 22528; e += 256) stats0[e] = 0.f;
        int o = threadIdx.x;
        if (o < 128) {
            float a = 0.f, bv = 0.f;
            for (int c = 0; c < 128; ++c) {
                float w_ = pw1[o * 128 + c];
                a += w_ * gn_g[c];
                bv += w_ * gn_b[c];
            }
            wgs[o] = a;
            wbv[o] = bv;
        }
        return;
    }
    int i = blockIdx.x * 256 + threadIdx.x;   // 0..163839
    float v;
    if (i < 65536) {
        int o = i >> 9, kn = i & 511;
        int c = kn >> 2, dy = (kn >> 1) & 1, dx = kn & 1;
        float sdy = dy ? -1.f : 1.f, sdx = dx ? -1.f : 1.f;
        const float* wr = w_c1 + o * 512 + c;
        v = 0.5f * (wr[0] + sdy * wr[128] + sdx * wr[256] + sdy * sdx * wr[384]);
    } else if (i < 81920) v = pw1[i - 65536] * gn_g[(i - 65536) & 127];
    else if (i < 98304) v = pw2[i - 81920];
    else v = w_c2[i - 98304];
    wb[i] = f2bf(v);
}

// ---- fused DWT+conv1+BN1-stats: reads x f32 NCHW directly (512 thr) ----
__global__ __launch_bounds__(512) void k_conv1(const float* __restrict__ x,
                                               const u16* __restrict__ Wt,
                                               u16* __restrict__ Cout,
                                               float* __restrict__ statS,
                                               float* __restrict__ statQ) {
    __shared__ __align__(16) u16 lds[16384];
    __shared__ float sblk[128], qblk[128];
    const int t = threadIdx.x;
    const int lane = t & 63, w = t >> 6, wr = w & 1, wc = w >> 1;
    const int b = blockIdx.z, i = blockIdx.y;
    if (t < 128) { sblk[t] = 0.f; qblk[t] = 0.f; }

    const int r15 = lane & 15, kq = lane >> 4;
    const int half = t >> 8;
    const int colblk = t & 7, cc = (t >> 3) & 15, dy = (t >> 7) & 1;
    const int kbase = cc * 4 + dy * 2;
    const int gG = kbase >> 3, e2 = (kbase & 7) * 2;

    float4 xv[4];
    uint4 rb[2];
    {
        const float* xp = x + (((long)(b * Cc + cc)) * Hh + (2 * i + dy)) * Wf;
#pragma unroll
        for (int q = 0; q < 4; ++q) {
            int col = (half * 4 + q) * 32 + colblk * 4;
            xv[q] = *(const float4*)(xp + col);
        }
#pragma unroll
        for (int ii = 0; ii < 2; ++ii) {
            int s = ii * 512 + t;
            rb[ii] = *(const uint4*)(Wt + (long)(s >> 3) * 512 + (s & 7) * 8);
        }
    }

    f32x4 acc[4][2];
#pragma unroll
    for (int a2 = 0; a2 < 4; ++a2)
#pragma unroll
        for (int j2 = 0; j2 < 2; ++j2) acc[a2][j2] = (f32x4){0.f, 0.f, 0.f, 0.f};

    for (int k0 = 0; k0 < 512; k0 += 64) {
        __syncthreads();
#pragma unroll
        for (int q = 0; q < 4; ++q) {
            int col = (half * 4 + q) * 32 + colblk * 4;
            int j0 = col >> 1;
            u32 p0 = (u32)f2bf(xv[q].x) | ((u32)f2bf(xv[q].y) << 16);
            u32 p1 = (u32)f2bf(xv[q].z) | ((u32)f2bf(xv[q].w) << 16);
            *(u32*)((char*)lds + j0 * 128 + 16 * (gG ^ (j0 & 7)) + e2) = p0;
            *(u32*)((char*)lds + (j0 + 1) * 128 + 16 * (gG ^ ((j0 + 1) & 7)) + e2) = p1;
        }
#pragma unroll
        for (int ii = 0; ii < 2; ++ii) {
            int s = ii * 512 + t;
            int row_ = s >> 3, ch_ = s & 7;
            *(uint4*)((char*)lds + 16384 + row_ * 128 + 16 * (ch_ ^ (row_ & 7))) = rb[ii];
        }
        __syncthreads();
        if (k0 + 64 < 512) {
            const int c0n = (k0 + 64) >> 2;
            const float* xp = x + (((long)(b * Cc + c0n + cc)) * Hh + (2 * i + dy)) * Wf;
#pragma unroll
            for (int q = 0; q < 4; ++q) {
                int col = (half * 4 + q) * 32 + colblk * 4;
                xv[q] = *(const float4*)(xp + col);
            }
#pragma unroll
            for (int ii = 0; ii < 2; ++ii) {
                int s = ii * 512 + t;
                rb[ii] = *(const uint4*)(Wt + (long)(s >> 3) * 512 + (k0 + 64) + (s & 7) * 8);
            }
        }
#pragma unroll
        for (int ks = 0; ks < 2; ++ks) {
            short8 af[4], bfv[2];
            const int ch = ks * 4 + kq;
#pragma unroll
            for (int mi = 0; mi < 4; ++mi) {
                int row = wr * 64 + mi * 16 + r15;
                af[mi] = *(const short8*)((const char*)lds + row * 128 + 16 * (ch ^ (row & 7)));
            }
#pragma unroll
            for (int ni = 0; ni < 2; ++ni) {
                int row = wc * 32 + ni * 16 + r15;
                bfv[ni] = *(const short8*)((const char*)lds + 16384 + row * 128 + 16 * (ch ^ (row & 7)));
            }
#pragma unroll
            for (int mi = 0; mi < 4; ++mi)
#pragma unroll
                for (int ni = 0; ni < 2; ++ni)
                    acc[mi][ni] = __builtin_amdgcn_mfma_f32_16x16x32_bf16(
                        af[mi], bfv[ni], acc[mi][ni], 0, 0, 0);
        }
    }
    __syncthreads();

#pragma unroll
    for (int mi = 0; mi < 4; ++mi)
#pragma unroll
        for (int ni = 0; ni < 2; ++ni)
#pragma unroll
            for (int r = 0; r < 4; ++r) {
                int row = wr * 64 + mi * 16 + kq * 4 + r;
                int col = wc * 32 + ni * 16 + r15;
                lds[row * 128 + (col ^ ((row & 7) << 3))] = f2bf(acc[mi][ni][r]);
            }
#pragma unroll
    for (int ni = 0; ni < 2; ++ni) {
        float s = 0.f, q2 = 0.f;
#pragma unroll
        for (int mi = 0; mi < 4; ++mi)
#pragma unroll
            for (int r = 0; r < 4; ++r) {
                float v = acc[mi][ni][r];
                s += v; q2 += v * v;
            }
        s += __shfl_down(s, 32); s += __shfl_down(s, 16);
        q2 += __shfl_down(q2, 32); q2 += __shfl_down(q2, 16);
        if (lane < 16) {
            int col = wc * 32 + ni * 16 + r15;
            atomicAdd(&sblk[col], s);
            atomicAdd(&qblk[col], q2);
        }
    }
    __syncthreads();
    {
        u16* Cb = Cout + (long)b * HW2 * 128;
        int row = t >> 2, quarter = (t & 3) * 32;
        int sx = (row & 7) << 3;
        long gbase = (long)(i * 128 + row) * 128;
#pragma unroll
        for (int q = 0; q < 4; ++q) {
            int c = quarter + q * 8;
            *(uint4*)(Cb + gbase + c) = *(const uint4*)(lds + row * 128 + (c ^ sx));
        }
    }
    if (t < 128) {
        atomicAdd(statS + (long)t * 16, sblk[t]);
        atomicAdd(statQ + (long)t * 16, qblk[t]);
    }
}

// ---- depthwise 3x3 NHWC, 4-row tile, fused BN1+gelu + LN stats ----
__global__ __launch_bounds__(256) void k_dwconv(const u16* __restrict__ xin,
                                                u16* __restrict__ y,
                                                const float* __restrict__ w,
                                                const float* __restrict__ bias,
                                                const float* __restrict__ bnS,
                                                const float* __restrict__ bnQ,
                                                const float* __restrict__ g1,
                                                const float* __restrict__ b1,
                                                float* __restrict__ lnS,
                                                float* __restrict__ lnQ) {
    __shared__ float wl2[1152];
    __shared__ float sA[128], sB[128];
    __shared__ __align__(16) u16 tile[108 * 136];
    const int t = threadIdx.x;
    if (t < 128) {
        const float invN = 1.0f / 131072.0f;
        float mu = bnS[(long)t * 16] * invN;
        float var = bnQ[(long)t * 16] * invN - mu * mu;
        float rs = rsqrtf(var + 1e-5f);
        float sc = rs * g1[t];
        sA[t] = sc;
        sB[t] = b1[t] - mu * sc;
    }
    for (int idx = t; idx < 1152; idx += 256) {
        int c = idx / 9, tap = idx - c * 9;
        wl2[tap * 128 + (c & 7) * 16 + (c >> 3)] = w[idx];
    }
    __syncthreads();
    const int jbase = blockIdx.x * 16, i0 = blockIdx.y * 4, b = blockIdx.z;
    const u16* xb = xin + (long)b * HW2 * 128;
    {
        int seg = t & 15, slot0 = t >> 4;
#pragma unroll
        for (int pass = 0; pass < 7; ++pass) {
            int slot = pass * 16 + slot0;
            if (slot < 108) {
                int r = slot / 18, p = slot - r * 18;
                int row = i0 - 1 + r, col = jbase - 1 + p;
                bool inb = (row >= 0) & (row < H2) & (col >= 0) & (col < W2);
                uint4 raw = inb ? *(const uint4*)(xb + ((long)row * W2 + col) * 128 + seg * 8)
                                : make_uint4(0u, 0u, 0u, 0u);
                const u16* pv = (const u16*)&raw;
                uint4 outv; u16* ov = (u16*)&outv;
#pragma unroll
                for (int u = 0; u < 8; ++u) {
                    int c = seg * 8 + u;
                    float v = inb ? gelu_f(bf2f(pv[u]) * sA[c] + sB[c]) : 0.f;
                    ov[u] = f2bf(v);
                }
                *(uint4*)(tile + slot * 136 + seg * 8) = outv;
            }
        }
    }
    __syncthreads();
    const int cg = t & 15, jj = t >> 4;
    float s = 0.f, q2 = 0.f;
    float bi[8];
#pragma unroll
    for (int u = 0; u < 8; ++u) bi[u] = bias[cg * 8 + u];
#pragma unroll
    for (int dr = 0; dr < 4; ++dr) {
        float acc[8];
#pragma unroll
        for (int u = 0; u < 8; ++u) acc[u] = bi[u];
#pragma unroll
        for (int r = 0; r < 3; ++r)
#pragma unroll
            for (int dj = 0; dj < 3; ++dj) {
                short8 vv = *(const short8*)(tile + ((dr + r) * 18 + jj + dj) * 136 + cg * 8);
                const int tap = r * 3 + dj;
#pragma unroll
                for (int u = 0; u < 8; ++u)
                    acc[u] = fmaf(bf2f((u16)vv[u]), wl2[tap * 128 + u * 16 + cg], acc[u]);
            }
        uint4 outv; u16* ov = (u16*)&outv;
#pragma unroll
        for (int u = 0; u < 8; ++u) {
            ov[u] = f2bf(acc[u]);
            s += acc[u]; q2 += acc[u] * acc[u];
        }
        *(uint4*)(y + ((long)b * HW2 + (long)(i0 + dr) * W2 + jbase + jj) * 128 + cg * 8) = outv;
    }
#pragma unroll
    for (int off = 32; off; off >>= 1) {
        s += __shfl_down(s, off);
        q2 += __shfl_down(q2, off);
    }
    __shared__ float r1[4], r2[4];
    if ((t & 63) == 0) { r1[t >> 6] = s; r2[t >> 6] = q2; }
    __syncthreads();
    if (t == 0) {
        int slot = (blockIdx.y * 8 + blockIdx.x) & 63;
        atomicAdd(lnS + ((long)b * 64 + slot) * 16, r1[0] + r1[1] + r1[2] + r1[3]);
        atomicAdd(lnQ + ((long)b * 64 + slot) * 16, r2[0] + r2[1] + r2[2] + r2[3]);
    }
}

// ---- fused MLP (512 thr): pw1 -> pw2, residual recomputed; W2 prefetch hoisted --
__global__ __launch_bounds__(512) void k_mlp(const u16* __restrict__ D,
                                             const u16* __restrict__ Wp1,
                                             const u16* __restrict__ Wp2,
                                             const float* __restrict__ b1p,
                                             const float* __restrict__ b2p,
                                             const u16* __restrict__ resA,
                                             u16* __restrict__ Yout,
                                             const float* __restrict__ lnS,
                                             const float* __restrict__ lnQ,
                                             const float* __restrict__ wbv,
                                             const float* __restrict__ wgs,
                                             const float* __restrict__ bnS,
                                             const float* __restrict__ bnQ,
                                             const float* __restrict__ g1,
                                             const float* __restrict__ b1v) {
    __shared__ __align__(16) u16 lA[16384];
    __shared__ __align__(16) u16 lB[16384];
    __shared__ float s1[128], s2[128], sA[128], sB[128], lnred[2];
    const int t = threadIdx.x;
    const int lane = t & 63, w = t >> 6, wr = w & 1, wc = w >> 1;
    const int r15 = lane & 15, kq = lane >> 4;
    const int b = blockIdx.z, m0 = blockIdx.y * 128;

    if (t < 64) {
        float s = lnS[((long)b * 64 + t) * 16];
        float q = lnQ[((long)b * 64 + t) * 16];
#pragma unroll
        for (int off = 32; off; off >>= 1) {
            s += __shfl_down(s, off);
            q += __shfl_down(q, off);
        }
        if (t == 0) { lnred[0] = s; lnred[1] = q; }
    }
    __syncthreads();
    const float invN = 1.0f / 2097152.0f;
    float mu = lnred[0] * invN;
    float var = lnred[1] * invN - mu * mu;
    const float rs = rsqrtf(var + 1e-5f);
    if (t < 128) {
        s1[t] = b1p[t] + wbv[t] - mu * rs * wgs[t];
        s2[t] = b2p[t];
        const float invN1 = 1.0f / 131072.0f;
        float mu1 = bnS[(long)t * 16] * invN1;
        float var1 = bnQ[(long)t * 16] * invN1 - mu1 * mu1;
        float rs1 = rsqrtf(var1 + 1e-5f);
        float sc1 = rs1 * g1[t];
        sA[t] = sc1;
        sB[t] = b1v[t] - mu1 * sc1;
    }

    const u16* Ab = D + ((long)b * HW2 + m0) * 128;
    uint4 ga[4], gb[4];
#pragma unroll
    for (int i = 0; i < 4; ++i) {
        int s = i * 512 + t, row = s >> 4, seg = s & 15;
        ga[i] = *(const uint4*)(Ab + (long)row * 128 + seg * 8);
        gb[i] = *(const uint4*)(Wp1 + (long)row * 128 + seg * 8);
    }
#pragma unroll
    for (int i = 0; i < 4; ++i) {
        int s = i * 512 + t, row = s >> 4, seg = s & 15;
        int off = (seg >> 3) * 16384 + row * 128 + 16 * ((seg & 7) ^ (row & 7));
        *(uint4*)((char*)lA + off) = ga[i];
        *(uint4*)((char*)lB + off) = gb[i];
    }
    __syncthreads();
    // prefetch pw2 weights EARLY (hides under GEMM1 MFMA)
#pragma unroll
    for (int i = 0; i < 4; ++i) {
        int s = i * 512 + t, row = s >> 4, seg = s & 15;
        gb[i] = *(const uint4*)(Wp2 + (long)row * 128 + seg * 8);
    }

    f32x4 acc[4][2];
#pragma unroll
    for (int i = 0; i < 4; ++i)
#pragma unroll
        for (int j = 0; j < 2; ++j) acc[i][j] = (f32x4){0.f, 0.f, 0.f, 0.f};
#pragma unroll
    for (int chunk = 0; chunk < 2; ++chunk)
#pragma unroll
        for (int ks = 0; ks < 2; ++ks) {
            const int ch = ks * 4 + kq;
            short8 af[4], bfv[2];
#pragma unroll
            for (int mi = 0; mi < 4; ++mi) {
                int row = wr * 64 + mi * 16 + r15;
                af[mi] = *(const short8*)((const char*)lA + chunk * 16384 +
                                          row * 128 + 16 * (ch ^ (row & 7)));
            }
#pragma unroll
            for (int ni = 0; ni < 2; ++ni) {
                int row = wc * 32 + ni * 16 + r15;
                bfv[ni] = *(const short8*)((const char*)lB + chunk * 16384 +
                                           row * 128 + 16 * (ch ^ (row & 7)));
            }
#pragma unroll
            for (int mi = 0; mi < 4; ++mi)
#pragma unroll
                for (int ni = 0; ni < 2; ++ni)
                    acc[mi][ni] = __builtin_amdgcn_mfma_f32_16x16x32_bf16(
                        af[mi], bfv[ni], acc[mi][ni], 0, 0, 0);
        }
    __syncthreads();   // all lA/lB reads complete

    // bounce1: gelu(rs*acc + s1[ch]) -> lA in GEMM-A k-major layout (k = ch)
#pragma unroll
    for (int mi = 0; mi < 4; ++mi)
#pragma unroll
        for (int ni = 0; ni < 2; ++ni)
#pragma unroll
            for (int r = 0; r < 4; ++r) {
                int row = wr * 64 + mi * 16 + kq * 4 + r;
                int col = wc * 32 + ni * 16 + r15;
                float v = gelu_f(rs * acc[mi][ni][r] + s1[col]);
                lA[(col >> 6) * 8192 + row * 64 +
                   8 * (((col >> 3) & 7) ^ (row & 7)) + (col & 7)] = f2bf(v);
            }
#pragma unroll
    for (int i = 0; i < 4; ++i) {
        int s = i * 512 + t, row = s >> 4, seg = s & 15;
        int off = (seg >> 3) * 16384 + row * 128 + 16 * ((seg & 7) ^ (row & 7));
        *(uint4*)((char*)lB + off) = gb[i];
    }
    __syncthreads();

    // GEMM2
#pragma unroll
    for (int i = 0; i < 4; ++i)
#pragma unroll
        for (int j = 0; j < 2; ++j) acc[i][j] = (f32x4){0.f, 0.f, 0.f, 0.f};
#pragma unroll
    for (int chunk = 0; chunk < 2; ++chunk)
#pragma unroll
        for (int ks = 0; ks < 2; ++ks) {
            const int ch = ks * 4 + kq;
            short8 af[4], bfv[2];
#pragma unroll
            for (int mi = 0; mi < 4; ++mi) {
                int row = wr * 64 + mi * 16 + r15;
                af[mi] = *(const short8*)((const char*)lA + chunk * 16384 +
                                          row * 128 + 16 * (ch ^ (row & 7)));
            }
#pragma unroll
            for (int ni = 0; ni < 2; ++ni) {
                int row = wc * 32 + ni * 16 + r15;
                bfv[ni] = *(const short8*)((const char*)lB + chunk * 16384 +
                                           row * 128 + 16 * (ch ^ (row & 7)));
            }
#pragma unroll
            for (int mi = 0; mi < 4; ++mi)
#pragma unroll
                for (int ni = 0; ni < 2; ++ni)
                    acc[mi][ni] = __builtin_amdgcn_mfma_f32_16x16x32_bf16(
                        af[mi], bfv[ni], acc[mi][ni], 0, 0, 0);
        }
    __syncthreads();

#pragma unroll
    for (int mi = 0; mi < 4; ++mi)
#pragma unroll
        for (int ni = 0; ni < 2; ++ni)
#pragma unroll
            for (int r = 0; r < 4; ++r) {
                int row = wr * 64 + mi * 16 + kq * 4 + r;
                int col = wc * 32 + ni * 16 + r15;
                lA[row * 128 + (col ^ ((row & 7) << 3))] = f2bf(acc[mi][ni][r]);
            }
    __syncthreads();

    const u16* Ra = resA + ((long)b * HW2 + m0) * 128;
    u16* Cb = Yout + ((long)b * HW2 + m0) * 128;
    {
        int row = t >> 2, quarter = (t & 3) * 32;
        int sx = (row & 7) << 3;
#pragma unroll
        for (int q = 0; q < 4; ++q) {
            int c = quarter + q * 8;
            uint4 raw = *(const uint4*)(lA + row * 128 + (c ^ sx));
            uint4 rr = *(const uint4*)(Ra + (long)row * 128 + c);
            u16* pv = (u16*)&raw;
            const u16* rv = (const u16*)&rr;
#pragma unroll
            for (int u = 0; u < 8; ++u) {
                float hres = gelu_f(bf2f(rv[u]) * sA[c + u] + sB[c + u]);
                pv[u] = f2bf(bf2f(pv[u]) + s2[c + u] + hres);
            }
            *(uint4*)(Cb + (long)row * 128 + c) = raw;
        }
    }
}

// ---- second moment partials: 256 blocks x 512 px (full-GPU utilization) ----
__global__ __launch_bounds__(256) void k_moment(const u16* __restrict__ Y,
                                                float* __restrict__ M2p,
                                                float* __restrict__ csum) {
    __shared__ __align__(16) u16 T[8192];
    __shared__ float cred[16][16][8];
    const int t = threadIdx.x;
    const int lane = t & 63, w = t >> 6, wr = w >> 1, wc = w & 1;
    const int r15 = lane & 15, kq = lane >> 4;
    const long px0 = (long)blockIdx.x * 512;
    float cs[8] = {};

    f32x4 acc[4][4];
#pragma unroll
    for (int i = 0; i < 4; ++i)
#pragma unroll
        for (int j = 0; j < 4; ++j) acc[i][j] = (f32x4){0.f, 0.f, 0.f, 0.f};

    for (int it = 0; it < 8; ++it) {
        uint4 rv[4];
#pragma unroll
        for (int i = 0; i < 4; ++i) {
            int s = i * 256 + t;
            int px = s >> 4, ch8 = (s & 15) * 8;
            rv[i] = *(const uint4*)(Y + (px0 + it * 64 + px) * 128 + ch8);
        }
#pragma unroll
        for (int i = 0; i < 4; ++i) {
            const u16* pv = (const u16*)&rv[i];
#pragma unroll
            for (int u = 0; u < 8; ++u) cs[u] += bf2f(pv[u]);
        }
        __syncthreads();
#pragma unroll
        for (int i = 0; i < 4; ++i) {
            int s = i * 256 + t;
            int px = s >> 4, ch8 = (s & 15) * 8;
            const u16* pv = (const u16*)&rv[i];
#pragma unroll
            for (int u = 0; u < 8; ++u) {
                int row = ch8 + u;
                T[row * 64 + 8 * ((px >> 3) ^ (row & 7)) + (px & 7)] = pv[u];
            }
        }
        __syncthreads();
#pragma unroll
        for (int ks = 0; ks < 2; ++ks) {
            const int ch = ks * 4 + kq;
            short8 af[4], bfv[4];
#pragma unroll
            for (int mi = 0; mi < 4; ++mi) {
                int row = wr * 64 + mi * 16 + r15;
                af[mi] = *(const short8*)(T + row * 64 + 8 * (ch ^ (row & 7)));
            }
#pragma unroll
            for (int ni = 0; ni < 4; ++ni) {
                int row = wc * 64 + ni * 16 + r15;
                bfv[ni] = *(const short8*)(T + row * 64 + 8 * (ch ^ (row & 7)));
            }
#pragma unroll
            for (int mi = 0; mi < 4; ++mi)
#pragma unroll
                for (int ni = 0; ni < 4; ++ni)
                    acc[mi][ni] = __builtin_amdgcn_mfma_f32_16x16x32_bf16(
                        af[mi], bfv[ni], acc[mi][ni], 0, 0, 0);
        }
    }
    {
        int g = t & 15, m = t >> 4;
#pragma unroll
        for (int u = 0; u < 8; ++u) cred[m][g][u] = cs[u];
    }
    __syncthreads();
    if (t < 128) {
        float s = 0.f;
#pragma unroll
        for (int m = 0; m < 16; ++m) s += cred[m][t >> 3][t & 7];
        atomicAdd(csum + (long)t * 16, s);
    }
    float* Mb = M2p + (long)blockIdx.x * 16384;
#pragma unroll
    for (int mi = 0; mi < 4; ++mi)
#pragma unroll
        for (int ni = 0; ni < 4; ++ni)
#pragma unroll
            for (int r = 0; r < 4; ++r) {
                int row = wr * 64 + mi * 16 + kq * 4 + r;
                int col = wc * 64 + ni * 16 + r15;
                Mb[row * 128 + col] = acc[mi][ni][r];
            }
}

// ---- reduce 256 M2 partials -> M2 dense ----
__global__ __launch_bounds__(256) void k_m2red(const float* __restrict__ M2p,
                                               float* __restrict__ M2) {
    int e = blockIdx.x * 256 + threadIdx.x;
    float s = 0.f;
    for (int p = 0; p < 256; ++p) s += M2p[(long)p * 16384 + e];
    M2[e] = s;
}

// ---- combine: per-out-channel BN2 scale/shift ----
__global__ __launch_bounds__(128) void k_statcomb(const float* __restrict__ w_c2,
                                                  const float* __restrict__ M2,
                                                  const float* __restrict__ csum,
                                                  const float* __restrict__ g,
                                                  const float* __restrict__ bb,
                                                  float* __restrict__ scsh) {
    __shared__ float wl[128];
    __shared__ float red[2][2];
    const int o = blockIdx.x, c = threadIdx.x;
    wl[c] = w_c2[o * 128 + c];
    __syncthreads();
    const float* m2r = M2 + c * 128;
    float tmp = 0.f;
#pragma unroll
    for (int c2 = 0; c2 < 128; c2 += 4) {
        float4 m = *(const float4*)(m2r + c2);
        tmp += m.x * wl[c2] + m.y * wl[c2 + 1] + m.z * wl[c2 + 2] + m.w * wl[c2 + 3];
    }
    float s2p = wl[c] * tmp;
    float mup = wl[c] * csum[(long)c * 16];
#pragma unroll
    for (int off = 32; off; off >>= 1) {
        s2p += __shfl_down(s2p, off);
        mup += __shfl_down(mup, off);
    }
    if ((c & 63) == 0) { red[0][c >> 6] = s2p; red[1][c >> 6] = mup; }
    __syncthreads();
    if (c == 0) {
        float s2 = (red[0][0] + red[0][1]) / NPIX;
        float mu = (red[1][0] + red[1][1]) / NPIX;
        float var = s2 - mu * mu;
        float rs = rsqrtf(var + 1e-5f);
        float sc = g[o] * rs;
        scsh[o] = sc;
        scsh[512 + o] = bb[o] - mu * sc;
    }
}

// ---- conv2 + BN2 + GELU + IDWT; weight prefetch hoisted before MFMA ----
__global__ __launch_bounds__(512) void k_conv2_idwt(const u16* __restrict__ Y,
                                                    const u16* __restrict__ Wc,
                                                    const float* __restrict__ scsh,
                                                    float* __restrict__ out) {
    __shared__ __align__(16) u16 lA[16384];
    __shared__ __align__(16) u16 lB[8192];
    __shared__ float sparam[1024];
    const int t = threadIdx.x;
    const int lane = t & 63, w = t >> 6, wr = w & 1, wc = w >> 1;
    const int r15 = lane & 15, kq = lane >> 4;
    const int b = blockIdx.y, n0 = blockIdx.x;
#pragma unroll
    for (int u = 0; u < 2; ++u) sparam[t + u * 512] = scsh[t + u * 512];

    const u16* Yb = Y + ((long)b * HW2 + (long)n0 * 64) * 128;
    uint4 rb2[2], ra4[4];
#pragma unroll
    for (int i = 0; i < 2; ++i) {
        int s = i * 512 + t, row = s >> 4, seg = s & 15;
        rb2[i] = *(const uint4*)(Yb + (long)row * 128 + seg * 8);
    }
#define GLOADA(q)                                                                \
    {                                                                            \
        _Pragma("unroll")                                                        \
        for (int i = 0; i < 4; ++i) {                                            \
            int s = i * 512 + t, row = s >> 4, seg = s & 15;                     \
            ra4[i] = *(const uint4*)(Wc + (long)((q) * 128 + row) * 128 + seg * 8); \
        }                                                                        \
    }
#define LWRITEA()                                                                \
    {                                                                            \
        _Pragma("unroll")                                                        \
        for (int i = 0; i < 4; ++i) {                                            \
            int s = i * 512 + t, row = s >> 4, seg = s & 15;                     \
            *(uint4*)((char*)lA + (seg >> 3) * 16384 + row * 128 +               \
                      16 * ((seg & 7) ^ (row & 7))) = ra4[i];                    \
        }                                                                        \
    }
    GLOADA(0)
#pragma unroll
    for (int i = 0; i < 2; ++i) {
        int s = i * 512 + t, row = s >> 4, seg = s & 15;
        *(uint4*)((char*)lB + (seg >> 3) * 8192 + row * 128 +
                  16 * ((seg & 7) ^ (row & 7))) = rb2[i];
    }
    LWRITEA()
    __syncthreads();

    u32 sbp[4][4][2];
#pragma unroll
    for (int q = 0; q < 4; ++q) {
        if (q < 3) GLOADA(q + 1)   // issue next-phase weight loads before MFMA
        f32x4 acc[4];
#pragma unroll
        for (int mi = 0; mi < 4; ++mi) acc[mi] = (f32x4){0.f, 0.f, 0.f, 0.f};
#pragma unroll
        for (int chunk = 0; chunk < 2; ++chunk)
#pragma unroll
            for (int ks = 0; ks < 2; ++ks) {
                const int ch = ks * 4 + kq;
                short8 af[4], bfv;
#pragma unroll
                for (int mi = 0; mi < 4; ++mi) {
                    int row = wr * 64 + mi * 16 + r15;
                    af[mi] = *(const short8*)((const char*)lA + chunk * 16384 +
                                              row * 128 + 16 * (ch ^ (row & 7)));
                }
                {
                    int row = wc * 16 + r15;
                    bfv = *(const short8*)((const char*)lB + chunk * 8192 +
                                           row * 128 + 16 * (ch ^ (row & 7)));
                }
#pragma unroll
                for (int mi = 0; mi < 4; ++mi)
                    acc[mi] = __builtin_amdgcn_mfma_f32_16x16x32_bf16(
                        af[mi], bfv, acc[mi], 0, 0, 0);
            }
#pragma unroll
        for (int mi = 0; mi < 4; ++mi)
#pragma unroll
            for (int rp = 0; rp < 2; ++rp) {
                int c0 = q * 128 + wr * 64 + mi * 16 + kq * 4 + rp * 2;
                float v0 = gelu_f(acc[mi][rp * 2] * sparam[c0] + sparam[512 + c0]);
                float v1 = gelu_f(acc[mi][rp * 2 + 1] * sparam[c0 + 1] + sparam[512 + c0 + 1]);
                sbp[q][mi][rp] = (u32)f2bf(v0) | ((u32)f2bf(v1) << 16);
            }
        if (q < 3) {
            __syncthreads();
            LWRITEA()
            __syncthreads();
        }
    }
    const int i = n0 >> 1;
    const int j = (n0 & 1) * 64 + wc * 16 + r15;
#pragma unroll
    for (int mi = 0; mi < 4; ++mi)
#pragma unroll
        for (int rp = 0; rp < 2; ++rp) {
            u32 p0 = sbp[0][mi][rp], p1 = sbp[1][mi][rp];
            u32 p2 = sbp[2][mi][rp], p3 = sbp[3][mi][rp];
#pragma unroll
            for (int e = 0; e < 2; ++e) {
                int c = wr * 64 + mi * 16 + kq * 4 + rp * 2 + e;
                float ll = bf2f(e ? (u16)(p0 >> 16) : (u16)(p0 & 0xFFFF));
                float lh = bf2f(e ? (u16)(p1 >> 16) : (u16)(p1 & 0xFFFF));
                float hl = bf2f(e ? (u16)(p2 >> 16) : (u16)(p2 & 0xFFFF));
                float hh = bf2f(e ? (u16)(p3 >> 16) : (u16)(p3 & 0xFFFF));
                long ob = (((long)(b * Cc + c) * Hh + 2 * i) * Wf + 2 * j);
                union { float2 v; u64 u; } w0, w1;
                w0.v = make_float2((ll + lh + hl + hh) * 0.5f, (ll + lh - hl - hh) * 0.5f);
                w1.v = make_float2((ll - lh + hl - hh) * 0.5f, (ll - lh - hl + hh) * 0.5f);
                __builtin_nontemporal_store(w0.u, (u64*)(out + ob));
                __builtin_nontemporal_store(w1.u, (u64*)(out + ob + Wf));
            }
        }
#undef GLOADA
#undef LWRITEA
}

extern "C" void kernel_launch(void* const* d_in, const int* in_sizes, int n_in,
                              void* d_out, int out_size, void* d_ws, size_t ws_size,
                              hipStream_t stream) {
    const float* x     = (const float*)d_in[0];
    const float* w_c1  = (const float*)d_in[1];
    const float* bn1_g = (const float*)d_in[3];
    const float* bn1_b = (const float*)d_in[4];
    const float* dw_w  = (const float*)d_in[5];
    const float* dw_b  = (const float*)d_in[6];
    const float* gn_g  = (const float*)d_in[7];
    const float* gn_b  = (const float*)d_in[8];
    const float* pw1_w = (const float*)d_in[9];
    const float* pw1_b = (const float*)d_in[10];
    const float* pw2_w = (const float*)d_in[11];
    const float* pw2_b = (const float*)d_in[12];
    const float* w_c2  = (const float*)d_in[13];
    const float* bn2_g = (const float*)d_in[15];
    const float* bn2_b = (const float*)d_in[16];
    float* out = (float*)d_out;

    const size_t n128 = (size_t)Bq * Cc * HW2;
    u16* bufA = (u16*)d_ws;
    u16* bufD = bufA + n128;
    u16* bufY = bufD + n128;
    u16* wb   = bufY + n128;
    float* stats = (float*)(wb + 163840);
    float* M2p = stats + 49152;    // 256 x 16384 f32 partials (16 MB)
    size_t need = (3 * n128 + 163840) * 2 + (49152 + 256 * 16384) * 4;
    if (ws_size < need) return;

    float* bn1_sum = stats;
    float* bn1_sq  = stats + 2048;
    float* ln_sum  = stats + 4096;
    float* ln_sq   = stats + 12288;
    float* csum    = stats + 20480;
    float* M2      = stats + 22528;
    float* scsh    = stats + 38912;
    float* wbv     = stats + 39936;
    float* wgs     = stats + 40064;

    // 0. weights -> bf16 + stats zeroing + LN-fold vectors (block 640)
    k_wconv<<<641, 256, 0, stream>>>(w_c1, pw1_w, pw2_w, w_c2, gn_g, gn_b,
                                     wb, wbv, wgs, stats);

    // 1. fused DWT + conv1 + BN1 stats
    k_conv1<<<dim3(1, 128, 8), 512, 0, stream>>>(x, wb, bufA, bn1_sum, bn1_sq);

    // 2. depthwise 3x3, 4-row tiles, fused BN1+gelu on load + LN stats
    k_dwconv<<<dim3(8, 32, 8), 256, 0, stream>>>(bufA, bufD, dw_w, dw_b,
                                                 bn1_sum, bn1_sq, bn1_g, bn1_b,
                                                 ln_sum, ln_sq);

    // 3. fused MLP (512 thr): pw1 (LN-folded + gelu) -> pw2 (+bias + residual)
    k_mlp<<<dim3(1, 128, 8), 512, 0, stream>>>(
        bufD, wb + 65536, wb + 81920, pw1_b, pw2_b, bufA, bufY,
        ln_sum, ln_sq, wbv, wgs, bn1_sum, bn1_sq, bn1_g, bn1_b);

    // 4. BN2 stats: per-block M2 partials (256 blocks) + reduce + combine
    k_moment<<<256, 256, 0, stream>>>(bufY, M2p, csum);
    k_m2red<<<64, 256, 0, stream>>>(M2p, M2);
    k_statcomb<<<512, 128, 0, stream>>>(w_c2, M2, csum, bn2_g, bn2_b, scsh);

    // 5. conv2 + BN2 + gelu + IDWT -> out (NT stores, hoisted prefetch)
    k_conv2_idwt<<<dim3(256, 8), 512, 0, stream>>>(bufY, wb + 98304, scsh, out);
}